// Round 1
// baseline (1323.848 us; speedup 1.0000x reference)
//
#include <hip/hip_runtime.h>
#include <hip/hip_bf16.h>
#include <math.h>

#define N_ENTITY 30000
#define N_REL    12
#define N_BASES  8
#define KG_DIM   128
#define TOK_DIM  768
#define BATCH    32
#define N_CTX    50
#define SEQ      256
#define N_EDGES  400000

// ---------------- workspace layout (in floats) ----------------
// kg      : 3,840,000
// cnt(int): 360,000
// e_tok   : 8,192
// ent_rep : 4,096
// tok_rep : 4,096
// user    : 4,096
// weight  : 46,080,000 (optional)
#define OFF_KG    0
#define OFF_CNT   3840000
#define OFF_ETOK  4200000
#define OFF_ENT   4208192
#define OFF_TOK   4212288
#define OFF_USER  4216384
#define OFF_W     4220480
#define NEED_W_BYTES ((size_t)(OFF_W + 46080000) * 4)

__global__ void zero_cnt_kernel(int* __restrict__ cnt) {
    int i = blockIdx.x * 256 + threadIdx.x;
    if (i < N_REL * N_ENTITY) cnt[i] = 0;
}

__global__ void count_kernel(const int* __restrict__ edge_index,
                             const int* __restrict__ edge_type,
                             int* __restrict__ cnt) {
    int e = blockIdx.x * 256 + threadIdx.x;
    if (e >= N_EDGES) return;
    int r = edge_type[e];
    int dst = edge_index[N_EDGES + e];
    atomicAdd(&cnt[r * N_ENTITY + dst], 1);
}

// weight[r,n,d] = sum_b comp[r,b] * basis[b,n,d]
__global__ void weight_kernel(const float* __restrict__ comp,
                              const float4* __restrict__ basis4,
                              float4* __restrict__ weight4) {
    int idx = blockIdx.x * 256 + threadIdx.x;  // over N_ENTITY*KG_DIM/4 = 960000
    float4 bv[N_BASES];
#pragma unroll
    for (int b = 0; b < N_BASES; ++b) bv[b] = basis4[(size_t)b * 960000 + idx];
#pragma unroll
    for (int r = 0; r < N_REL; ++r) {
        float4 w = make_float4(0.f, 0.f, 0.f, 0.f);
#pragma unroll
        for (int b = 0; b < N_BASES; ++b) {
            float c = comp[r * N_BASES + b];
            w.x += c * bv[b].x; w.y += c * bv[b].y;
            w.z += c * bv[b].z; w.w += c * bv[b].w;
        }
        weight4[(size_t)r * 960000 + idx] = w;
    }
}

// kg = root + bias (then scatter atomically accumulates)
__global__ void kg_init_kernel(const float4* __restrict__ root4,
                               const float4* __restrict__ bias4,
                               float4* __restrict__ kg4) {
    int i = blockIdx.x * 256 + threadIdx.x;  // 960000
    float4 r = root4[i];
    float4 b = bias4[i & 31];
    kg4[i] = make_float4(r.x + b.x, r.y + b.y, r.z + b.z, r.w + b.w);
}

__global__ void scatter_kernel(const int* __restrict__ edge_index,
                               const int* __restrict__ edge_type,
                               const int* __restrict__ cnt,
                               const float4* __restrict__ weight4,
                               float* __restrict__ kg) {
    int sub = threadIdx.x >> 5, lane = threadIdx.x & 31;
    int e = blockIdx.x * 8 + sub;
    if (e >= N_EDGES) return;
    int r = edge_type[e];
    int src = edge_index[e];
    int dst = edge_index[N_EDGES + e];
    int c = cnt[r * N_ENTITY + dst];
    float norm = 1.0f / (float)(c > 1 ? c : 1);
    float4 w = weight4[(size_t)r * 960000 + (size_t)src * 32 + lane];
    float* p = kg + (size_t)dst * KG_DIM + lane * 4;
    atomicAdd(p + 0, w.x * norm);
    atomicAdd(p + 1, w.y * norm);
    atomicAdd(p + 2, w.z * norm);
    atomicAdd(p + 3, w.w * norm);
}

// fallback: compute msg on the fly (no 184MB weight buffer)
__global__ void scatter_otf_kernel(const int* __restrict__ edge_index,
                                   const int* __restrict__ edge_type,
                                   const int* __restrict__ cnt,
                                   const float* __restrict__ comp,
                                   const float4* __restrict__ basis4,
                                   float* __restrict__ kg) {
    int sub = threadIdx.x >> 5, lane = threadIdx.x & 31;
    int e = blockIdx.x * 8 + sub;
    if (e >= N_EDGES) return;
    int r = edge_type[e];
    int src = edge_index[e];
    int dst = edge_index[N_EDGES + e];
    int c = cnt[r * N_ENTITY + dst];
    float norm = 1.0f / (float)(c > 1 ? c : 1);
    float4 msg = make_float4(0.f, 0.f, 0.f, 0.f);
#pragma unroll
    for (int b = 0; b < N_BASES; ++b) {
        float cf = comp[r * N_BASES + b];
        float4 bs = basis4[(size_t)b * 960000 + (size_t)src * 32 + lane];
        msg.x += cf * bs.x; msg.y += cf * bs.y;
        msg.z += cf * bs.z; msg.w += cf * bs.w;
    }
    float* p = kg + (size_t)dst * KG_DIM + lane * 4;
    atomicAdd(p + 0, msg.x * norm);
    atomicAdd(p + 1, msg.y * norm);
    atomicAdd(p + 2, msg.z * norm);
    atomicAdd(p + 3, msg.w * norm);
}

// entity self-dot attention pool: one block per batch element
__global__ void ent_attn_kernel(const int* __restrict__ ctx_ent,
                                const float* __restrict__ kg,
                                const float* __restrict__ W,
                                const float* __restrict__ bb,
                                const float* __restrict__ v,
                                float* __restrict__ ent_rep) {
    __shared__ float h[N_CTX * KG_DIM];  // 25.6 KB
    __shared__ float es[64];
    __shared__ int ids[N_CTX];
    int b = blockIdx.x, tid = threadIdx.x;
    if (tid < N_CTX) ids[tid] = ctx_ent[b * N_CTX + tid];
    __syncthreads();
    for (int i = tid; i < N_CTX * KG_DIM; i += 256) {
        int l = i >> 7, d = i & 127;
        h[i] = kg[(size_t)ids[l] * KG_DIM + d];
    }
    __syncthreads();

    int wave = tid >> 6, lane = tid & 63;
    // wave handles l = wave, wave+4, ... ; waves 0,1: 13 l's, waves 2,3: 12
    const int nl = (N_CTX - wave + 3) / 4;
    float s0[13], s1[13];
#pragma unroll
    for (int i = 0; i < 13; ++i) { s0[i] = 0.f; s1[i] = 0.f; }
    for (int k = 0; k < KG_DIM; ++k) {
        float w0 = W[k * KG_DIM + lane];
        float w1 = W[k * KG_DIM + lane + 64];
#pragma unroll
        for (int i = 0; i < 13; ++i) {
            if (i < nl) {
                float hk = h[(wave + i * 4) * KG_DIM + k];
                s0[i] += hk * w0;
                s1[i] += hk * w1;
            }
        }
    }
    float bias0 = bb[lane], bias1 = bb[lane + 64];
    float v0 = v[lane], v1 = v[lane + 64];
    for (int i = 0; i < nl; ++i) {
        int l = wave + i * 4;
        float p = tanhf(s0[i] + bias0) * v0 + tanhf(s1[i] + bias1) * v1;
        p += __shfl_xor(p, 32); p += __shfl_xor(p, 16); p += __shfl_xor(p, 8);
        p += __shfl_xor(p, 4);  p += __shfl_xor(p, 2);  p += __shfl_xor(p, 1);
        if (lane == 0) es[l] = p;
    }
    __syncthreads();
    if (tid < 64) {
        float val = (tid < N_CTX && ids[tid] != 0) ? es[tid] : -1e9f;
        float mx = val;
        mx = fmaxf(mx, __shfl_xor(mx, 32)); mx = fmaxf(mx, __shfl_xor(mx, 16));
        mx = fmaxf(mx, __shfl_xor(mx, 8));  mx = fmaxf(mx, __shfl_xor(mx, 4));
        mx = fmaxf(mx, __shfl_xor(mx, 2));  mx = fmaxf(mx, __shfl_xor(mx, 1));
        float ex = (tid < N_CTX) ? expf(val - mx) : 0.f;
        float sm = ex;
        sm += __shfl_xor(sm, 32); sm += __shfl_xor(sm, 16); sm += __shfl_xor(sm, 8);
        sm += __shfl_xor(sm, 4);  sm += __shfl_xor(sm, 2);  sm += __shfl_xor(sm, 1);
        if (tid < N_CTX) es[tid] = ex / sm;
    }
    __syncthreads();
    if (tid < KG_DIM) {
        float o = 0.f;
#pragma unroll
        for (int l = 0; l < N_CTX; ++l) o += es[l] * h[l * KG_DIM + tid];
        ent_rep[b * KG_DIM + tid] = o;
    }
}

// e[b,l] = v . tanh(h W + b) over tokens. Block = 16 rows, 256 threads,
// 3 output columns per thread (768 = 3*256). A tile staged in LDS.
__global__ __launch_bounds__(256) void tok_e_kernel(const float4* __restrict__ A4,
                                                    const float* __restrict__ W,
                                                    const float* __restrict__ bias,
                                                    const float* __restrict__ v,
                                                    float* __restrict__ e_out) {
    __shared__ float4 As4[16 * 192];  // 48 KB : 16 rows x 768 floats
    __shared__ float e_sh[16];
    int tid = threadIdx.x;
    int r0 = blockIdx.x * 16;
    if (tid < 16) e_sh[tid] = 0.f;
#pragma unroll
    for (int i = 0; i < 12; ++i)
        As4[tid + i * 256] = A4[(size_t)r0 * 192 + tid + i * 256];
    __syncthreads();

    float acc0[16], acc1[16], acc2[16];
#pragma unroll
    for (int m = 0; m < 16; ++m) { acc0[m] = 0.f; acc1[m] = 0.f; acc2[m] = 0.f; }
    const int c0 = tid, c1 = tid + 256, c2 = tid + 512;
    for (int k = 0; k < TOK_DIM; k += 4) {
        const float* Wk = W + (size_t)k * TOK_DIM;
        float w00 = Wk[c0],            w01 = Wk[c1],            w02 = Wk[c2];
        float w10 = Wk[TOK_DIM + c0],  w11 = Wk[TOK_DIM + c1],  w12 = Wk[TOK_DIM + c2];
        float w20 = Wk[2*TOK_DIM + c0],w21 = Wk[2*TOK_DIM + c1],w22 = Wk[2*TOK_DIM + c2];
        float w30 = Wk[3*TOK_DIM + c0],w31 = Wk[3*TOK_DIM + c1],w32 = Wk[3*TOK_DIM + c2];
#pragma unroll
        for (int m = 0; m < 16; ++m) {
            float4 a = As4[m * 192 + (k >> 2)];
            acc0[m] += a.x * w00 + a.y * w10 + a.z * w20 + a.w * w30;
            acc1[m] += a.x * w01 + a.y * w11 + a.z * w21 + a.w * w31;
            acc2[m] += a.x * w02 + a.y * w12 + a.z * w22 + a.w * w32;
        }
    }
    float b0 = bias[c0], b1 = bias[c1], b2 = bias[c2];
    float v0 = v[c0],   v1 = v[c1],   v2 = v[c2];
    int lane = tid & 63;
#pragma unroll
    for (int m = 0; m < 16; ++m) {
        float p = tanhf(acc0[m] + b0) * v0 + tanhf(acc1[m] + b1) * v1 +
                  tanhf(acc2[m] + b2) * v2;
        p += __shfl_xor(p, 32); p += __shfl_xor(p, 16); p += __shfl_xor(p, 8);
        p += __shfl_xor(p, 4);  p += __shfl_xor(p, 2);  p += __shfl_xor(p, 1);
        if (lane == 0) atomicAdd(&e_sh[m], p);
    }
    __syncthreads();
    if (tid < 16) e_out[r0 + tid] = e_sh[tid];
}

// masked softmax over SEQ, pooled = a.h, then linear 768->128. One block per b.
__global__ void tok_pool_kernel(const int* __restrict__ ctx_tok,
                                const float* __restrict__ e_ws,
                                const float* __restrict__ tok_emb,
                                const float* __restrict__ lin_W,
                                const float* __restrict__ lin_b,
                                float* __restrict__ tok_rep) {
    __shared__ float a_s[SEQ];
    __shared__ float pooled[TOK_DIM];
    __shared__ float redm[4];
    __shared__ float reds[4];
    int b = blockIdx.x, tid = threadIdx.x;
    int wave = tid >> 6, lane = tid & 63;
    int t = ctx_tok[b * SEQ + tid];
    float val = (t != 0) ? e_ws[b * SEQ + tid] : -1e9f;
    float mx = val;
    mx = fmaxf(mx, __shfl_xor(mx, 32)); mx = fmaxf(mx, __shfl_xor(mx, 16));
    mx = fmaxf(mx, __shfl_xor(mx, 8));  mx = fmaxf(mx, __shfl_xor(mx, 4));
    mx = fmaxf(mx, __shfl_xor(mx, 2));  mx = fmaxf(mx, __shfl_xor(mx, 1));
    if (lane == 0) redm[wave] = mx;
    __syncthreads();
    mx = fmaxf(fmaxf(redm[0], redm[1]), fmaxf(redm[2], redm[3]));
    float ex = expf(val - mx);
    float sm = ex;
    sm += __shfl_xor(sm, 32); sm += __shfl_xor(sm, 16); sm += __shfl_xor(sm, 8);
    sm += __shfl_xor(sm, 4);  sm += __shfl_xor(sm, 2);  sm += __shfl_xor(sm, 1);
    if (lane == 0) reds[wave] = sm;
    __syncthreads();
    sm = reds[0] + reds[1] + reds[2] + reds[3];
    a_s[tid] = ex / sm;
    __syncthreads();
    const float* emb = tok_emb + (size_t)b * SEQ * TOK_DIM;
    for (int d = tid; d < TOK_DIM; d += 256) {
        float acc = 0.f;
        for (int l = 0; l < SEQ; ++l) acc += a_s[l] * emb[(size_t)l * TOK_DIM + d];
        pooled[d] = acc;
    }
    __syncthreads();
    if (tid < KG_DIM) {
        float s = lin_b[tid];
        const float* wr = lin_W + (size_t)tid * TOK_DIM;
        for (int k = 0; k < TOK_DIM; ++k) s += pooled[k] * wr[k];
        tok_rep[b * KG_DIM + tid] = s;
    }
}

__global__ void gate_kernel(const float* __restrict__ tok_rep,
                            const float* __restrict__ ent_rep,
                            const float* __restrict__ gate_W,
                            const float* __restrict__ gate_b,
                            float* __restrict__ user) {
    __shared__ float tr[KG_DIM], er[KG_DIM];
    int b = blockIdx.x, d = threadIdx.x;  // 128 threads
    tr[d] = tok_rep[b * KG_DIM + d];
    er[d] = ent_rep[b * KG_DIM + d];
    __syncthreads();
    float g = gate_b[d];
    const float* wr = gate_W + (size_t)d * 256;
#pragma unroll 8
    for (int k = 0; k < KG_DIM; ++k) g += tr[k] * wr[k] + er[k] * wr[KG_DIM + k];
    float sig = 1.f / (1.f + expf(-g));
    user[b * KG_DIM + d] = sig * tr[d] + (1.f - sig) * er[d];
}

__global__ void scores_kernel(const float* __restrict__ user,
                              const float4* __restrict__ kg4,
                              float* __restrict__ out) {
    __shared__ float4 u4[BATCH * 32];  // 16 KB
    int tid = threadIdx.x;
    for (int i = tid; i < BATCH * 32; i += 256) u4[i] = ((const float4*)user)[i];
    __syncthreads();
    int n = blockIdx.x * 256 + tid;
    if (n >= N_ENTITY) return;
    float acc[BATCH];
#pragma unroll
    for (int b = 0; b < BATCH; ++b) acc[b] = 0.f;
    for (int d4 = 0; d4 < 32; ++d4) {
        float4 k = kg4[(size_t)n * 32 + d4];
#pragma unroll
        for (int b = 0; b < BATCH; ++b) {
            float4 u = u4[b * 32 + d4];
            acc[b] += k.x * u.x + k.y * u.y + k.z * u.z + k.w * u.w;
        }
    }
    for (int b = 0; b < BATCH; ++b) out[(size_t)b * N_ENTITY + n] = acc[b];
}

extern "C" void kernel_launch(void* const* d_in, const int* in_sizes, int n_in,
                              void* d_out, int out_size, void* d_ws, size_t ws_size,
                              hipStream_t stream) {
    (void)in_sizes; (void)n_in; (void)out_size;
    const int*   ctx_ent   = (const int*)d_in[0];
    const int*   ctx_tok   = (const int*)d_in[1];
    const int*   edge_index= (const int*)d_in[2];
    const int*   edge_type = (const int*)d_in[3];
    const float* tok_emb   = (const float*)d_in[4];
    const float* comp      = (const float*)d_in[5];
    const float* basis     = (const float*)d_in[6];
    const float* root      = (const float*)d_in[7];
    const float* rgcn_bias = (const float*)d_in[8];
    const float* ent_W     = (const float*)d_in[9];
    const float* ent_b     = (const float*)d_in[10];
    const float* ent_v     = (const float*)d_in[11];
    const float* tok_W     = (const float*)d_in[12];
    const float* tok_b     = (const float*)d_in[13];
    const float* tok_v     = (const float*)d_in[14];
    const float* lin_W     = (const float*)d_in[15];
    const float* lin_b     = (const float*)d_in[16];
    const float* gate_W    = (const float*)d_in[17];
    const float* gate_b    = (const float*)d_in[18];
    float* scores = (float*)d_out;

    float* ws = (float*)d_ws;
    float* kg      = ws + OFF_KG;
    int*   cnt     = (int*)(ws + OFF_CNT);
    float* e_ws    = ws + OFF_ETOK;
    float* ent_rep = ws + OFF_ENT;
    float* tok_rep = ws + OFF_TOK;
    float* user    = ws + OFF_USER;
    float* weight  = ws + OFF_W;
    const bool use_weight = (ws_size >= NEED_W_BYTES);

    zero_cnt_kernel<<<(N_REL * N_ENTITY + 255) / 256, 256, 0, stream>>>(cnt);
    count_kernel<<<(N_EDGES + 255) / 256, 256, 0, stream>>>(edge_index, edge_type, cnt);
    kg_init_kernel<<<3750, 256, 0, stream>>>((const float4*)root, (const float4*)rgcn_bias,
                                             (float4*)kg);
    if (use_weight) {
        weight_kernel<<<3750, 256, 0, stream>>>(comp, (const float4*)basis, (float4*)weight);
        scatter_kernel<<<N_EDGES / 8, 256, 0, stream>>>(edge_index, edge_type, cnt,
                                                        (const float4*)weight, kg);
    } else {
        scatter_otf_kernel<<<N_EDGES / 8, 256, 0, stream>>>(edge_index, edge_type, cnt,
                                                            comp, (const float4*)basis, kg);
    }
    ent_attn_kernel<<<BATCH, 256, 0, stream>>>(ctx_ent, kg, ent_W, ent_b, ent_v, ent_rep);
    tok_e_kernel<<<(BATCH * SEQ) / 16, 256, 0, stream>>>((const float4*)tok_emb, tok_W,
                                                         tok_b, tok_v, e_ws);
    tok_pool_kernel<<<BATCH, 256, 0, stream>>>(ctx_tok, e_ws, tok_emb, lin_W, lin_b, tok_rep);
    gate_kernel<<<BATCH, 128, 0, stream>>>(tok_rep, ent_rep, gate_W, gate_b, user);
    scores_kernel<<<(N_ENTITY + 255) / 256, 256, 0, stream>>>(user, (const float4*)kg, scores);
}

// Round 2
// 810.164 us; speedup vs baseline: 1.6340x; 1.6340x over previous
//
#include <hip/hip_runtime.h>
#include <hip/hip_bf16.h>
#include <math.h>

#define N_ENTITY 30000
#define N_REL    12
#define N_BASES  8
#define KG_DIM   128
#define TOK_DIM  768
#define BATCH    32
#define N_CTX    50
#define SEQ      256
#define N_EDGES  400000

// ---------------- workspace layout (in floats, all 16B-aligned) ----------------
#define OFF_KG     0           // 3,840,000
#define OFF_CNT    3840000     // 360,000 ints
#define OFF_DEG    4200000     // 30,000 ints
#define OFF_START  4230000     // 30,004 ints (N+1 used)
#define OFF_CURSOR 4260004     // 30,000 ints
#define OFF_SR     4290004     // 400,000 ints (packed src|r<<15)
#define OFF_NORM   4690004     // 400,000 floats
#define OFF_ETOK   5090004     // 8,192
#define OFF_ENT    5098196     // 4,096
#define OFF_TOK    5102292     // 4,096
#define OFF_USER   5106388     // 4,096
#define OFF_W      5110484     // 46,080,000
#define NEED_W_BYTES ((size_t)(OFF_W + 46080000) * 4)

__global__ void zero_kernel(int* __restrict__ p, int n) {
    int i = blockIdx.x * 256 + threadIdx.x;
    if (i < n) p[i] = 0;
}

// per-(r,dst) count and per-dst degree
__global__ void count_kernel(const int* __restrict__ edge_index,
                             const int* __restrict__ edge_type,
                             int* __restrict__ cnt,
                             int* __restrict__ deg) {
    int e = blockIdx.x * 256 + threadIdx.x;
    if (e >= N_EDGES) return;
    int r = edge_type[e];
    int dst = edge_index[N_EDGES + e];
    atomicAdd(&cnt[r * N_ENTITY + dst], 1);
    atomicAdd(&deg[dst], 1);
}

// single-block exclusive scan of deg -> start, also copies to cursor
__global__ __launch_bounds__(1024) void scan_kernel(const int* __restrict__ deg,
                                                    int* __restrict__ start,
                                                    int* __restrict__ cursor) {
    __shared__ int buf[1024];
    __shared__ int carry;
    int tid = threadIdx.x;
    if (tid == 0) carry = 0;
    __syncthreads();
    for (int base = 0; base < N_ENTITY; base += 1024) {
        int i = base + tid;
        int v = (i < N_ENTITY) ? deg[i] : 0;
        buf[tid] = v;
        __syncthreads();
        for (int off = 1; off < 1024; off <<= 1) {
            int t = (tid >= off) ? buf[tid - off] : 0;
            __syncthreads();
            buf[tid] += t;
            __syncthreads();
        }
        if (i < N_ENTITY) {
            int ex = carry + buf[tid] - v;
            start[i] = ex;
            cursor[i] = ex;
        }
        __syncthreads();
        if (tid == 1023) carry += buf[1023];
        __syncthreads();
    }
    if (tid == 0) start[N_ENTITY] = carry;
}

__global__ void place_kernel(const int* __restrict__ edge_index,
                             const int* __restrict__ edge_type,
                             const int* __restrict__ cnt,
                             int* __restrict__ cursor,
                             int* __restrict__ sr,
                             float* __restrict__ nrm) {
    int e = blockIdx.x * 256 + threadIdx.x;
    if (e >= N_EDGES) return;
    int r = edge_type[e];
    int src = edge_index[e];
    int dst = edge_index[N_EDGES + e];
    int c = cnt[r * N_ENTITY + dst];
    int slot = atomicAdd(&cursor[dst], 1);
    sr[slot] = src | (r << 15);
    nrm[slot] = 1.0f / (float)(c > 1 ? c : 1);
}

// weight[r,n,d] = sum_b comp[r,b] * basis[b,n,d]
__global__ void weight_kernel(const float* __restrict__ comp,
                              const float4* __restrict__ basis4,
                              float4* __restrict__ weight4) {
    int idx = blockIdx.x * 256 + threadIdx.x;  // over N_ENTITY*KG_DIM/4 = 960000
    float4 bv[N_BASES];
#pragma unroll
    for (int b = 0; b < N_BASES; ++b) bv[b] = basis4[(size_t)b * 960000 + idx];
#pragma unroll
    for (int r = 0; r < N_REL; ++r) {
        float4 w = make_float4(0.f, 0.f, 0.f, 0.f);
#pragma unroll
        for (int b = 0; b < N_BASES; ++b) {
            float c = comp[r * N_BASES + b];
            w.x += c * bv[b].x; w.y += c * bv[b].y;
            w.z += c * bv[b].z; w.w += c * bv[b].w;
        }
        weight4[(size_t)r * 960000 + idx] = w;
    }
}

// one wave per dst entity; lane owns dims [2*lane, 2*lane+1]
__global__ __launch_bounds__(256) void gather_kernel(const int* __restrict__ start,
                                                     const int* __restrict__ deg,
                                                     const int* __restrict__ sr,
                                                     const float* __restrict__ nrm,
                                                     const float2* __restrict__ w2,
                                                     const float2* __restrict__ root2,
                                                     const float2* __restrict__ bias2,
                                                     float2* __restrict__ kg2) {
    int wv = threadIdx.x >> 6, lane = threadIdx.x & 63;
    int dst = blockIdx.x * 4 + wv;
    if (dst >= N_ENTITY) return;
    int s = start[dst], n = deg[dst];
    float ax = 0.f, ay = 0.f;
    int j = 0;
    for (; j + 1 < n; j += 2) {
        int p0 = sr[s + j], p1 = sr[s + j + 1];
        float n0 = nrm[s + j], n1 = nrm[s + j + 1];
        int s0 = p0 & 32767, r0 = p0 >> 15;
        int s1 = p1 & 32767, r1 = p1 >> 15;
        float2 w0 = w2[((size_t)(r0 * N_ENTITY + s0)) * 64 + lane];
        float2 w1 = w2[((size_t)(r1 * N_ENTITY + s1)) * 64 + lane];
        ax += w0.x * n0 + w1.x * n1;
        ay += w0.y * n0 + w1.y * n1;
    }
    if (j < n) {
        int p0 = sr[s + j];
        float n0 = nrm[s + j];
        int s0 = p0 & 32767, r0 = p0 >> 15;
        float2 w0 = w2[((size_t)(r0 * N_ENTITY + s0)) * 64 + lane];
        ax += w0.x * n0;
        ay += w0.y * n0;
    }
    float2 rt = root2[(size_t)dst * 64 + lane];
    float2 bs = bias2[lane];
    kg2[(size_t)dst * 64 + lane] = make_float2(ax + rt.x + bs.x, ay + rt.y + bs.y);
}

// fallback: compute message from basis on the fly (no weight buffer)
__global__ __launch_bounds__(256) void gather_otf_kernel(const int* __restrict__ start,
                                                         const int* __restrict__ deg,
                                                         const int* __restrict__ sr,
                                                         const float* __restrict__ nrm,
                                                         const float* __restrict__ comp,
                                                         const float2* __restrict__ basis2,
                                                         const float2* __restrict__ root2,
                                                         const float2* __restrict__ bias2,
                                                         float2* __restrict__ kg2) {
    int wv = threadIdx.x >> 6, lane = threadIdx.x & 63;
    int dst = blockIdx.x * 4 + wv;
    if (dst >= N_ENTITY) return;
    int s = start[dst], n = deg[dst];
    float ax = 0.f, ay = 0.f;
    for (int j = 0; j < n; ++j) {
        int p = sr[s + j];
        float nm = nrm[s + j];
        int src = p & 32767, r = p >> 15;
        float mx = 0.f, my = 0.f;
#pragma unroll
        for (int b = 0; b < N_BASES; ++b) {
            float cf = comp[r * N_BASES + b];
            float2 bs = basis2[((size_t)b * N_ENTITY + src) * 64 + lane];
            mx += cf * bs.x; my += cf * bs.y;
        }
        ax += mx * nm; ay += my * nm;
    }
    float2 rt = root2[(size_t)dst * 64 + lane];
    float2 bs = bias2[lane];
    kg2[(size_t)dst * 64 + lane] = make_float2(ax + rt.x + bs.x, ay + rt.y + bs.y);
}

// entity self-dot attention pool: one block per batch element
__global__ void ent_attn_kernel(const int* __restrict__ ctx_ent,
                                const float* __restrict__ kg,
                                const float* __restrict__ W,
                                const float* __restrict__ bb,
                                const float* __restrict__ v,
                                float* __restrict__ ent_rep) {
    __shared__ float h[N_CTX * KG_DIM];  // 25.6 KB
    __shared__ float es[64];
    __shared__ int ids[N_CTX];
    int b = blockIdx.x, tid = threadIdx.x;
    if (tid < N_CTX) ids[tid] = ctx_ent[b * N_CTX + tid];
    __syncthreads();
    for (int i = tid; i < N_CTX * KG_DIM; i += 256) {
        int l = i >> 7, d = i & 127;
        h[i] = kg[(size_t)ids[l] * KG_DIM + d];
    }
    __syncthreads();

    int wave = tid >> 6, lane = tid & 63;
    const int nl = (N_CTX - wave + 3) / 4;
    float s0[13], s1[13];
#pragma unroll
    for (int i = 0; i < 13; ++i) { s0[i] = 0.f; s1[i] = 0.f; }
    for (int k = 0; k < KG_DIM; ++k) {
        float w0 = W[k * KG_DIM + lane];
        float w1 = W[k * KG_DIM + lane + 64];
#pragma unroll
        for (int i = 0; i < 13; ++i) {
            if (i < nl) {
                float hk = h[(wave + i * 4) * KG_DIM + k];
                s0[i] += hk * w0;
                s1[i] += hk * w1;
            }
        }
    }
    float bias0 = bb[lane], bias1 = bb[lane + 64];
    float v0 = v[lane], v1 = v[lane + 64];
    for (int i = 0; i < nl; ++i) {
        int l = wave + i * 4;
        float p = tanhf(s0[i] + bias0) * v0 + tanhf(s1[i] + bias1) * v1;
        p += __shfl_xor(p, 32); p += __shfl_xor(p, 16); p += __shfl_xor(p, 8);
        p += __shfl_xor(p, 4);  p += __shfl_xor(p, 2);  p += __shfl_xor(p, 1);
        if (lane == 0) es[l] = p;
    }
    __syncthreads();
    if (tid < 64) {
        float val = (tid < N_CTX && ids[tid] != 0) ? es[tid] : -1e9f;
        float mx = val;
        mx = fmaxf(mx, __shfl_xor(mx, 32)); mx = fmaxf(mx, __shfl_xor(mx, 16));
        mx = fmaxf(mx, __shfl_xor(mx, 8));  mx = fmaxf(mx, __shfl_xor(mx, 4));
        mx = fmaxf(mx, __shfl_xor(mx, 2));  mx = fmaxf(mx, __shfl_xor(mx, 1));
        float ex = (tid < N_CTX) ? expf(val - mx) : 0.f;
        float sm = ex;
        sm += __shfl_xor(sm, 32); sm += __shfl_xor(sm, 16); sm += __shfl_xor(sm, 8);
        sm += __shfl_xor(sm, 4);  sm += __shfl_xor(sm, 2);  sm += __shfl_xor(sm, 1);
        if (tid < N_CTX) es[tid] = ex / sm;
    }
    __syncthreads();
    if (tid < KG_DIM) {
        float o = 0.f;
#pragma unroll
        for (int l = 0; l < N_CTX; ++l) o += es[l] * h[l * KG_DIM + tid];
        ent_rep[b * KG_DIM + tid] = o;
    }
}

// e[b,l] = v . tanh(h W + b) over tokens. Block = 16 rows, 256 threads,
// 3 output columns per thread (768 = 3*256). A tile staged in LDS.
__global__ __launch_bounds__(256) void tok_e_kernel(const float4* __restrict__ A4,
                                                    const float* __restrict__ W,
                                                    const float* __restrict__ bias,
                                                    const float* __restrict__ v,
                                                    float* __restrict__ e_out) {
    __shared__ float4 As4[16 * 192];  // 48 KB : 16 rows x 768 floats
    __shared__ float e_sh[16];
    int tid = threadIdx.x;
    int r0 = blockIdx.x * 16;
    if (tid < 16) e_sh[tid] = 0.f;
#pragma unroll
    for (int i = 0; i < 12; ++i)
        As4[tid + i * 256] = A4[(size_t)r0 * 192 + tid + i * 256];
    __syncthreads();

    float acc0[16], acc1[16], acc2[16];
#pragma unroll
    for (int m = 0; m < 16; ++m) { acc0[m] = 0.f; acc1[m] = 0.f; acc2[m] = 0.f; }
    const int c0 = tid, c1 = tid + 256, c2 = tid + 512;
    for (int k = 0; k < TOK_DIM; k += 4) {
        const float* Wk = W + (size_t)k * TOK_DIM;
        float w00 = Wk[c0],            w01 = Wk[c1],            w02 = Wk[c2];
        float w10 = Wk[TOK_DIM + c0],  w11 = Wk[TOK_DIM + c1],  w12 = Wk[TOK_DIM + c2];
        float w20 = Wk[2*TOK_DIM + c0],w21 = Wk[2*TOK_DIM + c1],w22 = Wk[2*TOK_DIM + c2];
        float w30 = Wk[3*TOK_DIM + c0],w31 = Wk[3*TOK_DIM + c1],w32 = Wk[3*TOK_DIM + c2];
#pragma unroll
        for (int m = 0; m < 16; ++m) {
            float4 a = As4[m * 192 + (k >> 2)];
            acc0[m] += a.x * w00 + a.y * w10 + a.z * w20 + a.w * w30;
            acc1[m] += a.x * w01 + a.y * w11 + a.z * w21 + a.w * w31;
            acc2[m] += a.x * w02 + a.y * w12 + a.z * w22 + a.w * w32;
        }
    }
    float b0 = bias[c0], b1 = bias[c1], b2 = bias[c2];
    float v0 = v[c0],   v1 = v[c1],   v2 = v[c2];
    int lane = tid & 63;
#pragma unroll
    for (int m = 0; m < 16; ++m) {
        float p = tanhf(acc0[m] + b0) * v0 + tanhf(acc1[m] + b1) * v1 +
                  tanhf(acc2[m] + b2) * v2;
        p += __shfl_xor(p, 32); p += __shfl_xor(p, 16); p += __shfl_xor(p, 8);
        p += __shfl_xor(p, 4);  p += __shfl_xor(p, 2);  p += __shfl_xor(p, 1);
        if (lane == 0) atomicAdd(&e_sh[m], p);
    }
    __syncthreads();
    if (tid < 16) e_out[r0 + tid] = e_sh[tid];
}

// masked softmax over SEQ, pooled = a.h, then linear 768->128. One block per b.
__global__ void tok_pool_kernel(const int* __restrict__ ctx_tok,
                                const float* __restrict__ e_ws,
                                const float* __restrict__ tok_emb,
                                const float* __restrict__ lin_W,
                                const float* __restrict__ lin_b,
                                float* __restrict__ tok_rep) {
    __shared__ float a_s[SEQ];
    __shared__ float pooled[TOK_DIM];
    __shared__ float redm[4];
    __shared__ float reds[4];
    int b = blockIdx.x, tid = threadIdx.x;
    int wave = tid >> 6, lane = tid & 63;
    int t = ctx_tok[b * SEQ + tid];
    float val = (t != 0) ? e_ws[b * SEQ + tid] : -1e9f;
    float mx = val;
    mx = fmaxf(mx, __shfl_xor(mx, 32)); mx = fmaxf(mx, __shfl_xor(mx, 16));
    mx = fmaxf(mx, __shfl_xor(mx, 8));  mx = fmaxf(mx, __shfl_xor(mx, 4));
    mx = fmaxf(mx, __shfl_xor(mx, 2));  mx = fmaxf(mx, __shfl_xor(mx, 1));
    if (lane == 0) redm[wave] = mx;
    __syncthreads();
    mx = fmaxf(fmaxf(redm[0], redm[1]), fmaxf(redm[2], redm[3]));
    float ex = expf(val - mx);
    float sm = ex;
    sm += __shfl_xor(sm, 32); sm += __shfl_xor(sm, 16); sm += __shfl_xor(sm, 8);
    sm += __shfl_xor(sm, 4);  sm += __shfl_xor(sm, 2);  sm += __shfl_xor(sm, 1);
    if (lane == 0) reds[wave] = sm;
    __syncthreads();
    sm = reds[0] + reds[1] + reds[2] + reds[3];
    a_s[tid] = ex / sm;
    __syncthreads();
    const float* emb = tok_emb + (size_t)b * SEQ * TOK_DIM;
    for (int d = tid; d < TOK_DIM; d += 256) {
        float acc = 0.f;
        for (int l = 0; l < SEQ; ++l) acc += a_s[l] * emb[(size_t)l * TOK_DIM + d];
        pooled[d] = acc;
    }
    __syncthreads();
    if (tid < KG_DIM) {
        float s = lin_b[tid];
        const float* wr = lin_W + (size_t)tid * TOK_DIM;
        for (int k = 0; k < TOK_DIM; ++k) s += pooled[k] * wr[k];
        tok_rep[b * KG_DIM + tid] = s;
    }
}

__global__ void gate_kernel(const float* __restrict__ tok_rep,
                            const float* __restrict__ ent_rep,
                            const float* __restrict__ gate_W,
                            const float* __restrict__ gate_b,
                            float* __restrict__ user) {
    __shared__ float tr[KG_DIM], er[KG_DIM];
    int b = blockIdx.x, d = threadIdx.x;  // 128 threads
    tr[d] = tok_rep[b * KG_DIM + d];
    er[d] = ent_rep[b * KG_DIM + d];
    __syncthreads();
    float g = gate_b[d];
    const float* wr = gate_W + (size_t)d * 256;
#pragma unroll 8
    for (int k = 0; k < KG_DIM; ++k) g += tr[k] * wr[k] + er[k] * wr[KG_DIM + k];
    float sig = 1.f / (1.f + expf(-g));
    user[b * KG_DIM + d] = sig * tr[d] + (1.f - sig) * er[d];
}

__global__ void scores_kernel(const float* __restrict__ user,
                              const float4* __restrict__ kg4,
                              float* __restrict__ out) {
    __shared__ float4 u4[BATCH * 32];  // 16 KB
    int tid = threadIdx.x;
    for (int i = tid; i < BATCH * 32; i += 256) u4[i] = ((const float4*)user)[i];
    __syncthreads();
    int n = blockIdx.x * 256 + tid;
    if (n >= N_ENTITY) return;
    float acc[BATCH];
#pragma unroll
    for (int b = 0; b < BATCH; ++b) acc[b] = 0.f;
    for (int d4 = 0; d4 < 32; ++d4) {
        float4 k = kg4[(size_t)n * 32 + d4];
#pragma unroll
        for (int b = 0; b < BATCH; ++b) {
            float4 u = u4[b * 32 + d4];
            acc[b] += k.x * u.x + k.y * u.y + k.z * u.z + k.w * u.w;
        }
    }
    for (int b = 0; b < BATCH; ++b) out[(size_t)b * N_ENTITY + n] = acc[b];
}

extern "C" void kernel_launch(void* const* d_in, const int* in_sizes, int n_in,
                              void* d_out, int out_size, void* d_ws, size_t ws_size,
                              hipStream_t stream) {
    (void)in_sizes; (void)n_in; (void)out_size;
    const int*   ctx_ent   = (const int*)d_in[0];
    const int*   ctx_tok   = (const int*)d_in[1];
    const int*   edge_index= (const int*)d_in[2];
    const int*   edge_type = (const int*)d_in[3];
    const float* tok_emb   = (const float*)d_in[4];
    const float* comp      = (const float*)d_in[5];
    const float* basis     = (const float*)d_in[6];
    const float* root      = (const float*)d_in[7];
    const float* rgcn_bias = (const float*)d_in[8];
    const float* ent_W     = (const float*)d_in[9];
    const float* ent_b     = (const float*)d_in[10];
    const float* ent_v     = (const float*)d_in[11];
    const float* tok_W     = (const float*)d_in[12];
    const float* tok_b     = (const float*)d_in[13];
    const float* tok_v     = (const float*)d_in[14];
    const float* lin_W     = (const float*)d_in[15];
    const float* lin_b     = (const float*)d_in[16];
    const float* gate_W    = (const float*)d_in[17];
    const float* gate_b    = (const float*)d_in[18];
    float* scores = (float*)d_out;

    float* ws = (float*)d_ws;
    float* kg      = ws + OFF_KG;
    int*   cnt     = (int*)(ws + OFF_CNT);
    int*   deg     = (int*)(ws + OFF_DEG);
    int*   start   = (int*)(ws + OFF_START);
    int*   cursor  = (int*)(ws + OFF_CURSOR);
    int*   sr      = (int*)(ws + OFF_SR);
    float* nrm     = ws + OFF_NORM;
    float* e_ws    = ws + OFF_ETOK;
    float* ent_rep = ws + OFF_ENT;
    float* tok_rep = ws + OFF_TOK;
    float* user    = ws + OFF_USER;
    float* weight  = ws + OFF_W;
    const bool use_weight = (ws_size >= NEED_W_BYTES);

    // zero cnt+deg (contiguous: 360000 + 30000 ints)
    zero_kernel<<<(390000 + 255) / 256, 256, 0, stream>>>(cnt, 390000);
    count_kernel<<<(N_EDGES + 255) / 256, 256, 0, stream>>>(edge_index, edge_type, cnt, deg);
    scan_kernel<<<1, 1024, 0, stream>>>(deg, start, cursor);
    place_kernel<<<(N_EDGES + 255) / 256, 256, 0, stream>>>(edge_index, edge_type, cnt,
                                                            cursor, sr, nrm);
    if (use_weight) {
        weight_kernel<<<3750, 256, 0, stream>>>(comp, (const float4*)basis, (float4*)weight);
        gather_kernel<<<(N_ENTITY + 3) / 4, 256, 0, stream>>>(
            start, deg, sr, nrm, (const float2*)weight, (const float2*)root,
            (const float2*)rgcn_bias, (float2*)kg);
    } else {
        gather_otf_kernel<<<(N_ENTITY + 3) / 4, 256, 0, stream>>>(
            start, deg, sr, nrm, comp, (const float2*)basis, (const float2*)root,
            (const float2*)rgcn_bias, (float2*)kg);
    }
    ent_attn_kernel<<<BATCH, 256, 0, stream>>>(ctx_ent, kg, ent_W, ent_b, ent_v, ent_rep);
    tok_e_kernel<<<(BATCH * SEQ) / 16, 256, 0, stream>>>((const float4*)tok_emb, tok_W,
                                                         tok_b, tok_v, e_ws);
    tok_pool_kernel<<<BATCH, 256, 0, stream>>>(ctx_tok, e_ws, tok_emb, lin_W, lin_b, tok_rep);
    gate_kernel<<<BATCH, 128, 0, stream>>>(tok_rep, ent_rep, gate_W, gate_b, user);
    scores_kernel<<<(N_ENTITY + 255) / 256, 256, 0, stream>>>(user, (const float4*)kg, scores);
}

// Round 3
// 648.193 us; speedup vs baseline: 2.0424x; 1.2499x over previous
//
#include <hip/hip_runtime.h>
#include <hip/hip_bf16.h>
#include <math.h>

#define N_ENTITY 30000
#define N_REL    12
#define N_BASES  8
#define KG_DIM   128
#define TOK_DIM  768
#define BATCH    32
#define N_CTX    50
#define SEQ      256
#define N_EDGES  400000

// ---------------- workspace layout (in floats, all 16B-aligned) ----------------
#define OFF_KG     0           // 3,840,000
#define OFF_CNT    3840000     // 360,000 ints
#define OFF_DEG    4200000     // 30,000 ints
#define OFF_START  4230000     // 30,004 ints (N+1 used)
#define OFF_CURSOR 4260004     // 30,000 ints
#define OFF_SR     4290004     // 400,000 ints (packed src|r<<15)
#define OFF_NORM   4690004     // 400,000 floats
#define OFF_ETOK   5090004     // 8,192
#define OFF_ENT    5098196     // 4,096
#define OFF_TOK    5102292     // 4,096
#define OFF_USER   5106388     // 4,096
// bf16 buffers OVERLAY the weight region (weight is consumed by gather before
// these are written; stream order guarantees no hazard).
#define OFF_W      5110484     // weight: 46,080,000 floats
#define OFF_ABF    5110484     // 6,291,456 bf16 = 3,145,728 floats
#define OFF_WBF    8256212     // 589,824 bf16 = 294,912 floats (ends 8,551,124)
#define NEED_W_BYTES ((size_t)(OFF_W + 46080000) * 4)

typedef __bf16 bf16x8 __attribute__((ext_vector_type(8)));
typedef float  floatx4 __attribute__((ext_vector_type(4)));

__device__ __forceinline__ float tanh_fast(float x) {
    float ax = fabsf(x);
    float e = __expf(-2.0f * ax);
    float t = 1.0f - 2.0f * e / (1.0f + e);
    return copysignf(t, x);
}

__global__ void zero_kernel(int* __restrict__ p, int n) {
    int i = blockIdx.x * 256 + threadIdx.x;
    if (i < n) p[i] = 0;
}

// per-(r,dst) count and per-dst degree
__global__ void count_kernel(const int* __restrict__ edge_index,
                             const int* __restrict__ edge_type,
                             int* __restrict__ cnt,
                             int* __restrict__ deg) {
    int e = blockIdx.x * 256 + threadIdx.x;
    if (e >= N_EDGES) return;
    int r = edge_type[e];
    int dst = edge_index[N_EDGES + e];
    atomicAdd(&cnt[r * N_ENTITY + dst], 1);
    atomicAdd(&deg[dst], 1);
}

// single-block exclusive scan of deg -> start, also copies to cursor
__global__ __launch_bounds__(1024) void scan_kernel(const int* __restrict__ deg,
                                                    int* __restrict__ start,
                                                    int* __restrict__ cursor) {
    __shared__ int buf[1024];
    __shared__ int carry;
    int tid = threadIdx.x;
    if (tid == 0) carry = 0;
    __syncthreads();
    for (int base = 0; base < N_ENTITY; base += 1024) {
        int i = base + tid;
        int v = (i < N_ENTITY) ? deg[i] : 0;
        buf[tid] = v;
        __syncthreads();
        for (int off = 1; off < 1024; off <<= 1) {
            int t = (tid >= off) ? buf[tid - off] : 0;
            __syncthreads();
            buf[tid] += t;
            __syncthreads();
        }
        if (i < N_ENTITY) {
            int ex = carry + buf[tid] - v;
            start[i] = ex;
            cursor[i] = ex;
        }
        __syncthreads();
        if (tid == 1023) carry += buf[1023];
        __syncthreads();
    }
    if (tid == 0) start[N_ENTITY] = carry;
}

__global__ void place_kernel(const int* __restrict__ edge_index,
                             const int* __restrict__ edge_type,
                             const int* __restrict__ cnt,
                             int* __restrict__ cursor,
                             int* __restrict__ sr,
                             float* __restrict__ nrm) {
    int e = blockIdx.x * 256 + threadIdx.x;
    if (e >= N_EDGES) return;
    int r = edge_type[e];
    int src = edge_index[e];
    int dst = edge_index[N_EDGES + e];
    int c = cnt[r * N_ENTITY + dst];
    int slot = atomicAdd(&cursor[dst], 1);
    sr[slot] = src | (r << 15);
    nrm[slot] = 1.0f / (float)(c > 1 ? c : 1);
}

// weight[r,n,d] = sum_b comp[r,b] * basis[b,n,d]
__global__ void weight_kernel(const float* __restrict__ comp,
                              const float4* __restrict__ basis4,
                              float4* __restrict__ weight4) {
    int idx = blockIdx.x * 256 + threadIdx.x;  // over N_ENTITY*KG_DIM/4 = 960000
    float4 bv[N_BASES];
#pragma unroll
    for (int b = 0; b < N_BASES; ++b) bv[b] = basis4[(size_t)b * 960000 + idx];
#pragma unroll
    for (int r = 0; r < N_REL; ++r) {
        float4 w = make_float4(0.f, 0.f, 0.f, 0.f);
#pragma unroll
        for (int b = 0; b < N_BASES; ++b) {
            float c = comp[r * N_BASES + b];
            w.x += c * bv[b].x; w.y += c * bv[b].y;
            w.z += c * bv[b].z; w.w += c * bv[b].w;
        }
        weight4[(size_t)r * 960000 + idx] = w;
    }
}

// one wave per dst entity; lane owns dims [2*lane, 2*lane+1]
__global__ __launch_bounds__(256) void gather_kernel(const int* __restrict__ start,
                                                     const int* __restrict__ deg,
                                                     const int* __restrict__ sr,
                                                     const float* __restrict__ nrm,
                                                     const float2* __restrict__ w2,
                                                     const float2* __restrict__ root2,
                                                     const float2* __restrict__ bias2,
                                                     float2* __restrict__ kg2) {
    int wv = threadIdx.x >> 6, lane = threadIdx.x & 63;
    int dst = blockIdx.x * 4 + wv;
    if (dst >= N_ENTITY) return;
    int s = start[dst], n = deg[dst];
    float ax = 0.f, ay = 0.f;
    int j = 0;
    for (; j + 1 < n; j += 2) {
        int p0 = sr[s + j], p1 = sr[s + j + 1];
        float n0 = nrm[s + j], n1 = nrm[s + j + 1];
        int s0 = p0 & 32767, r0 = p0 >> 15;
        int s1 = p1 & 32767, r1 = p1 >> 15;
        float2 w0 = w2[((size_t)(r0 * N_ENTITY + s0)) * 64 + lane];
        float2 w1 = w2[((size_t)(r1 * N_ENTITY + s1)) * 64 + lane];
        ax += w0.x * n0 + w1.x * n1;
        ay += w0.y * n0 + w1.y * n1;
    }
    if (j < n) {
        int p0 = sr[s + j];
        float n0 = nrm[s + j];
        int s0 = p0 & 32767, r0 = p0 >> 15;
        float2 w0 = w2[((size_t)(r0 * N_ENTITY + s0)) * 64 + lane];
        ax += w0.x * n0;
        ay += w0.y * n0;
    }
    float2 rt = root2[(size_t)dst * 64 + lane];
    float2 bs = bias2[lane];
    kg2[(size_t)dst * 64 + lane] = make_float2(ax + rt.x + bs.x, ay + rt.y + bs.y);
}

// fallback: compute message from basis on the fly (no weight buffer)
__global__ __launch_bounds__(256) void gather_otf_kernel(const int* __restrict__ start,
                                                         const int* __restrict__ deg,
                                                         const int* __restrict__ sr,
                                                         const float* __restrict__ nrm,
                                                         const float* __restrict__ comp,
                                                         const float2* __restrict__ basis2,
                                                         const float2* __restrict__ root2,
                                                         const float2* __restrict__ bias2,
                                                         float2* __restrict__ kg2) {
    int wv = threadIdx.x >> 6, lane = threadIdx.x & 63;
    int dst = blockIdx.x * 4 + wv;
    if (dst >= N_ENTITY) return;
    int s = start[dst], n = deg[dst];
    float ax = 0.f, ay = 0.f;
    for (int j = 0; j < n; ++j) {
        int p = sr[s + j];
        float nm = nrm[s + j];
        int src = p & 32767, r = p >> 15;
        float mx = 0.f, my = 0.f;
#pragma unroll
        for (int b = 0; b < N_BASES; ++b) {
            float cf = comp[r * N_BASES + b];
            float2 bs = basis2[((size_t)b * N_ENTITY + src) * 64 + lane];
            mx += cf * bs.x; my += cf * bs.y;
        }
        ax += mx * nm; ay += my * nm;
    }
    float2 rt = root2[(size_t)dst * 64 + lane];
    float2 bs = bias2[lane];
    kg2[(size_t)dst * 64 + lane] = make_float2(ax + rt.x + bs.x, ay + rt.y + bs.y);
}

// entity self-dot attention pool: one block per batch element
__global__ void ent_attn_kernel(const int* __restrict__ ctx_ent,
                                const float* __restrict__ kg,
                                const float* __restrict__ W,
                                const float* __restrict__ bb,
                                const float* __restrict__ v,
                                float* __restrict__ ent_rep) {
    __shared__ float h[N_CTX * KG_DIM];  // 25.6 KB
    __shared__ float es[64];
    __shared__ int ids[N_CTX];
    int b = blockIdx.x, tid = threadIdx.x;
    if (tid < N_CTX) ids[tid] = ctx_ent[b * N_CTX + tid];
    __syncthreads();
    for (int i = tid; i < N_CTX * KG_DIM; i += 256) {
        int l = i >> 7, d = i & 127;
        h[i] = kg[(size_t)ids[l] * KG_DIM + d];
    }
    __syncthreads();

    int wave = tid >> 6, lane = tid & 63;
    const int nl = (N_CTX - wave + 3) / 4;
    float s0[13], s1[13];
#pragma unroll
    for (int i = 0; i < 13; ++i) { s0[i] = 0.f; s1[i] = 0.f; }
    for (int k = 0; k < KG_DIM; ++k) {
        float w0 = W[k * KG_DIM + lane];
        float w1 = W[k * KG_DIM + lane + 64];
#pragma unroll
        for (int i = 0; i < 13; ++i) {
            if (i < nl) {
                float hk = h[(wave + i * 4) * KG_DIM + k];
                s0[i] += hk * w0;
                s1[i] += hk * w1;
            }
        }
    }
    float bias0 = bb[lane], bias1 = bb[lane + 64];
    float v0 = v[lane], v1 = v[lane + 64];
    for (int i = 0; i < nl; ++i) {
        int l = wave + i * 4;
        float p = tanhf(s0[i] + bias0) * v0 + tanhf(s1[i] + bias1) * v1;
        p += __shfl_xor(p, 32); p += __shfl_xor(p, 16); p += __shfl_xor(p, 8);
        p += __shfl_xor(p, 4);  p += __shfl_xor(p, 2);  p += __shfl_xor(p, 1);
        if (lane == 0) es[l] = p;
    }
    __syncthreads();
    if (tid < 64) {
        float val = (tid < N_CTX && ids[tid] != 0) ? es[tid] : -1e9f;
        float mx = val;
        mx = fmaxf(mx, __shfl_xor(mx, 32)); mx = fmaxf(mx, __shfl_xor(mx, 16));
        mx = fmaxf(mx, __shfl_xor(mx, 8));  mx = fmaxf(mx, __shfl_xor(mx, 4));
        mx = fmaxf(mx, __shfl_xor(mx, 2));  mx = fmaxf(mx, __shfl_xor(mx, 1));
        float ex = (tid < N_CTX) ? expf(val - mx) : 0.f;
        float sm = ex;
        sm += __shfl_xor(sm, 32); sm += __shfl_xor(sm, 16); sm += __shfl_xor(sm, 8);
        sm += __shfl_xor(sm, 4);  sm += __shfl_xor(sm, 2);  sm += __shfl_xor(sm, 1);
        if (tid < N_CTX) es[tid] = ex / sm;
    }
    __syncthreads();
    if (tid < KG_DIM) {
        float o = 0.f;
#pragma unroll
        for (int l = 0; l < N_CTX; ++l) o += es[l] * h[l * KG_DIM + tid];
        ent_rep[b * KG_DIM + tid] = o;
    }
}

// ---------------- tok path: bf16 conversion + MFMA GEMM ----------------

// fp32 -> bf16, 8 elems/thread
__global__ void convA_kernel(const float* __restrict__ in, __bf16* __restrict__ out,
                             int n8) {
    int i = blockIdx.x * 256 + threadIdx.x;
    if (i >= n8) return;
    const float4* p = (const float4*)(in + (size_t)i * 8);
    float4 a = p[0], b = p[1];
    union { __bf16 h[8]; uint4 u; } r;
    r.h[0] = (__bf16)a.x; r.h[1] = (__bf16)a.y; r.h[2] = (__bf16)a.z; r.h[3] = (__bf16)a.w;
    r.h[4] = (__bf16)b.x; r.h[5] = (__bf16)b.y; r.h[6] = (__bf16)b.z; r.h[7] = (__bf16)b.w;
    *(uint4*)(out + (size_t)i * 8) = r.u;
}

// Wt[c][k] = (bf16) W[k][c] : 64x64 LDS tile transpose, grid (12,12)
__global__ void convWT_kernel(const float* __restrict__ W, __bf16* __restrict__ Wt) {
    __shared__ float tile[64][65];
    int tx = threadIdx.x & 63, ty = threadIdx.x >> 6;
    int kb = blockIdx.x * 64, cb = blockIdx.y * 64;
#pragma unroll
    for (int i = 0; i < 16; ++i) {
        int r = ty + i * 4;
        tile[r][tx] = W[(size_t)(kb + r) * TOK_DIM + cb + tx];
    }
    __syncthreads();
#pragma unroll
    for (int i = 0; i < 16; ++i) {
        int r = ty + i * 4;
        Wt[(size_t)(cb + r) * TOK_DIM + kb + tx] = (__bf16)tile[tx][r];
    }
}

// Z = A[8192x768] x W[768x768] in bf16 MFMA, epilogue computes
// e[row] += sum_c v[c]*tanh(Z[row,c]+bias[c]) for this block's 128 cols.
// Block 256 thr = 4 waves (2x2 of 64x64), tile 128x128, BK=32.
__global__ __launch_bounds__(256) void tok_gemm_kernel(const __bf16* __restrict__ A,
                                                       const __bf16* __restrict__ Bt,
                                                       const float* __restrict__ bias,
                                                       const float* __restrict__ v,
                                                       float* __restrict__ e_out) {
    __shared__ __align__(16) __bf16 sA[4096];  // [kpart][row][8] : kpart*1024+row*8
    __shared__ __align__(16) __bf16 sB[4096];  // [kpart][col][8]
    int tid = threadIdx.x;
    int wave = tid >> 6, lane = tid & 63;
    int wm = wave >> 1, wn = wave & 1;
    int quad = lane >> 4, idx = lane & 15;
    int m0 = blockIdx.y * 128, c0 = blockIdx.x * 128;

    // staging: flat f = tid (kpart=tid>>7,row=tid&127) and f+256 (kpart+2)
    int rowS = tid & 127, kpS = tid >> 7;
    const __bf16* gA0 = A + (size_t)(m0 + rowS) * TOK_DIM + kpS * 8;
    const __bf16* gA1 = gA0 + 16;  // kpart+2 -> +16 elems
    const __bf16* gB0 = Bt + (size_t)(c0 + rowS) * TOK_DIM + kpS * 8;
    const __bf16* gB1 = gB0 + 16;
    __bf16* dA0 = &sA[tid * 8];
    __bf16* dA1 = &sA[tid * 8 + 2048];
    __bf16* dB0 = &sB[tid * 8];
    __bf16* dB1 = &sB[tid * 8 + 2048];

    floatx4 acc[4][4];
#pragma unroll
    for (int mi = 0; mi < 4; ++mi)
#pragma unroll
        for (int ni = 0; ni < 4; ++ni)
            acc[mi][ni] = (floatx4){0.f, 0.f, 0.f, 0.f};

    for (int k0 = 0; k0 < TOK_DIM; k0 += 32) {
        uint4 ra0 = *(const uint4*)(gA0 + k0);
        uint4 ra1 = *(const uint4*)(gA1 + k0);
        uint4 rb0 = *(const uint4*)(gB0 + k0);
        uint4 rb1 = *(const uint4*)(gB1 + k0);
        __syncthreads();
        *(uint4*)dA0 = ra0; *(uint4*)dA1 = ra1;
        *(uint4*)dB0 = rb0; *(uint4*)dB1 = rb1;
        __syncthreads();
        bf16x8 aF[4], bF[4];
#pragma unroll
        for (int i = 0; i < 4; ++i) {
            aF[i] = *(const bf16x8*)&sA[quad * 1024 + (wm * 64 + i * 16 + idx) * 8];
            bF[i] = *(const bf16x8*)&sB[quad * 1024 + (wn * 64 + i * 16 + idx) * 8];
        }
#pragma unroll
        for (int mi = 0; mi < 4; ++mi)
#pragma unroll
            for (int ni = 0; ni < 4; ++ni)
                acc[mi][ni] = __builtin_amdgcn_mfma_f32_16x16x32_bf16(
                    aF[mi], bF[ni], acc[mi][ni], 0, 0, 0);
    }

    // epilogue: p = tanh(z + bias[c]) * v[c]; reduce over this block's cols
    float bv[4], vv[4];
#pragma unroll
    for (int ni = 0; ni < 4; ++ni) {
        int c = c0 + wn * 64 + ni * 16 + idx;
        bv[ni] = bias[c]; vv[ni] = v[c];
    }
#pragma unroll
    for (int mi = 0; mi < 4; ++mi) {
        float s[4] = {0.f, 0.f, 0.f, 0.f};
#pragma unroll
        for (int ni = 0; ni < 4; ++ni)
#pragma unroll
            for (int r = 0; r < 4; ++r)
                s[r] += tanh_fast(acc[mi][ni][r] + bv[ni]) * vv[ni];
#pragma unroll
        for (int r = 0; r < 4; ++r) {
            s[r] += __shfl_xor(s[r], 1); s[r] += __shfl_xor(s[r], 2);
            s[r] += __shfl_xor(s[r], 4); s[r] += __shfl_xor(s[r], 8);
        }
        if (idx == 0) {
            int rbase = m0 + wm * 64 + mi * 16 + quad * 4;
#pragma unroll
            for (int r = 0; r < 4; ++r) atomicAdd(&e_out[rbase + r], s[r]);
        }
    }
}

// masked softmax over SEQ, pooled = a.h, then linear 768->128. One block per b.
__global__ void tok_pool_kernel(const int* __restrict__ ctx_tok,
                                const float* __restrict__ e_ws,
                                const float* __restrict__ tok_emb,
                                const float* __restrict__ lin_W,
                                const float* __restrict__ lin_b,
                                float* __restrict__ tok_rep) {
    __shared__ float a_s[SEQ];
    __shared__ float pooled[TOK_DIM];
    __shared__ float redm[4];
    __shared__ float reds[4];
    int b = blockIdx.x, tid = threadIdx.x;
    int wave = tid >> 6, lane = tid & 63;
    int t = ctx_tok[b * SEQ + tid];
    float val = (t != 0) ? e_ws[b * SEQ + tid] : -1e9f;
    float mx = val;
    mx = fmaxf(mx, __shfl_xor(mx, 32)); mx = fmaxf(mx, __shfl_xor(mx, 16));
    mx = fmaxf(mx, __shfl_xor(mx, 8));  mx = fmaxf(mx, __shfl_xor(mx, 4));
    mx = fmaxf(mx, __shfl_xor(mx, 2));  mx = fmaxf(mx, __shfl_xor(mx, 1));
    if (lane == 0) redm[wave] = mx;
    __syncthreads();
    mx = fmaxf(fmaxf(redm[0], redm[1]), fmaxf(redm[2], redm[3]));
    float ex = expf(val - mx);
    float sm = ex;
    sm += __shfl_xor(sm, 32); sm += __shfl_xor(sm, 16); sm += __shfl_xor(sm, 8);
    sm += __shfl_xor(sm, 4);  sm += __shfl_xor(sm, 2);  sm += __shfl_xor(sm, 1);
    if (lane == 0) reds[wave] = sm;
    __syncthreads();
    sm = reds[0] + reds[1] + reds[2] + reds[3];
    a_s[tid] = ex / sm;
    __syncthreads();
    const float* emb = tok_emb + (size_t)b * SEQ * TOK_DIM;
    for (int d = tid; d < TOK_DIM; d += 256) {
        float acc = 0.f;
        for (int l = 0; l < SEQ; ++l) acc += a_s[l] * emb[(size_t)l * TOK_DIM + d];
        pooled[d] = acc;
    }
    __syncthreads();
    if (tid < KG_DIM) {
        float s = lin_b[tid];
        const float* wr = lin_W + (size_t)tid * TOK_DIM;
        for (int k = 0; k < TOK_DIM; ++k) s += pooled[k] * wr[k];
        tok_rep[b * KG_DIM + tid] = s;
    }
}

__global__ void gate_kernel(const float* __restrict__ tok_rep,
                            const float* __restrict__ ent_rep,
                            const float* __restrict__ gate_W,
                            const float* __restrict__ gate_b,
                            float* __restrict__ user) {
    __shared__ float tr[KG_DIM], er[KG_DIM];
    int b = blockIdx.x, d = threadIdx.x;  // 128 threads
    tr[d] = tok_rep[b * KG_DIM + d];
    er[d] = ent_rep[b * KG_DIM + d];
    __syncthreads();
    float g = gate_b[d];
    const float* wr = gate_W + (size_t)d * 256;
#pragma unroll 8
    for (int k = 0; k < KG_DIM; ++k) g += tr[k] * wr[k] + er[k] * wr[KG_DIM + k];
    float sig = 1.f / (1.f + expf(-g));
    user[b * KG_DIM + d] = sig * tr[d] + (1.f - sig) * er[d];
}

__global__ void scores_kernel(const float* __restrict__ user,
                              const float4* __restrict__ kg4,
                              float* __restrict__ out) {
    __shared__ float4 u4[BATCH * 32];  // 16 KB
    int tid = threadIdx.x;
    for (int i = tid; i < BATCH * 32; i += 256) u4[i] = ((const float4*)user)[i];
    __syncthreads();
    int n = blockIdx.x * 256 + tid;
    if (n >= N_ENTITY) return;
    float acc[BATCH];
#pragma unroll
    for (int b = 0; b < BATCH; ++b) acc[b] = 0.f;
    for (int d4 = 0; d4 < 32; ++d4) {
        float4 k = kg4[(size_t)n * 32 + d4];
#pragma unroll
        for (int b = 0; b < BATCH; ++b) {
            float4 u = u4[b * 32 + d4];
            acc[b] += k.x * u.x + k.y * u.y + k.z * u.z + k.w * u.w;
        }
    }
    for (int b = 0; b < BATCH; ++b) out[(size_t)b * N_ENTITY + n] = acc[b];
}

extern "C" void kernel_launch(void* const* d_in, const int* in_sizes, int n_in,
                              void* d_out, int out_size, void* d_ws, size_t ws_size,
                              hipStream_t stream) {
    (void)in_sizes; (void)n_in; (void)out_size;
    const int*   ctx_ent   = (const int*)d_in[0];
    const int*   ctx_tok   = (const int*)d_in[1];
    const int*   edge_index= (const int*)d_in[2];
    const int*   edge_type = (const int*)d_in[3];
    const float* tok_emb   = (const float*)d_in[4];
    const float* comp      = (const float*)d_in[5];
    const float* basis     = (const float*)d_in[6];
    const float* root      = (const float*)d_in[7];
    const float* rgcn_bias = (const float*)d_in[8];
    const float* ent_W     = (const float*)d_in[9];
    const float* ent_b     = (const float*)d_in[10];
    const float* ent_v     = (const float*)d_in[11];
    const float* tok_W     = (const float*)d_in[12];
    const float* tok_b     = (const float*)d_in[13];
    const float* tok_v     = (const float*)d_in[14];
    const float* lin_W     = (const float*)d_in[15];
    const float* lin_b     = (const float*)d_in[16];
    const float* gate_W    = (const float*)d_in[17];
    const float* gate_b    = (const float*)d_in[18];
    float* scores = (float*)d_out;

    float* ws = (float*)d_ws;
    float* kg      = ws + OFF_KG;
    int*   cnt     = (int*)(ws + OFF_CNT);
    int*   deg     = (int*)(ws + OFF_DEG);
    int*   start   = (int*)(ws + OFF_START);
    int*   cursor  = (int*)(ws + OFF_CURSOR);
    int*   sr      = (int*)(ws + OFF_SR);
    float* nrm     = ws + OFF_NORM;
    float* e_ws    = ws + OFF_ETOK;
    float* ent_rep = ws + OFF_ENT;
    float* tok_rep = ws + OFF_TOK;
    float* user    = ws + OFF_USER;
    float* weight  = ws + OFF_W;
    __bf16* Abf    = (__bf16*)(ws + OFF_ABF);
    __bf16* Wbf    = (__bf16*)(ws + OFF_WBF);
    const bool use_weight = (ws_size >= NEED_W_BYTES);

    // ---- RGCN: sort edges by dst, materialize weight, gather ----
    zero_kernel<<<(390000 + 255) / 256, 256, 0, stream>>>(cnt, 390000);
    count_kernel<<<(N_EDGES + 255) / 256, 256, 0, stream>>>(edge_index, edge_type, cnt, deg);
    scan_kernel<<<1, 1024, 0, stream>>>(deg, start, cursor);
    place_kernel<<<(N_EDGES + 255) / 256, 256, 0, stream>>>(edge_index, edge_type, cnt,
                                                            cursor, sr, nrm);
    if (use_weight) {
        weight_kernel<<<3750, 256, 0, stream>>>(comp, (const float4*)basis, (float4*)weight);
        gather_kernel<<<(N_ENTITY + 3) / 4, 256, 0, stream>>>(
            start, deg, sr, nrm, (const float2*)weight, (const float2*)root,
            (const float2*)rgcn_bias, (float2*)kg);
    } else {
        gather_otf_kernel<<<(N_ENTITY + 3) / 4, 256, 0, stream>>>(
            start, deg, sr, nrm, comp, (const float2*)basis, (const float2*)root,
            (const float2*)rgcn_bias, (float2*)kg);
    }
    ent_attn_kernel<<<BATCH, 256, 0, stream>>>(ctx_ent, kg, ent_W, ent_b, ent_v, ent_rep);

    // ---- tok path: bf16 convert (overlays weight region; gather is done) ----
    convA_kernel<<<(BATCH * SEQ * TOK_DIM / 8 + 255) / 256, 256, 0, stream>>>(
        tok_emb, Abf, BATCH * SEQ * TOK_DIM / 8);
    {
        dim3 g(12, 12);
        convWT_kernel<<<g, 256, 0, stream>>>(tok_W, Wbf);
    }
    zero_kernel<<<32, 256, 0, stream>>>((int*)e_ws, BATCH * SEQ);
    {
        dim3 g(TOK_DIM / 128, BATCH * SEQ / 128);  // (6, 64)
        tok_gemm_kernel<<<g, 256, 0, stream>>>(Abf, Wbf, tok_b, tok_v, e_ws);
    }
    tok_pool_kernel<<<BATCH, 256, 0, stream>>>(ctx_tok, e_ws, tok_emb, lin_W, lin_b, tok_rep);
    gate_kernel<<<BATCH, 128, 0, stream>>>(tok_rep, ent_rep, gate_W, gate_b, user);
    scores_kernel<<<(N_ENTITY + 255) / 256, 256, 0, stream>>>(user, (const float4*)kg, scores);
}

// Round 4
// 569.019 us; speedup vs baseline: 2.3265x; 1.1391x over previous
//
#include <hip/hip_runtime.h>
#include <hip/hip_bf16.h>
#include <math.h>

#define N_ENTITY 30000
#define N_REL    12
#define N_BASES  8
#define KG_DIM   128
#define TOK_DIM  768
#define BATCH    32
#define N_CTX    50
#define SEQ      256
#define N_EDGES  400000

// ---------------- workspace layout (in floats, all 16B-aligned) ----------------
#define OFF_KG     0           // 3,840,000
#define OFF_CNT    3840000     // 360,000 ints
#define OFF_DEG    4200000     // 30,000 ints
#define OFF_START  4230000     // 30,004 ints (N+1 used)
#define OFF_CURSOR 4260004     // 30,000 ints
#define OFF_SR     4290004     // 400,000 ints (packed src|r<<15)
#define OFF_NORM   4690004     // 400,000 floats
#define OFF_ETOK   5090004     // 8,192 (e_ws, then softmax a in-place)
#define OFF_ENT    5098196     // 4,096
#define OFF_TOK    5102292     // 4,096
#define OFF_USER   5106388     // 4,096
// weight (bf16, 92.16 MB = 23,040,000 floats) overlaid later by bf16 tok bufs
#define OFF_W      5110484
#define OFF_ABF    5110484     // 6,291,456 bf16 = 3,145,728 floats
#define OFF_WBF    8256212     // 589,824 bf16 = 294,912 floats
#define NEED_W_BYTES ((size_t)(OFF_W + 23040000) * 4)

typedef __bf16 bf16x8 __attribute__((ext_vector_type(8)));
typedef float  floatx4 __attribute__((ext_vector_type(4)));

__device__ __forceinline__ float tanh_fast(float x) {
    float ax = fabsf(x);
    float e = __expf(-2.0f * ax);
    float t = 1.0f - 2.0f * e / (1.0f + e);
    return copysignf(t, x);
}

__global__ void zero_kernel(int* __restrict__ p, int n) {
    int i = blockIdx.x * 256 + threadIdx.x;
    if (i < n) p[i] = 0;
}

// per-(r,dst) count and per-dst degree
__global__ void count_kernel(const int* __restrict__ edge_index,
                             const int* __restrict__ edge_type,
                             int* __restrict__ cnt,
                             int* __restrict__ deg) {
    int e = blockIdx.x * 256 + threadIdx.x;
    if (e >= N_EDGES) return;
    int r = edge_type[e];
    int dst = edge_index[N_EDGES + e];
    atomicAdd(&cnt[r * N_ENTITY + dst], 1);
    atomicAdd(&deg[dst], 1);
}

// single-block exclusive scan of deg -> start/cursor, shuffle-based (few syncs)
__global__ __launch_bounds__(1024) void scan_kernel(const int* __restrict__ deg,
                                                    int* __restrict__ start,
                                                    int* __restrict__ cursor) {
    __shared__ int wsum[16];
    __shared__ int carry_s;
    int tid = threadIdx.x, lane = tid & 63, wv = tid >> 6;
    if (tid == 0) carry_s = 0;
    __syncthreads();
    for (int base = 0; base < N_ENTITY; base += 1024) {
        int i = base + tid;
        int v = (i < N_ENTITY) ? deg[i] : 0;
        int x = v;
#pragma unroll
        for (int off = 1; off < 64; off <<= 1) {
            int t = __shfl_up(x, off);
            if (lane >= off) x += t;
        }
        if (lane == 63) wsum[wv] = x;
        __syncthreads();
        if (wv == 0 && lane < 16) {
            int w = wsum[lane];
#pragma unroll
            for (int off = 1; off < 16; off <<= 1) {
                int t = __shfl_up(w, off);
                if (lane >= off) w += t;
            }
            wsum[lane] = w;  // inclusive
        }
        __syncthreads();
        int carry = carry_s;
        int wbase = (wv == 0) ? 0 : wsum[wv - 1];
        if (i < N_ENTITY) {
            int ex = carry + wbase + x - v;
            start[i] = ex;
            cursor[i] = ex;
        }
        __syncthreads();
        if (tid == 1023) carry_s = carry + wsum[15];
        __syncthreads();
    }
    if (tid == 0) start[N_ENTITY] = carry_s;
}

__global__ void place_kernel(const int* __restrict__ edge_index,
                             const int* __restrict__ edge_type,
                             const int* __restrict__ cnt,
                             int* __restrict__ cursor,
                             int* __restrict__ sr,
                             float* __restrict__ nrm) {
    int e = blockIdx.x * 256 + threadIdx.x;
    if (e >= N_EDGES) return;
    int r = edge_type[e];
    int src = edge_index[e];
    int dst = edge_index[N_EDGES + e];
    int c = cnt[r * N_ENTITY + dst];
    int slot = atomicAdd(&cursor[dst], 1);
    sr[slot] = src | (r << 15);
    nrm[slot] = 1.0f / (float)(c > 1 ? c : 1);
}

// weight_bf16[r,n,d] = (bf16) sum_b comp[r,b] * basis[b,n,d]; 8 dims/thread
__global__ void weight_bf16_kernel(const float* __restrict__ comp,
                                   const float4* __restrict__ basis4,
                                   uint4* __restrict__ w4) {
    int idx = blockIdx.x * 256 + threadIdx.x;  // over N_ENTITY*KG_DIM/8 = 480000
    float4 a[N_BASES], b[N_BASES];
#pragma unroll
    for (int i = 0; i < N_BASES; ++i) {
        a[i] = basis4[(size_t)i * 960000 + idx * 2];
        b[i] = basis4[(size_t)i * 960000 + idx * 2 + 1];
    }
#pragma unroll
    for (int r = 0; r < N_REL; ++r) {
        float s[8] = {0.f, 0.f, 0.f, 0.f, 0.f, 0.f, 0.f, 0.f};
#pragma unroll
        for (int i = 0; i < N_BASES; ++i) {
            float c = comp[r * N_BASES + i];
            s[0] += c * a[i].x; s[1] += c * a[i].y;
            s[2] += c * a[i].z; s[3] += c * a[i].w;
            s[4] += c * b[i].x; s[5] += c * b[i].y;
            s[6] += c * b[i].z; s[7] += c * b[i].w;
        }
        union { __bf16 h[8]; uint4 u; } pk;
#pragma unroll
        for (int j = 0; j < 8; ++j) pk.h[j] = (__bf16)s[j];
        w4[(size_t)r * 480000 + idx] = pk.u;
    }
}

// one wave per dst entity; lane owns dims [2*lane, 2*lane+1] (one uint of bf16x2)
__global__ __launch_bounds__(256) void gather_kernel(const int* __restrict__ start,
                                                     const int* __restrict__ deg,
                                                     const int* __restrict__ sr,
                                                     const float* __restrict__ nrm,
                                                     const unsigned int* __restrict__ w,
                                                     const float2* __restrict__ root2,
                                                     const float2* __restrict__ bias2,
                                                     float2* __restrict__ kg2) {
    int wv = threadIdx.x >> 6, lane = threadIdx.x & 63;
    int dst = blockIdx.x * 4 + wv;
    if (dst >= N_ENTITY) return;
    int s = start[dst], n = deg[dst];
    float ax = 0.f, ay = 0.f;
    int j = 0;
    for (; j + 1 < n; j += 2) {
        int p0 = sr[s + j], p1 = sr[s + j + 1];
        float n0 = nrm[s + j], n1 = nrm[s + j + 1];
        int s0 = p0 & 32767, r0 = p0 >> 15;
        int s1 = p1 & 32767, r1 = p1 >> 15;
        unsigned int u0 = w[((size_t)(r0 * N_ENTITY + s0) << 6) + lane];
        unsigned int u1 = w[((size_t)(r1 * N_ENTITY + s1) << 6) + lane];
        ax += __uint_as_float(u0 << 16) * n0 + __uint_as_float(u1 << 16) * n1;
        ay += __uint_as_float(u0 & 0xffff0000u) * n0 +
              __uint_as_float(u1 & 0xffff0000u) * n1;
    }
    if (j < n) {
        int p0 = sr[s + j];
        float n0 = nrm[s + j];
        int s0 = p0 & 32767, r0 = p0 >> 15;
        unsigned int u0 = w[((size_t)(r0 * N_ENTITY + s0) << 6) + lane];
        ax += __uint_as_float(u0 << 16) * n0;
        ay += __uint_as_float(u0 & 0xffff0000u) * n0;
    }
    float2 rt = root2[(size_t)dst * 64 + lane];
    float2 bs = bias2[lane];
    kg2[(size_t)dst * 64 + lane] = make_float2(ax + rt.x + bs.x, ay + rt.y + bs.y);
}

// fallback: compute message from basis on the fly (no weight buffer)
__global__ __launch_bounds__(256) void gather_otf_kernel(const int* __restrict__ start,
                                                         const int* __restrict__ deg,
                                                         const int* __restrict__ sr,
                                                         const float* __restrict__ nrm,
                                                         const float* __restrict__ comp,
                                                         const float2* __restrict__ basis2,
                                                         const float2* __restrict__ root2,
                                                         const float2* __restrict__ bias2,
                                                         float2* __restrict__ kg2) {
    int wv = threadIdx.x >> 6, lane = threadIdx.x & 63;
    int dst = blockIdx.x * 4 + wv;
    if (dst >= N_ENTITY) return;
    int s = start[dst], n = deg[dst];
    float ax = 0.f, ay = 0.f;
    for (int j = 0; j < n; ++j) {
        int p = sr[s + j];
        float nm = nrm[s + j];
        int src = p & 32767, r = p >> 15;
        float mx = 0.f, my = 0.f;
#pragma unroll
        for (int b = 0; b < N_BASES; ++b) {
            float cf = comp[r * N_BASES + b];
            float2 bs = basis2[((size_t)b * N_ENTITY + src) * 64 + lane];
            mx += cf * bs.x; my += cf * bs.y;
        }
        ax += mx * nm; ay += my * nm;
    }
    float2 rt = root2[(size_t)dst * 64 + lane];
    float2 bs = bias2[lane];
    kg2[(size_t)dst * 64 + lane] = make_float2(ax + rt.x + bs.x, ay + rt.y + bs.y);
}

// entity self-dot attention pool: one block per batch element
__global__ void ent_attn_kernel(const int* __restrict__ ctx_ent,
                                const float* __restrict__ kg,
                                const float* __restrict__ W,
                                const float* __restrict__ bb,
                                const float* __restrict__ v,
                                float* __restrict__ ent_rep) {
    __shared__ float h[N_CTX * KG_DIM];  // 25.6 KB
    __shared__ float es[64];
    __shared__ int ids[N_CTX];
    int b = blockIdx.x, tid = threadIdx.x;
    if (tid < N_CTX) ids[tid] = ctx_ent[b * N_CTX + tid];
    __syncthreads();
    for (int i = tid; i < N_CTX * KG_DIM; i += 256) {
        int l = i >> 7, d = i & 127;
        h[i] = kg[(size_t)ids[l] * KG_DIM + d];
    }
    __syncthreads();

    int wave = tid >> 6, lane = tid & 63;
    const int nl = (N_CTX - wave + 3) / 4;
    float s0[13], s1[13];
#pragma unroll
    for (int i = 0; i < 13; ++i) { s0[i] = 0.f; s1[i] = 0.f; }
    for (int k = 0; k < KG_DIM; ++k) {
        float w0 = W[k * KG_DIM + lane];
        float w1 = W[k * KG_DIM + lane + 64];
#pragma unroll
        for (int i = 0; i < 13; ++i) {
            if (i < nl) {
                float hk = h[(wave + i * 4) * KG_DIM + k];
                s0[i] += hk * w0;
                s1[i] += hk * w1;
            }
        }
    }
    float bias0 = bb[lane], bias1 = bb[lane + 64];
    float v0 = v[lane], v1 = v[lane + 64];
    for (int i = 0; i < nl; ++i) {
        int l = wave + i * 4;
        float p = tanhf(s0[i] + bias0) * v0 + tanhf(s1[i] + bias1) * v1;
        p += __shfl_xor(p, 32); p += __shfl_xor(p, 16); p += __shfl_xor(p, 8);
        p += __shfl_xor(p, 4);  p += __shfl_xor(p, 2);  p += __shfl_xor(p, 1);
        if (lane == 0) es[l] = p;
    }
    __syncthreads();
    if (tid < 64) {
        float val = (tid < N_CTX && ids[tid] != 0) ? es[tid] : -1e9f;
        float mx = val;
        mx = fmaxf(mx, __shfl_xor(mx, 32)); mx = fmaxf(mx, __shfl_xor(mx, 16));
        mx = fmaxf(mx, __shfl_xor(mx, 8));  mx = fmaxf(mx, __shfl_xor(mx, 4));
        mx = fmaxf(mx, __shfl_xor(mx, 2));  mx = fmaxf(mx, __shfl_xor(mx, 1));
        float ex = (tid < N_CTX) ? expf(val - mx) : 0.f;
        float sm = ex;
        sm += __shfl_xor(sm, 32); sm += __shfl_xor(sm, 16); sm += __shfl_xor(sm, 8);
        sm += __shfl_xor(sm, 4);  sm += __shfl_xor(sm, 2);  sm += __shfl_xor(sm, 1);
        if (tid < N_CTX) es[tid] = ex / sm;
    }
    __syncthreads();
    if (tid < KG_DIM) {
        float o = 0.f;
#pragma unroll
        for (int l = 0; l < N_CTX; ++l) o += es[l] * h[l * KG_DIM + tid];
        ent_rep[b * KG_DIM + tid] = o;
    }
}

// ---------------- tok path: bf16 conversion + MFMA GEMM ----------------

// fp32 -> bf16, 8 elems/thread
__global__ void convA_kernel(const float* __restrict__ in, __bf16* __restrict__ out,
                             int n8) {
    int i = blockIdx.x * 256 + threadIdx.x;
    if (i >= n8) return;
    const float4* p = (const float4*)(in + (size_t)i * 8);
    float4 a = p[0], b = p[1];
    union { __bf16 h[8]; uint4 u; } r;
    r.h[0] = (__bf16)a.x; r.h[1] = (__bf16)a.y; r.h[2] = (__bf16)a.z; r.h[3] = (__bf16)a.w;
    r.h[4] = (__bf16)b.x; r.h[5] = (__bf16)b.y; r.h[6] = (__bf16)b.z; r.h[7] = (__bf16)b.w;
    *(uint4*)(out + (size_t)i * 8) = r.u;
}

// Wt[c][k] = (bf16) W[k][c] : 64x64 LDS tile transpose, grid (12,12)
__global__ void convWT_kernel(const float* __restrict__ W, __bf16* __restrict__ Wt) {
    __shared__ float tile[64][65];
    int tx = threadIdx.x & 63, ty = threadIdx.x >> 6;
    int kb = blockIdx.x * 64, cb = blockIdx.y * 64;
#pragma unroll
    for (int i = 0; i < 16; ++i) {
        int r = ty + i * 4;
        tile[r][tx] = W[(size_t)(kb + r) * TOK_DIM + cb + tx];
    }
    __syncthreads();
#pragma unroll
    for (int i = 0; i < 16; ++i) {
        int r = ty + i * 4;
        Wt[(size_t)(cb + r) * TOK_DIM + kb + tx] = (__bf16)tile[tx][r];
    }
}

// Z = A[8192x768] x W[768x768] bf16 MFMA; epilogue: e[row] += sum v*tanh(z+b)
__global__ __launch_bounds__(256) void tok_gemm_kernel(const __bf16* __restrict__ A,
                                                       const __bf16* __restrict__ Bt,
                                                       const float* __restrict__ bias,
                                                       const float* __restrict__ v,
                                                       float* __restrict__ e_out) {
    __shared__ __align__(16) __bf16 sA[4096];
    __shared__ __align__(16) __bf16 sB[4096];
    int tid = threadIdx.x;
    int wave = tid >> 6, lane = tid & 63;
    int wm = wave >> 1, wn = wave & 1;
    int quad = lane >> 4, idx = lane & 15;
    int m0 = blockIdx.y * 128, c0 = blockIdx.x * 128;

    int rowS = tid & 127, kpS = tid >> 7;
    const __bf16* gA0 = A + (size_t)(m0 + rowS) * TOK_DIM + kpS * 8;
    const __bf16* gA1 = gA0 + 16;
    const __bf16* gB0 = Bt + (size_t)(c0 + rowS) * TOK_DIM + kpS * 8;
    const __bf16* gB1 = gB0 + 16;
    __bf16* dA0 = &sA[tid * 8];
    __bf16* dA1 = &sA[tid * 8 + 2048];
    __bf16* dB0 = &sB[tid * 8];
    __bf16* dB1 = &sB[tid * 8 + 2048];

    floatx4 acc[4][4];
#pragma unroll
    for (int mi = 0; mi < 4; ++mi)
#pragma unroll
        for (int ni = 0; ni < 4; ++ni)
            acc[mi][ni] = (floatx4){0.f, 0.f, 0.f, 0.f};

    for (int k0 = 0; k0 < TOK_DIM; k0 += 32) {
        uint4 ra0 = *(const uint4*)(gA0 + k0);
        uint4 ra1 = *(const uint4*)(gA1 + k0);
        uint4 rb0 = *(const uint4*)(gB0 + k0);
        uint4 rb1 = *(const uint4*)(gB1 + k0);
        __syncthreads();
        *(uint4*)dA0 = ra0; *(uint4*)dA1 = ra1;
        *(uint4*)dB0 = rb0; *(uint4*)dB1 = rb1;
        __syncthreads();
        bf16x8 aF[4], bF[4];
#pragma unroll
        for (int i = 0; i < 4; ++i) {
            aF[i] = *(const bf16x8*)&sA[quad * 1024 + (wm * 64 + i * 16 + idx) * 8];
            bF[i] = *(const bf16x8*)&sB[quad * 1024 + (wn * 64 + i * 16 + idx) * 8];
        }
#pragma unroll
        for (int mi = 0; mi < 4; ++mi)
#pragma unroll
            for (int ni = 0; ni < 4; ++ni)
                acc[mi][ni] = __builtin_amdgcn_mfma_f32_16x16x32_bf16(
                    aF[mi], bF[ni], acc[mi][ni], 0, 0, 0);
    }

    float bv[4], vv[4];
#pragma unroll
    for (int ni = 0; ni < 4; ++ni) {
        int c = c0 + wn * 64 + ni * 16 + idx;
        bv[ni] = bias[c]; vv[ni] = v[c];
    }
#pragma unroll
    for (int mi = 0; mi < 4; ++mi) {
        float s[4] = {0.f, 0.f, 0.f, 0.f};
#pragma unroll
        for (int ni = 0; ni < 4; ++ni)
#pragma unroll
            for (int r = 0; r < 4; ++r)
                s[r] += tanh_fast(acc[mi][ni][r] + bv[ni]) * vv[ni];
#pragma unroll
        for (int r = 0; r < 4; ++r) {
            s[r] += __shfl_xor(s[r], 1); s[r] += __shfl_xor(s[r], 2);
            s[r] += __shfl_xor(s[r], 4); s[r] += __shfl_xor(s[r], 8);
        }
        if (idx == 0) {
            int rbase = m0 + wm * 64 + mi * 16 + quad * 4;
#pragma unroll
            for (int r = 0; r < 4; ++r) atomicAdd(&e_out[rbase + r], s[r]);
        }
    }
}

// masked softmax over SEQ, writes attention weights back in place. grid 32.
__global__ void tok_softmax_kernel(const int* __restrict__ ctx_tok,
                                   float* __restrict__ e_ws) {
    __shared__ float redm[4];
    __shared__ float reds[4];
    int b = blockIdx.x, tid = threadIdx.x;
    int wave = tid >> 6, lane = tid & 63;
    int t = ctx_tok[b * SEQ + tid];
    float val = (t != 0) ? e_ws[b * SEQ + tid] : -1e9f;
    float mx = val;
    mx = fmaxf(mx, __shfl_xor(mx, 32)); mx = fmaxf(mx, __shfl_xor(mx, 16));
    mx = fmaxf(mx, __shfl_xor(mx, 8));  mx = fmaxf(mx, __shfl_xor(mx, 4));
    mx = fmaxf(mx, __shfl_xor(mx, 2));  mx = fmaxf(mx, __shfl_xor(mx, 1));
    if (lane == 0) redm[wave] = mx;
    __syncthreads();
    mx = fmaxf(fmaxf(redm[0], redm[1]), fmaxf(redm[2], redm[3]));
    float ex = expf(val - mx);
    float sm = ex;
    sm += __shfl_xor(sm, 32); sm += __shfl_xor(sm, 16); sm += __shfl_xor(sm, 8);
    sm += __shfl_xor(sm, 4);  sm += __shfl_xor(sm, 2);  sm += __shfl_xor(sm, 1);
    if (lane == 0) reds[wave] = sm;
    __syncthreads();
    sm = reds[0] + reds[1] + reds[2] + reds[3];
    e_ws[b * SEQ + tid] = ex / sm;
}

// pooled chunk (128 dims) + partial linear into tok_rep. grid (32, 6), 256 thr.
__global__ __launch_bounds__(256) void tok_pool2_kernel(const float* __restrict__ a_ws,
                                                        const float4* __restrict__ emb4,
                                                        const float* __restrict__ lin_W,
                                                        float* __restrict__ tok_rep) {
    __shared__ float a_s[SEQ];
    __shared__ float4 part[8][32];
    __shared__ __align__(16) float pooled[128];
    int b = blockIdx.x, c = blockIdx.y;
    int tid = threadIdx.x;
    a_s[tid] = a_ws[b * SEQ + tid];
    __syncthreads();
    int d4 = tid & 31, lg = tid >> 5;
    const float4* eb = emb4 + (size_t)b * SEQ * 192 + c * 32 + d4;
    float4 acc = make_float4(0.f, 0.f, 0.f, 0.f);
    for (int l = lg; l < SEQ; l += 8) {
        float al = a_s[l];
        float4 e = eb[(size_t)l * 192];
        acc.x += al * e.x; acc.y += al * e.y; acc.z += al * e.z; acc.w += al * e.w;
    }
    part[lg][d4] = acc;
    __syncthreads();
    if (tid < 32) {
        float4 s = part[0][tid];
#pragma unroll
        for (int g = 1; g < 8; ++g) {
            float4 p = part[g][tid];
            s.x += p.x; s.y += p.y; s.z += p.z; s.w += p.w;
        }
        ((float4*)pooled)[tid] = s;
    }
    __syncthreads();
    int d = tid & 127, hf = tid >> 7;
    const float* wr = lin_W + (size_t)d * TOK_DIM + c * 128 + hf * 64;
    float s = 0.f;
#pragma unroll 8
    for (int k = 0; k < 64; ++k) s += pooled[hf * 64 + k] * wr[k];
    atomicAdd(&tok_rep[b * KG_DIM + d], s);
}

__global__ void gate_kernel(const float* __restrict__ tok_rep,
                            const float* __restrict__ lin_b,
                            const float* __restrict__ ent_rep,
                            const float* __restrict__ gate_W,
                            const float* __restrict__ gate_b,
                            float* __restrict__ user) {
    __shared__ float tr[KG_DIM], er[KG_DIM];
    int b = blockIdx.x, d = threadIdx.x;  // 128 threads
    tr[d] = tok_rep[b * KG_DIM + d] + lin_b[d];
    er[d] = ent_rep[b * KG_DIM + d];
    __syncthreads();
    float g = gate_b[d];
    const float* wr = gate_W + (size_t)d * 256;
#pragma unroll 8
    for (int k = 0; k < KG_DIM; ++k) g += tr[k] * wr[k] + er[k] * wr[KG_DIM + k];
    float sig = 1.f / (1.f + expf(-g));
    user[b * KG_DIM + d] = sig * tr[d] + (1.f - sig) * er[d];
}

__global__ void scores_kernel(const float* __restrict__ user,
                              const float4* __restrict__ kg4,
                              float* __restrict__ out) {
    __shared__ float4 u4[BATCH * 32];  // 16 KB
    int tid = threadIdx.x;
    for (int i = tid; i < BATCH * 32; i += 256) u4[i] = ((const float4*)user)[i];
    __syncthreads();
    int n = blockIdx.x * 256 + tid;
    if (n >= N_ENTITY) return;
    float acc[BATCH];
#pragma unroll
    for (int b = 0; b < BATCH; ++b) acc[b] = 0.f;
    for (int d4 = 0; d4 < 32; ++d4) {
        float4 k = kg4[(size_t)n * 32 + d4];
#pragma unroll
        for (int b = 0; b < BATCH; ++b) {
            float4 u = u4[b * 32 + d4];
            acc[b] += k.x * u.x + k.y * u.y + k.z * u.z + k.w * u.w;
        }
    }
    for (int b = 0; b < BATCH; ++b) out[(size_t)b * N_ENTITY + n] = acc[b];
}

extern "C" void kernel_launch(void* const* d_in, const int* in_sizes, int n_in,
                              void* d_out, int out_size, void* d_ws, size_t ws_size,
                              hipStream_t stream) {
    (void)in_sizes; (void)n_in; (void)out_size;
    const int*   ctx_ent   = (const int*)d_in[0];
    const int*   ctx_tok   = (const int*)d_in[1];
    const int*   edge_index= (const int*)d_in[2];
    const int*   edge_type = (const int*)d_in[3];
    const float* tok_emb   = (const float*)d_in[4];
    const float* comp      = (const float*)d_in[5];
    const float* basis     = (const float*)d_in[6];
    const float* root      = (const float*)d_in[7];
    const float* rgcn_bias = (const float*)d_in[8];
    const float* ent_W     = (const float*)d_in[9];
    const float* ent_b     = (const float*)d_in[10];
    const float* ent_v     = (const float*)d_in[11];
    const float* tok_W     = (const float*)d_in[12];
    const float* tok_b     = (const float*)d_in[13];
    const float* tok_v     = (const float*)d_in[14];
    const float* lin_W     = (const float*)d_in[15];
    const float* lin_b     = (const float*)d_in[16];
    const float* gate_W    = (const float*)d_in[17];
    const float* gate_b    = (const float*)d_in[18];
    float* scores = (float*)d_out;

    float* ws = (float*)d_ws;
    float* kg      = ws + OFF_KG;
    int*   cnt     = (int*)(ws + OFF_CNT);
    int*   deg     = (int*)(ws + OFF_DEG);
    int*   start   = (int*)(ws + OFF_START);
    int*   cursor  = (int*)(ws + OFF_CURSOR);
    int*   sr      = (int*)(ws + OFF_SR);
    float* nrm     = ws + OFF_NORM;
    float* e_ws    = ws + OFF_ETOK;
    float* ent_rep = ws + OFF_ENT;
    float* tok_rep = ws + OFF_TOK;
    float* user    = ws + OFF_USER;
    float* weight  = ws + OFF_W;
    __bf16* Abf    = (__bf16*)(ws + OFF_ABF);
    __bf16* Wbf    = (__bf16*)(ws + OFF_WBF);
    const bool use_weight = (ws_size >= NEED_W_BYTES);

    // ---- RGCN: sort edges by dst, materialize bf16 weight, gather ----
    zero_kernel<<<(390000 + 255) / 256, 256, 0, stream>>>(cnt, 390000);
    count_kernel<<<(N_EDGES + 255) / 256, 256, 0, stream>>>(edge_index, edge_type, cnt, deg);
    scan_kernel<<<1, 1024, 0, stream>>>(deg, start, cursor);
    place_kernel<<<(N_EDGES + 255) / 256, 256, 0, stream>>>(edge_index, edge_type, cnt,
                                                            cursor, sr, nrm);
    // zero e_ws .. user (contiguous 20480 floats); e_ws needs 0 for gemm atomics,
    // tok_rep needs 0 for pool2 atomics; ent_rep/user fully overwritten later.
    zero_kernel<<<80, 256, 0, stream>>>((int*)e_ws, 20480);
    if (use_weight) {
        weight_bf16_kernel<<<1875, 256, 0, stream>>>(comp, (const float4*)basis,
                                                     (uint4*)weight);
        gather_kernel<<<(N_ENTITY + 3) / 4, 256, 0, stream>>>(
            start, deg, sr, nrm, (const unsigned int*)weight, (const float2*)root,
            (const float2*)rgcn_bias, (float2*)kg);
    } else {
        gather_otf_kernel<<<(N_ENTITY + 3) / 4, 256, 0, stream>>>(
            start, deg, sr, nrm, comp, (const float2*)basis, (const float2*)root,
            (const float2*)rgcn_bias, (float2*)kg);
    }
    ent_attn_kernel<<<BATCH, 256, 0, stream>>>(ctx_ent, kg, ent_W, ent_b, ent_v, ent_rep);

    // ---- tok path: bf16 convert (overlays weight region; gather is done) ----
    convA_kernel<<<(BATCH * SEQ * TOK_DIM / 8 + 255) / 256, 256, 0, stream>>>(
        tok_emb, Abf, BATCH * SEQ * TOK_DIM / 8);
    {
        dim3 g(12, 12);
        convWT_kernel<<<g, 256, 0, stream>>>(tok_W, Wbf);
    }
    {
        dim3 g(TOK_DIM / 128, BATCH * SEQ / 128);  // (6, 64)
        tok_gemm_kernel<<<g, 256, 0, stream>>>(Abf, Wbf, tok_b, tok_v, e_ws);
    }
    tok_softmax_kernel<<<BATCH, 256, 0, stream>>>(ctx_tok, e_ws);
    {
        dim3 g(BATCH, 6);
        tok_pool2_kernel<<<g, 256, 0, stream>>>(e_ws, (const float4*)tok_emb, lin_W,
                                                tok_rep);
    }
    gate_kernel<<<BATCH, 128, 0, stream>>>(tok_rep, lin_b, ent_rep, gate_W, gate_b, user);
    scores_kernel<<<(N_ENTITY + 255) / 256, 256, 0, stream>>>(user, (const float4*)kg, scores);
}

// Round 5
// 530.139 us; speedup vs baseline: 2.4972x; 1.0733x over previous
//
#include <hip/hip_runtime.h>
#include <hip/hip_bf16.h>
#include <math.h>

#define N_ENTITY 30000
#define N_REL    12
#define N_BASES  8
#define KG_DIM   128
#define TOK_DIM  768
#define BATCH    32
#define N_CTX    50
#define SEQ      256
#define N_EDGES  400000

// ---------------- workspace layout (in floats, all 16B-aligned) ----------------
#define OFF_KG     0           // 3,840,000
#define OFF_CNT    3840000     // 360,000 ints
#define OFF_DEG    4200000     // 30,000 ints
#define OFF_START  4230000     // 30,004 ints (N+1 used)
#define OFF_CURSOR 4260004     // 30,000 ints
#define OFF_SR     4290004     // 400,000 ints (packed src|r<<15)
#define OFF_NORM   4690004     // 400,000 floats
#define OFF_ETOK   5090004     // 8,192 (e_ws, then softmax a in-place)
#define OFF_ENT    5098196     // 4,096
#define OFF_TOK    5102292     // 4,096
#define OFF_USER   5106388     // 4,096
// weight (bf16, 92.16 MB = 23,040,000 floats) overlaid later by bf16 tok bufs
#define OFF_W      5110484
#define OFF_ABF    5110484     // 6,291,456 bf16 = 3,145,728 floats
#define OFF_WBF    8256212     // 589,824 bf16 = 294,912 floats
#define NEED_W_BYTES ((size_t)(OFF_W + 23040000) * 4)

typedef __bf16 bf16x8 __attribute__((ext_vector_type(8)));
typedef float  floatx4 __attribute__((ext_vector_type(4)));

__device__ __forceinline__ float tanh_fast(float x) {
    float ax = fabsf(x);
    float e = __expf(-2.0f * ax);
    float t = 1.0f - 2.0f * e / (1.0f + e);
    return copysignf(t, x);
}

__global__ void zero_kernel(int* __restrict__ p, int n) {
    int i = blockIdx.x * 256 + threadIdx.x;
    if (i < n) p[i] = 0;
}

// per-(r,dst) count and per-dst degree
__global__ void count_kernel(const int* __restrict__ edge_index,
                             const int* __restrict__ edge_type,
                             int* __restrict__ cnt,
                             int* __restrict__ deg) {
    int e = blockIdx.x * 256 + threadIdx.x;
    if (e >= N_EDGES) return;
    int r = edge_type[e];
    int dst = edge_index[N_EDGES + e];
    atomicAdd(&cnt[r * N_ENTITY + dst], 1);
    atomicAdd(&deg[dst], 1);
}

// single-block exclusive scan of deg -> start/cursor, shuffle-based (few syncs)
__global__ __launch_bounds__(1024) void scan_kernel(const int* __restrict__ deg,
                                                    int* __restrict__ start,
                                                    int* __restrict__ cursor) {
    __shared__ int wsum[16];
    __shared__ int carry_s;
    int tid = threadIdx.x, lane = tid & 63, wv = tid >> 6;
    if (tid == 0) carry_s = 0;
    __syncthreads();
    for (int base = 0; base < N_ENTITY; base += 1024) {
        int i = base + tid;
        int v = (i < N_ENTITY) ? deg[i] : 0;
        int x = v;
#pragma unroll
        for (int off = 1; off < 64; off <<= 1) {
            int t = __shfl_up(x, off);
            if (lane >= off) x += t;
        }
        if (lane == 63) wsum[wv] = x;
        __syncthreads();
        if (wv == 0 && lane < 16) {
            int w = wsum[lane];
#pragma unroll
            for (int off = 1; off < 16; off <<= 1) {
                int t = __shfl_up(w, off);
                if (lane >= off) w += t;
            }
            wsum[lane] = w;  // inclusive
        }
        __syncthreads();
        int carry = carry_s;
        int wbase = (wv == 0) ? 0 : wsum[wv - 1];
        if (i < N_ENTITY) {
            int ex = carry + wbase + x - v;
            start[i] = ex;
            cursor[i] = ex;
        }
        __syncthreads();
        if (tid == 1023) carry_s = carry + wsum[15];
        __syncthreads();
    }
    if (tid == 0) start[N_ENTITY] = carry_s;
}

__global__ void place_kernel(const int* __restrict__ edge_index,
                             const int* __restrict__ edge_type,
                             const int* __restrict__ cnt,
                             int* __restrict__ cursor,
                             int* __restrict__ sr,
                             float* __restrict__ nrm) {
    int e = blockIdx.x * 256 + threadIdx.x;
    if (e >= N_EDGES) return;
    int r = edge_type[e];
    int src = edge_index[e];
    int dst = edge_index[N_EDGES + e];
    int c = cnt[r * N_ENTITY + dst];
    int slot = atomicAdd(&cursor[dst], 1);
    sr[slot] = src | (r << 15);
    nrm[slot] = 1.0f / (float)(c > 1 ? c : 1);
}

// weight_bf16[r,n,d] = (bf16) sum_b comp[r,b] * basis[b,n,d]; 8 dims/thread
__global__ void weight_bf16_kernel(const float* __restrict__ comp,
                                   const float4* __restrict__ basis4,
                                   uint4* __restrict__ w4) {
    int idx = blockIdx.x * 256 + threadIdx.x;  // over N_ENTITY*KG_DIM/8 = 480000
    float4 a[N_BASES], b[N_BASES];
#pragma unroll
    for (int i = 0; i < N_BASES; ++i) {
        a[i] = basis4[(size_t)i * 960000 + idx * 2];
        b[i] = basis4[(size_t)i * 960000 + idx * 2 + 1];
    }
#pragma unroll
    for (int r = 0; r < N_REL; ++r) {
        float s[8] = {0.f, 0.f, 0.f, 0.f, 0.f, 0.f, 0.f, 0.f};
#pragma unroll
        for (int i = 0; i < N_BASES; ++i) {
            float c = comp[r * N_BASES + i];
            s[0] += c * a[i].x; s[1] += c * a[i].y;
            s[2] += c * a[i].z; s[3] += c * a[i].w;
            s[4] += c * b[i].x; s[5] += c * b[i].y;
            s[6] += c * b[i].z; s[7] += c * b[i].w;
        }
        union { __bf16 h[8]; uint4 u; } pk;
#pragma unroll
        for (int j = 0; j < 8; ++j) pk.h[j] = (__bf16)s[j];
        w4[(size_t)r * 480000 + idx] = pk.u;
    }
}

// one wave per dst entity; lane owns dims [2*lane, 2*lane+1] (one uint of bf16x2)
__global__ __launch_bounds__(256) void gather_kernel(const int* __restrict__ start,
                                                     const int* __restrict__ deg,
                                                     const int* __restrict__ sr,
                                                     const float* __restrict__ nrm,
                                                     const unsigned int* __restrict__ w,
                                                     const float2* __restrict__ root2,
                                                     const float2* __restrict__ bias2,
                                                     float2* __restrict__ kg2) {
    int wv = threadIdx.x >> 6, lane = threadIdx.x & 63;
    int dst = blockIdx.x * 4 + wv;
    if (dst >= N_ENTITY) return;
    int s = start[dst], n = deg[dst];
    float ax = 0.f, ay = 0.f;
    int j = 0;
    for (; j + 1 < n; j += 2) {
        int p0 = sr[s + j], p1 = sr[s + j + 1];
        float n0 = nrm[s + j], n1 = nrm[s + j + 1];
        int s0 = p0 & 32767, r0 = p0 >> 15;
        int s1 = p1 & 32767, r1 = p1 >> 15;
        unsigned int u0 = w[((size_t)(r0 * N_ENTITY + s0) << 6) + lane];
        unsigned int u1 = w[((size_t)(r1 * N_ENTITY + s1) << 6) + lane];
        ax += __uint_as_float(u0 << 16) * n0 + __uint_as_float(u1 << 16) * n1;
        ay += __uint_as_float(u0 & 0xffff0000u) * n0 +
              __uint_as_float(u1 & 0xffff0000u) * n1;
    }
    if (j < n) {
        int p0 = sr[s + j];
        float n0 = nrm[s + j];
        int s0 = p0 & 32767, r0 = p0 >> 15;
        unsigned int u0 = w[((size_t)(r0 * N_ENTITY + s0) << 6) + lane];
        ax += __uint_as_float(u0 << 16) * n0;
        ay += __uint_as_float(u0 & 0xffff0000u) * n0;
    }
    float2 rt = root2[(size_t)dst * 64 + lane];
    float2 bs = bias2[lane];
    kg2[(size_t)dst * 64 + lane] = make_float2(ax + rt.x + bs.x, ay + rt.y + bs.y);
}

// fallback: compute message from basis on the fly (no weight buffer)
__global__ __launch_bounds__(256) void gather_otf_kernel(const int* __restrict__ start,
                                                         const int* __restrict__ deg,
                                                         const int* __restrict__ sr,
                                                         const float* __restrict__ nrm,
                                                         const float* __restrict__ comp,
                                                         const float2* __restrict__ basis2,
                                                         const float2* __restrict__ root2,
                                                         const float2* __restrict__ bias2,
                                                         float2* __restrict__ kg2) {
    int wv = threadIdx.x >> 6, lane = threadIdx.x & 63;
    int dst = blockIdx.x * 4 + wv;
    if (dst >= N_ENTITY) return;
    int s = start[dst], n = deg[dst];
    float ax = 0.f, ay = 0.f;
    for (int j = 0; j < n; ++j) {
        int p = sr[s + j];
        float nm = nrm[s + j];
        int src = p & 32767, r = p >> 15;
        float mx = 0.f, my = 0.f;
#pragma unroll
        for (int b = 0; b < N_BASES; ++b) {
            float cf = comp[r * N_BASES + b];
            float2 bs = basis2[((size_t)b * N_ENTITY + src) * 64 + lane];
            mx += cf * bs.x; my += cf * bs.y;
        }
        ax += mx * nm; ay += my * nm;
    }
    float2 rt = root2[(size_t)dst * 64 + lane];
    float2 bs = bias2[lane];
    kg2[(size_t)dst * 64 + lane] = make_float2(ax + rt.x + bs.x, ay + rt.y + bs.y);
}

// entity self-dot attention pool: one block per batch element.
// ent_W staged in LDS (64 KB) -> no global loads in the hot loop.
__global__ __launch_bounds__(256) void ent_attn_kernel(const int* __restrict__ ctx_ent,
                                                       const float* __restrict__ kg,
                                                       const float* __restrict__ W,
                                                       const float* __restrict__ bb,
                                                       const float* __restrict__ v,
                                                       float* __restrict__ ent_rep) {
    __shared__ __align__(16) float Ws[KG_DIM * KG_DIM];  // 64 KB
    __shared__ __align__(16) float h[N_CTX * KG_DIM];    // 25.6 KB
    __shared__ float es[64];
    __shared__ int ids[N_CTX];
    int b = blockIdx.x, tid = threadIdx.x;
    if (tid < N_CTX) ids[tid] = ctx_ent[b * N_CTX + tid];
    __syncthreads();
    // stage h (gathered kg rows) and W, both as float4
    for (int i = tid; i < N_CTX * 32; i += 256) {
        int l = i >> 5, d4 = i & 31;
        ((float4*)h)[i] = ((const float4*)kg)[(size_t)ids[l] * 32 + d4];
    }
    for (int i = tid; i < KG_DIM * KG_DIM / 4; i += 256)
        ((float4*)Ws)[i] = ((const float4*)W)[i];
    __syncthreads();

    int wave = tid >> 6, lane = tid & 63;
    const int nl = (N_CTX - wave + 3) / 4;  // 13,13,12,12
    float s0[13], s1[13];
#pragma unroll
    for (int i = 0; i < 13; ++i) { s0[i] = 0.f; s1[i] = 0.f; }
    for (int k4 = 0; k4 < 32; ++k4) {
        float4 hk[13];
#pragma unroll
        for (int i = 0; i < 13; ++i)
            if (i < nl) hk[i] = ((const float4*)h)[(wave + i * 4) * 32 + k4];
#pragma unroll
        for (int kk = 0; kk < 4; ++kk) {
            int k = k4 * 4 + kk;
            float w0 = Ws[k * KG_DIM + lane];
            float w1 = Ws[k * KG_DIM + lane + 64];
#pragma unroll
            for (int i = 0; i < 13; ++i) {
                if (i < nl) {
                    float hv = (&hk[i].x)[kk];
                    s0[i] += hv * w0;
                    s1[i] += hv * w1;
                }
            }
        }
    }
    float bias0 = bb[lane], bias1 = bb[lane + 64];
    float v0 = v[lane], v1 = v[lane + 64];
    for (int i = 0; i < nl; ++i) {
        int l = wave + i * 4;
        float p = tanhf(s0[i] + bias0) * v0 + tanhf(s1[i] + bias1) * v1;
        p += __shfl_xor(p, 32); p += __shfl_xor(p, 16); p += __shfl_xor(p, 8);
        p += __shfl_xor(p, 4);  p += __shfl_xor(p, 2);  p += __shfl_xor(p, 1);
        if (lane == 0) es[l] = p;
    }
    __syncthreads();
    if (tid < 64) {
        float val = (tid < N_CTX && ids[tid] != 0) ? es[tid] : -1e9f;
        float mx = val;
        mx = fmaxf(mx, __shfl_xor(mx, 32)); mx = fmaxf(mx, __shfl_xor(mx, 16));
        mx = fmaxf(mx, __shfl_xor(mx, 8));  mx = fmaxf(mx, __shfl_xor(mx, 4));
        mx = fmaxf(mx, __shfl_xor(mx, 2));  mx = fmaxf(mx, __shfl_xor(mx, 1));
        float ex = (tid < N_CTX) ? expf(val - mx) : 0.f;
        float sm = ex;
        sm += __shfl_xor(sm, 32); sm += __shfl_xor(sm, 16); sm += __shfl_xor(sm, 8);
        sm += __shfl_xor(sm, 4);  sm += __shfl_xor(sm, 2);  sm += __shfl_xor(sm, 1);
        if (tid < N_CTX) es[tid] = ex / sm;
    }
    __syncthreads();
    if (tid < KG_DIM) {
        float o = 0.f;
#pragma unroll
        for (int l = 0; l < N_CTX; ++l) o += es[l] * h[l * KG_DIM + tid];
        ent_rep[b * KG_DIM + tid] = o;
    }
}

// ---------------- tok path: bf16 conversion + MFMA GEMM ----------------

// fp32 -> bf16, 8 elems/thread
__global__ void convA_kernel(const float* __restrict__ in, __bf16* __restrict__ out,
                             int n8) {
    int i = blockIdx.x * 256 + threadIdx.x;
    if (i >= n8) return;
    const float4* p = (const float4*)(in + (size_t)i * 8);
    float4 a = p[0], b = p[1];
    union { __bf16 h[8]; uint4 u; } r;
    r.h[0] = (__bf16)a.x; r.h[1] = (__bf16)a.y; r.h[2] = (__bf16)a.z; r.h[3] = (__bf16)a.w;
    r.h[4] = (__bf16)b.x; r.h[5] = (__bf16)b.y; r.h[6] = (__bf16)b.z; r.h[7] = (__bf16)b.w;
    *(uint4*)(out + (size_t)i * 8) = r.u;
}

// Wt[c][k] = (bf16) W[k][c] : 64x64 LDS tile transpose, grid (12,12)
__global__ void convWT_kernel(const float* __restrict__ W, __bf16* __restrict__ Wt) {
    __shared__ float tile[64][65];
    int tx = threadIdx.x & 63, ty = threadIdx.x >> 6;
    int kb = blockIdx.x * 64, cb = blockIdx.y * 64;
#pragma unroll
    for (int i = 0; i < 16; ++i) {
        int r = ty + i * 4;
        tile[r][tx] = W[(size_t)(kb + r) * TOK_DIM + cb + tx];
    }
    __syncthreads();
#pragma unroll
    for (int i = 0; i < 16; ++i) {
        int r = ty + i * 4;
        Wt[(size_t)(cb + r) * TOK_DIM + kb + tx] = (__bf16)tile[tx][r];
    }
}

// Z = A[8192x768] x W[768x768] bf16 MFMA; epilogue: e[row] += sum v*tanh(z+b)
__global__ __launch_bounds__(256) void tok_gemm_kernel(const __bf16* __restrict__ A,
                                                       const __bf16* __restrict__ Bt,
                                                       const float* __restrict__ bias,
                                                       const float* __restrict__ v,
                                                       float* __restrict__ e_out) {
    __shared__ __align__(16) __bf16 sA[4096];
    __shared__ __align__(16) __bf16 sB[4096];
    int tid = threadIdx.x;
    int wave = tid >> 6, lane = tid & 63;
    int wm = wave >> 1, wn = wave & 1;
    int quad = lane >> 4, idx = lane & 15;
    int m0 = blockIdx.y * 128, c0 = blockIdx.x * 128;

    int rowS = tid & 127, kpS = tid >> 7;
    const __bf16* gA0 = A + (size_t)(m0 + rowS) * TOK_DIM + kpS * 8;
    const __bf16* gA1 = gA0 + 16;
    const __bf16* gB0 = Bt + (size_t)(c0 + rowS) * TOK_DIM + kpS * 8;
    const __bf16* gB1 = gB0 + 16;
    __bf16* dA0 = &sA[tid * 8];
    __bf16* dA1 = &sA[tid * 8 + 2048];
    __bf16* dB0 = &sB[tid * 8];
    __bf16* dB1 = &sB[tid * 8 + 2048];

    floatx4 acc[4][4];
#pragma unroll
    for (int mi = 0; mi < 4; ++mi)
#pragma unroll
        for (int ni = 0; ni < 4; ++ni)
            acc[mi][ni] = (floatx4){0.f, 0.f, 0.f, 0.f};

    for (int k0 = 0; k0 < TOK_DIM; k0 += 32) {
        uint4 ra0 = *(const uint4*)(gA0 + k0);
        uint4 ra1 = *(const uint4*)(gA1 + k0);
        uint4 rb0 = *(const uint4*)(gB0 + k0);
        uint4 rb1 = *(const uint4*)(gB1 + k0);
        __syncthreads();
        *(uint4*)dA0 = ra0; *(uint4*)dA1 = ra1;
        *(uint4*)dB0 = rb0; *(uint4*)dB1 = rb1;
        __syncthreads();
        bf16x8 aF[4], bF[4];
#pragma unroll
        for (int i = 0; i < 4; ++i) {
            aF[i] = *(const bf16x8*)&sA[quad * 1024 + (wm * 64 + i * 16 + idx) * 8];
            bF[i] = *(const bf16x8*)&sB[quad * 1024 + (wn * 64 + i * 16 + idx) * 8];
        }
#pragma unroll
        for (int mi = 0; mi < 4; ++mi)
#pragma unroll
            for (int ni = 0; ni < 4; ++ni)
                acc[mi][ni] = __builtin_amdgcn_mfma_f32_16x16x32_bf16(
                    aF[mi], bF[ni], acc[mi][ni], 0, 0, 0);
    }

    float bv[4], vv[4];
#pragma unroll
    for (int ni = 0; ni < 4; ++ni) {
        int c = c0 + wn * 64 + ni * 16 + idx;
        bv[ni] = bias[c]; vv[ni] = v[c];
    }
#pragma unroll
    for (int mi = 0; mi < 4; ++mi) {
        float s[4] = {0.f, 0.f, 0.f, 0.f};
#pragma unroll
        for (int ni = 0; ni < 4; ++ni)
#pragma unroll
            for (int r = 0; r < 4; ++r)
                s[r] += tanh_fast(acc[mi][ni][r] + bv[ni]) * vv[ni];
#pragma unroll
        for (int r = 0; r < 4; ++r) {
            s[r] += __shfl_xor(s[r], 1); s[r] += __shfl_xor(s[r], 2);
            s[r] += __shfl_xor(s[r], 4); s[r] += __shfl_xor(s[r], 8);
        }
        if (idx == 0) {
            int rbase = m0 + wm * 64 + mi * 16 + quad * 4;
#pragma unroll
            for (int r = 0; r < 4; ++r) atomicAdd(&e_out[rbase + r], s[r]);
        }
    }
}

// masked softmax over SEQ, writes attention weights back in place. grid 32.
__global__ void tok_softmax_kernel(const int* __restrict__ ctx_tok,
                                   float* __restrict__ e_ws) {
    __shared__ float redm[4];
    __shared__ float reds[4];
    int b = blockIdx.x, tid = threadIdx.x;
    int wave = tid >> 6, lane = tid & 63;
    int t = ctx_tok[b * SEQ + tid];
    float val = (t != 0) ? e_ws[b * SEQ + tid] : -1e9f;
    float mx = val;
    mx = fmaxf(mx, __shfl_xor(mx, 32)); mx = fmaxf(mx, __shfl_xor(mx, 16));
    mx = fmaxf(mx, __shfl_xor(mx, 8));  mx = fmaxf(mx, __shfl_xor(mx, 4));
    mx = fmaxf(mx, __shfl_xor(mx, 2));  mx = fmaxf(mx, __shfl_xor(mx, 1));
    if (lane == 0) redm[wave] = mx;
    __syncthreads();
    mx = fmaxf(fmaxf(redm[0], redm[1]), fmaxf(redm[2], redm[3]));
    float ex = expf(val - mx);
    float sm = ex;
    sm += __shfl_xor(sm, 32); sm += __shfl_xor(sm, 16); sm += __shfl_xor(sm, 8);
    sm += __shfl_xor(sm, 4);  sm += __shfl_xor(sm, 2);  sm += __shfl_xor(sm, 1);
    if (lane == 0) reds[wave] = sm;
    __syncthreads();
    sm = reds[0] + reds[1] + reds[2] + reds[3];
    e_ws[b * SEQ + tid] = ex / sm;
}

// pooled chunk (128 dims) + partial linear into tok_rep. grid (32, 6), 256 thr.
__global__ __launch_bounds__(256) void tok_pool2_kernel(const float* __restrict__ a_ws,
                                                        const float4* __restrict__ emb4,
                                                        const float* __restrict__ lin_W,
                                                        float* __restrict__ tok_rep) {
    __shared__ float a_s[SEQ];
    __shared__ float4 part[8][32];
    __shared__ __align__(16) float pooled[128];
    int b = blockIdx.x, c = blockIdx.y;
    int tid = threadIdx.x;
    a_s[tid] = a_ws[b * SEQ + tid];
    __syncthreads();
    int d4 = tid & 31, lg = tid >> 5;
    const float4* eb = emb4 + (size_t)b * SEQ * 192 + c * 32 + d4;
    float4 acc = make_float4(0.f, 0.f, 0.f, 0.f);
    for (int l = lg; l < SEQ; l += 8) {
        float al = a_s[l];
        float4 e = eb[(size_t)l * 192];
        acc.x += al * e.x; acc.y += al * e.y; acc.z += al * e.z; acc.w += al * e.w;
    }
    part[lg][d4] = acc;
    __syncthreads();
    if (tid < 32) {
        float4 s = part[0][tid];
#pragma unroll
        for (int g = 1; g < 8; ++g) {
            float4 p = part[g][tid];
            s.x += p.x; s.y += p.y; s.z += p.z; s.w += p.w;
        }
        ((float4*)pooled)[tid] = s;
    }
    __syncthreads();
    int d = tid & 127, hf = tid >> 7;
    const float* wr = lin_W + (size_t)d * TOK_DIM + c * 128 + hf * 64;
    float s = 0.f;
#pragma unroll 8
    for (int k = 0; k < 64; ++k) s += pooled[hf * 64 + k] * wr[k];
    atomicAdd(&tok_rep[b * KG_DIM + d], s);
}

__global__ void gate_kernel(const float* __restrict__ tok_rep,
                            const float* __restrict__ lin_b,
                            const float* __restrict__ ent_rep,
                            const float* __restrict__ gate_W,
                            const float* __restrict__ gate_b,
                            float* __restrict__ user) {
    __shared__ float tr[KG_DIM], er[KG_DIM];
    int b = blockIdx.x, d = threadIdx.x;  // 128 threads
    tr[d] = tok_rep[b * KG_DIM + d] + lin_b[d];
    er[d] = ent_rep[b * KG_DIM + d];
    __syncthreads();
    float g = gate_b[d];
    const float* wr = gate_W + (size_t)d * 256;
#pragma unroll 8
    for (int k = 0; k < KG_DIM; ++k) g += tr[k] * wr[k] + er[k] * wr[KG_DIM + k];
    float sig = 1.f / (1.f + expf(-g));
    user[b * KG_DIM + d] = sig * tr[d] + (1.f - sig) * er[d];
}

__global__ void scores_kernel(const float* __restrict__ user,
                              const float4* __restrict__ kg4,
                              float* __restrict__ out) {
    __shared__ float4 u4[BATCH * 32];  // 16 KB
    int tid = threadIdx.x;
    for (int i = tid; i < BATCH * 32; i += 256) u4[i] = ((const float4*)user)[i];
    __syncthreads();
    int n = blockIdx.x * 256 + tid;
    if (n >= N_ENTITY) return;
    float acc[BATCH];
#pragma unroll
    for (int b = 0; b < BATCH; ++b) acc[b] = 0.f;
    for (int d4 = 0; d4 < 32; ++d4) {
        float4 k = kg4[(size_t)n * 32 + d4];
#pragma unroll
        for (int b = 0; b < BATCH; ++b) {
            float4 u = u4[b * 32 + d4];
            acc[b] += k.x * u.x + k.y * u.y + k.z * u.z + k.w * u.w;
        }
    }
    for (int b = 0; b < BATCH; ++b) out[(size_t)b * N_ENTITY + n] = acc[b];
}

extern "C" void kernel_launch(void* const* d_in, const int* in_sizes, int n_in,
                              void* d_out, int out_size, void* d_ws, size_t ws_size,
                              hipStream_t stream) {
    (void)in_sizes; (void)n_in; (void)out_size;
    const int*   ctx_ent   = (const int*)d_in[0];
    const int*   ctx_tok   = (const int*)d_in[1];
    const int*   edge_index= (const int*)d_in[2];
    const int*   edge_type = (const int*)d_in[3];
    const float* tok_emb   = (const float*)d_in[4];
    const float* comp      = (const float*)d_in[5];
    const float* basis     = (const float*)d_in[6];
    const float* root      = (const float*)d_in[7];
    const float* rgcn_bias = (const float*)d_in[8];
    const float* ent_W     = (const float*)d_in[9];
    const float* ent_b     = (const float*)d_in[10];
    const float* ent_v     = (const float*)d_in[11];
    const float* tok_W     = (const float*)d_in[12];
    const float* tok_b     = (const float*)d_in[13];
    const float* tok_v     = (const float*)d_in[14];
    const float* lin_W     = (const float*)d_in[15];
    const float* lin_b     = (const float*)d_in[16];
    const float* gate_W    = (const float*)d_in[17];
    const float* gate_b    = (const float*)d_in[18];
    float* scores = (float*)d_out;

    float* ws = (float*)d_ws;
    float* kg      = ws + OFF_KG;
    int*   cnt     = (int*)(ws + OFF_CNT);
    int*   deg     = (int*)(ws + OFF_DEG);
    int*   start   = (int*)(ws + OFF_START);
    int*   cursor  = (int*)(ws + OFF_CURSOR);
    int*   sr      = (int*)(ws + OFF_SR);
    float* nrm     = ws + OFF_NORM;
    float* e_ws    = ws + OFF_ETOK;
    float* ent_rep = ws + OFF_ENT;
    float* tok_rep = ws + OFF_TOK;
    float* user    = ws + OFF_USER;
    float* weight  = ws + OFF_W;
    __bf16* Abf    = (__bf16*)(ws + OFF_ABF);
    __bf16* Wbf    = (__bf16*)(ws + OFF_WBF);
    const bool use_weight = (ws_size >= NEED_W_BYTES);

    // ---- RGCN: sort edges by dst, materialize bf16 weight, gather ----
    zero_kernel<<<(390000 + 255) / 256, 256, 0, stream>>>(cnt, 390000);
    count_kernel<<<(N_EDGES + 255) / 256, 256, 0, stream>>>(edge_index, edge_type, cnt, deg);
    scan_kernel<<<1, 1024, 0, stream>>>(deg, start, cursor);
    place_kernel<<<(N_EDGES + 255) / 256, 256, 0, stream>>>(edge_index, edge_type, cnt,
                                                            cursor, sr, nrm);
    // zero e_ws .. user (contiguous 20480 floats); e_ws needs 0 for gemm atomics,
    // tok_rep needs 0 for pool2 atomics; ent_rep/user fully overwritten later.
    zero_kernel<<<80, 256, 0, stream>>>((int*)e_ws, 20480);
    if (use_weight) {
        weight_bf16_kernel<<<1875, 256, 0, stream>>>(comp, (const float4*)basis,
                                                     (uint4*)weight);
        gather_kernel<<<(N_ENTITY + 3) / 4, 256, 0, stream>>>(
            start, deg, sr, nrm, (const unsigned int*)weight, (const float2*)root,
            (const float2*)rgcn_bias, (float2*)kg);
    } else {
        gather_otf_kernel<<<(N_ENTITY + 3) / 4, 256, 0, stream>>>(
            start, deg, sr, nrm, comp, (const float2*)basis, (const float2*)root,
            (const float2*)rgcn_bias, (float2*)kg);
    }
    ent_attn_kernel<<<BATCH, 256, 0, stream>>>(ctx_ent, kg, ent_W, ent_b, ent_v, ent_rep);

    // ---- tok path: bf16 convert (overlays weight region; gather is done) ----
    convA_kernel<<<(BATCH * SEQ * TOK_DIM / 8 + 255) / 256, 256, 0, stream>>>(
        tok_emb, Abf, BATCH * SEQ * TOK_DIM / 8);
    {
        dim3 g(12, 12);
        convWT_kernel<<<g, 256, 0, stream>>>(tok_W, Wbf);
    }
    {
        dim3 g(TOK_DIM / 128, BATCH * SEQ / 128);  // (6, 64)
        tok_gemm_kernel<<<g, 256, 0, stream>>>(Abf, Wbf, tok_b, tok_v, e_ws);
    }
    tok_softmax_kernel<<<BATCH, 256, 0, stream>>>(ctx_tok, e_ws);
    {
        dim3 g(BATCH, 6);
        tok_pool2_kernel<<<g, 256, 0, stream>>>(e_ws, (const float4*)tok_emb, lin_W,
                                                tok_rep);
    }
    gate_kernel<<<BATCH, 128, 0, stream>>>(tok_rep, lin_b, ent_rep, gate_W, gate_b, user);
    scores_kernel<<<(N_ENTITY + 255) / 256, 256, 0, stream>>>(user, (const float4*)kg, scores);
}

// Round 6
// 523.632 us; speedup vs baseline: 2.5282x; 1.0124x over previous
//
#include <hip/hip_runtime.h>
#include <hip/hip_bf16.h>
#include <math.h>

#define N_ENTITY 30000
#define N_REL    12
#define N_BASES  8
#define KG_DIM   128
#define TOK_DIM  768
#define BATCH    32
#define N_CTX    50
#define SEQ      256
#define N_EDGES  400000

// ---------------- workspace layout (in floats, all 16B-aligned) ----------------
#define OFF_KG     0           // 3,840,000
#define OFF_CNT    3840000     // 360,000 ints
#define OFF_DEG    4200000     // 30,000 ints
#define OFF_START  4230000     // 30,004 ints (N+1 used)
#define OFF_CURSOR 4260004     // 30,000 ints
#define OFF_SR     4290004     // 400,000 int2 = 800,000 ints (packed {src|r<<15, norm})
#define OFF_ETOK   5090004     // 8,192 (e_ws, then softmax a in-place)
#define OFF_ENT    5098196     // 4,096
#define OFF_TOK    5102292     // 4,096
#define OFF_USER   5106388     // 4,096
// weight (bf16, 92.16 MB = 23,040,000 floats) overlaid later by bf16 tok bufs
#define OFF_W      5110484
#define OFF_ABF    5110484     // 6,291,456 bf16 = 3,145,728 floats
#define OFF_WBF    8256212     // 589,824 bf16 = 294,912 floats
#define NEED_W_BYTES ((size_t)(OFF_W + 23040000) * 4)

typedef __bf16 bf16x8 __attribute__((ext_vector_type(8)));
typedef float  floatx4 __attribute__((ext_vector_type(4)));

__device__ __forceinline__ float tanh_fast(float x) {
    float ax = fabsf(x);
    float e = __expf(-2.0f * ax);
    float t = 1.0f - 2.0f * e / (1.0f + e);
    return copysignf(t, x);
}

__global__ void zero_kernel(int* __restrict__ p, int n) {
    int i = blockIdx.x * 256 + threadIdx.x;
    if (i < n) p[i] = 0;
}

// per-(r,dst) count and per-dst degree
__global__ void count_kernel(const int* __restrict__ edge_index,
                             const int* __restrict__ edge_type,
                             int* __restrict__ cnt,
                             int* __restrict__ deg) {
    int e = blockIdx.x * 256 + threadIdx.x;
    if (e >= N_EDGES) return;
    int r = edge_type[e];
    int dst = edge_index[N_EDGES + e];
    atomicAdd(&cnt[r * N_ENTITY + dst], 1);
    atomicAdd(&deg[dst], 1);
}

// single-block exclusive scan of deg -> start/cursor, shuffle-based
__global__ __launch_bounds__(1024) void scan_kernel(const int* __restrict__ deg,
                                                    int* __restrict__ start,
                                                    int* __restrict__ cursor) {
    __shared__ int wsum[16];
    __shared__ int carry_s;
    int tid = threadIdx.x, lane = tid & 63, wv = tid >> 6;
    if (tid == 0) carry_s = 0;
    __syncthreads();
    for (int base = 0; base < N_ENTITY; base += 1024) {
        int i = base + tid;
        int v = (i < N_ENTITY) ? deg[i] : 0;
        int x = v;
#pragma unroll
        for (int off = 1; off < 64; off <<= 1) {
            int t = __shfl_up(x, off);
            if (lane >= off) x += t;
        }
        if (lane == 63) wsum[wv] = x;
        __syncthreads();
        if (wv == 0 && lane < 16) {
            int w = wsum[lane];
#pragma unroll
            for (int off = 1; off < 16; off <<= 1) {
                int t = __shfl_up(w, off);
                if (lane >= off) w += t;
            }
            wsum[lane] = w;  // inclusive
        }
        __syncthreads();
        int carry = carry_s;
        int wbase = (wv == 0) ? 0 : wsum[wv - 1];
        if (i < N_ENTITY) {
            int ex = carry + wbase + x - v;
            start[i] = ex;
            cursor[i] = ex;
        }
        __syncthreads();
        if (tid == 1023) carry_s = carry + wsum[15];
        __syncthreads();
    }
    if (tid == 0) start[N_ENTITY] = carry_s;
}

// one packed int2 store per edge: {src | r<<15, norm bits}
__global__ void place_kernel(const int* __restrict__ edge_index,
                             const int* __restrict__ edge_type,
                             const int* __restrict__ cnt,
                             int* __restrict__ cursor,
                             int2* __restrict__ er) {
    int e = blockIdx.x * 256 + threadIdx.x;
    if (e >= N_EDGES) return;
    int r = edge_type[e];
    int src = edge_index[e];
    int dst = edge_index[N_EDGES + e];
    int c = cnt[r * N_ENTITY + dst];
    float norm = 1.0f / (float)(c > 1 ? c : 1);
    int slot = atomicAdd(&cursor[dst], 1);
    er[slot] = make_int2(src | (r << 15), __float_as_int(norm));
}

// weight_bf16[r,n,d] = (bf16) sum_b comp[r,b] * basis[b,n,d]; 8 dims/thread.
// __launch_bounds__(256,2): allow ~128 VGPRs so the 16 staged float4 stay
// register-resident across the 12-relation loop (at 36 VGPRs the compiler
// re-read basis from L2 12x -> 2 TB/s; round-5 counters).
__global__ __launch_bounds__(256, 2) void weight_bf16_kernel(
        const float* __restrict__ comp,
        const float4* __restrict__ basis4,
        uint4* __restrict__ w4) {
    int idx = blockIdx.x * 256 + threadIdx.x;  // over N_ENTITY*KG_DIM/8 = 480000
    float4 a[N_BASES], b[N_BASES];
#pragma unroll
    for (int i = 0; i < N_BASES; ++i) {
        a[i] = basis4[(size_t)i * 960000 + idx * 2];
        b[i] = basis4[(size_t)i * 960000 + idx * 2 + 1];
    }
#pragma unroll
    for (int r = 0; r < N_REL; ++r) {
        float s[8] = {0.f, 0.f, 0.f, 0.f, 0.f, 0.f, 0.f, 0.f};
#pragma unroll
        for (int i = 0; i < N_BASES; ++i) {
            float c = comp[r * N_BASES + i];
            s[0] += c * a[i].x; s[1] += c * a[i].y;
            s[2] += c * a[i].z; s[3] += c * a[i].w;
            s[4] += c * b[i].x; s[5] += c * b[i].y;
            s[6] += c * b[i].z; s[7] += c * b[i].w;
        }
        union { __bf16 h[8]; uint4 u; } pk;
#pragma unroll
        for (int j = 0; j < 8; ++j) pk.h[j] = (__bf16)s[j];
        w4[(size_t)r * 480000 + idx] = pk.u;
    }
}

// one wave per dst entity; lane owns dims [2*lane, 2*lane+1] (one uint of bf16x2)
__global__ __launch_bounds__(256) void gather_kernel(const int* __restrict__ start,
                                                     const int* __restrict__ deg,
                                                     const int2* __restrict__ er,
                                                     const unsigned int* __restrict__ w,
                                                     const float2* __restrict__ root2,
                                                     const float2* __restrict__ bias2,
                                                     float2* __restrict__ kg2) {
    int wv = threadIdx.x >> 6, lane = threadIdx.x & 63;
    int dst = blockIdx.x * 4 + wv;
    if (dst >= N_ENTITY) return;
    int s = start[dst], n = deg[dst];
    float ax = 0.f, ay = 0.f;
    int j = 0;
    for (; j + 1 < n; j += 2) {
        int2 e0 = er[s + j], e1 = er[s + j + 1];
        float n0 = __int_as_float(e0.y), n1 = __int_as_float(e1.y);
        int s0 = e0.x & 32767, r0 = e0.x >> 15;
        int s1 = e1.x & 32767, r1 = e1.x >> 15;
        unsigned int u0 = w[((size_t)(r0 * N_ENTITY + s0) << 6) + lane];
        unsigned int u1 = w[((size_t)(r1 * N_ENTITY + s1) << 6) + lane];
        ax += __uint_as_float(u0 << 16) * n0 + __uint_as_float(u1 << 16) * n1;
        ay += __uint_as_float(u0 & 0xffff0000u) * n0 +
              __uint_as_float(u1 & 0xffff0000u) * n1;
    }
    if (j < n) {
        int2 e0 = er[s + j];
        float n0 = __int_as_float(e0.y);
        int s0 = e0.x & 32767, r0 = e0.x >> 15;
        unsigned int u0 = w[((size_t)(r0 * N_ENTITY + s0) << 6) + lane];
        ax += __uint_as_float(u0 << 16) * n0;
        ay += __uint_as_float(u0 & 0xffff0000u) * n0;
    }
    float2 rt = root2[(size_t)dst * 64 + lane];
    float2 bs = bias2[lane];
    kg2[(size_t)dst * 64 + lane] = make_float2(ax + rt.x + bs.x, ay + rt.y + bs.y);
}

// fallback: compute message from basis on the fly (no weight buffer)
__global__ __launch_bounds__(256) void gather_otf_kernel(const int* __restrict__ start,
                                                         const int* __restrict__ deg,
                                                         const int2* __restrict__ er,
                                                         const float* __restrict__ comp,
                                                         const float2* __restrict__ basis2,
                                                         const float2* __restrict__ root2,
                                                         const float2* __restrict__ bias2,
                                                         float2* __restrict__ kg2) {
    int wv = threadIdx.x >> 6, lane = threadIdx.x & 63;
    int dst = blockIdx.x * 4 + wv;
    if (dst >= N_ENTITY) return;
    int s = start[dst], n = deg[dst];
    float ax = 0.f, ay = 0.f;
    for (int j = 0; j < n; ++j) {
        int2 e0 = er[s + j];
        float nm = __int_as_float(e0.y);
        int src = e0.x & 32767, r = e0.x >> 15;
        float mx = 0.f, my = 0.f;
#pragma unroll
        for (int b = 0; b < N_BASES; ++b) {
            float cf = comp[r * N_BASES + b];
            float2 bs = basis2[((size_t)b * N_ENTITY + src) * 64 + lane];
            mx += cf * bs.x; my += cf * bs.y;
        }
        ax += mx * nm; ay += my * nm;
    }
    float2 rt = root2[(size_t)dst * 64 + lane];
    float2 bs = bias2[lane];
    kg2[(size_t)dst * 64 + lane] = make_float2(ax + rt.x + bs.x, ay + rt.y + bs.y);
}

// entity self-dot attention pool: one block per batch element.
// ent_W staged in LDS (64 KB) -> no global loads in the hot loop.
__global__ __launch_bounds__(256) void ent_attn_kernel(const int* __restrict__ ctx_ent,
                                                       const float* __restrict__ kg,
                                                       const float* __restrict__ W,
                                                       const float* __restrict__ bb,
                                                       const float* __restrict__ v,
                                                       float* __restrict__ ent_rep) {
    __shared__ __align__(16) float Ws[KG_DIM * KG_DIM];  // 64 KB
    __shared__ __align__(16) float h[N_CTX * KG_DIM];    // 25.6 KB
    __shared__ float es[64];
    __shared__ int ids[N_CTX];
    int b = blockIdx.x, tid = threadIdx.x;
    if (tid < N_CTX) ids[tid] = ctx_ent[b * N_CTX + tid];
    __syncthreads();
    for (int i = tid; i < N_CTX * 32; i += 256) {
        int l = i >> 5, d4 = i & 31;
        ((float4*)h)[i] = ((const float4*)kg)[(size_t)ids[l] * 32 + d4];
    }
    for (int i = tid; i < KG_DIM * KG_DIM / 4; i += 256)
        ((float4*)Ws)[i] = ((const float4*)W)[i];
    __syncthreads();

    int wave = tid >> 6, lane = tid & 63;
    const int nl = (N_CTX - wave + 3) / 4;  // 13,13,12,12
    float s0[13], s1[13];
#pragma unroll
    for (int i = 0; i < 13; ++i) { s0[i] = 0.f; s1[i] = 0.f; }
    for (int k4 = 0; k4 < 32; ++k4) {
        float4 hk[13];
#pragma unroll
        for (int i = 0; i < 13; ++i)
            if (i < nl) hk[i] = ((const float4*)h)[(wave + i * 4) * 32 + k4];
#pragma unroll
        for (int kk = 0; kk < 4; ++kk) {
            int k = k4 * 4 + kk;
            float w0 = Ws[k * KG_DIM + lane];
            float w1 = Ws[k * KG_DIM + lane + 64];
#pragma unroll
            for (int i = 0; i < 13; ++i) {
                if (i < nl) {
                    float hv = (&hk[i].x)[kk];
                    s0[i] += hv * w0;
                    s1[i] += hv * w1;
                }
            }
        }
    }
    float bias0 = bb[lane], bias1 = bb[lane + 64];
    float v0 = v[lane], v1 = v[lane + 64];
    for (int i = 0; i < nl; ++i) {
        int l = wave + i * 4;
        float p = tanhf(s0[i] + bias0) * v0 + tanhf(s1[i] + bias1) * v1;
        p += __shfl_xor(p, 32); p += __shfl_xor(p, 16); p += __shfl_xor(p, 8);
        p += __shfl_xor(p, 4);  p += __shfl_xor(p, 2);  p += __shfl_xor(p, 1);
        if (lane == 0) es[l] = p;
    }
    __syncthreads();
    if (tid < 64) {
        float val = (tid < N_CTX && ids[tid] != 0) ? es[tid] : -1e9f;
        float mx = val;
        mx = fmaxf(mx, __shfl_xor(mx, 32)); mx = fmaxf(mx, __shfl_xor(mx, 16));
        mx = fmaxf(mx, __shfl_xor(mx, 8));  mx = fmaxf(mx, __shfl_xor(mx, 4));
        mx = fmaxf(mx, __shfl_xor(mx, 2));  mx = fmaxf(mx, __shfl_xor(mx, 1));
        float ex = (tid < N_CTX) ? expf(val - mx) : 0.f;
        float sm = ex;
        sm += __shfl_xor(sm, 32); sm += __shfl_xor(sm, 16); sm += __shfl_xor(sm, 8);
        sm += __shfl_xor(sm, 4);  sm += __shfl_xor(sm, 2);  sm += __shfl_xor(sm, 1);
        if (tid < N_CTX) es[tid] = ex / sm;
    }
    __syncthreads();
    if (tid < KG_DIM) {
        float o = 0.f;
#pragma unroll
        for (int l = 0; l < N_CTX; ++l) o += es[l] * h[l * KG_DIM + tid];
        ent_rep[b * KG_DIM + tid] = o;
    }
}

// ---------------- tok path: bf16 conversion + MFMA GEMM ----------------

__global__ void convA_kernel(const float* __restrict__ in, __bf16* __restrict__ out,
                             int n8) {
    int i = blockIdx.x * 256 + threadIdx.x;
    if (i >= n8) return;
    const float4* p = (const float4*)(in + (size_t)i * 8);
    float4 a = p[0], b = p[1];
    union { __bf16 h[8]; uint4 u; } r;
    r.h[0] = (__bf16)a.x; r.h[1] = (__bf16)a.y; r.h[2] = (__bf16)a.z; r.h[3] = (__bf16)a.w;
    r.h[4] = (__bf16)b.x; r.h[5] = (__bf16)b.y; r.h[6] = (__bf16)b.z; r.h[7] = (__bf16)b.w;
    *(uint4*)(out + (size_t)i * 8) = r.u;
}

// Wt[c][k] = (bf16) W[k][c] : 64x64 LDS tile transpose, grid (12,12)
__global__ void convWT_kernel(const float* __restrict__ W, __bf16* __restrict__ Wt) {
    __shared__ float tile[64][65];
    int tx = threadIdx.x & 63, ty = threadIdx.x >> 6;
    int kb = blockIdx.x * 64, cb = blockIdx.y * 64;
#pragma unroll
    for (int i = 0; i < 16; ++i) {
        int r = ty + i * 4;
        tile[r][tx] = W[(size_t)(kb + r) * TOK_DIM + cb + tx];
    }
    __syncthreads();
#pragma unroll
    for (int i = 0; i < 16; ++i) {
        int r = ty + i * 4;
        Wt[(size_t)(cb + r) * TOK_DIM + kb + tx] = (__bf16)tile[tx][r];
    }
}

// Z = A[8192x768] x W[768x768] bf16 MFMA; epilogue: e[row] += sum v*tanh(z+b)
__global__ __launch_bounds__(256) void tok_gemm_kernel(const __bf16* __restrict__ A,
                                                       const __bf16* __restrict__ Bt,
                                                       const float* __restrict__ bias,
                                                       const float* __restrict__ v,
                                                       float* __restrict__ e_out) {
    __shared__ __align__(16) __bf16 sA[4096];
    __shared__ __align__(16) __bf16 sB[4096];
    int tid = threadIdx.x;
    int wave = tid >> 6, lane = tid & 63;
    int wm = wave >> 1, wn = wave & 1;
    int quad = lane >> 4, idx = lane & 15;
    int m0 = blockIdx.y * 128, c0 = blockIdx.x * 128;

    int rowS = tid & 127, kpS = tid >> 7;
    const __bf16* gA0 = A + (size_t)(m0 + rowS) * TOK_DIM + kpS * 8;
    const __bf16* gA1 = gA0 + 16;
    const __bf16* gB0 = Bt + (size_t)(c0 + rowS) * TOK_DIM + kpS * 8;
    const __bf16* gB1 = gB0 + 16;
    __bf16* dA0 = &sA[tid * 8];
    __bf16* dA1 = &sA[tid * 8 + 2048];
    __bf16* dB0 = &sB[tid * 8];
    __bf16* dB1 = &sB[tid * 8 + 2048];

    floatx4 acc[4][4];
#pragma unroll
    for (int mi = 0; mi < 4; ++mi)
#pragma unroll
        for (int ni = 0; ni < 4; ++ni)
            acc[mi][ni] = (floatx4){0.f, 0.f, 0.f, 0.f};

    for (int k0 = 0; k0 < TOK_DIM; k0 += 32) {
        uint4 ra0 = *(const uint4*)(gA0 + k0);
        uint4 ra1 = *(const uint4*)(gA1 + k0);
        uint4 rb0 = *(const uint4*)(gB0 + k0);
        uint4 rb1 = *(const uint4*)(gB1 + k0);
        __syncthreads();
        *(uint4*)dA0 = ra0; *(uint4*)dA1 = ra1;
        *(uint4*)dB0 = rb0; *(uint4*)dB1 = rb1;
        __syncthreads();
        bf16x8 aF[4], bF[4];
#pragma unroll
        for (int i = 0; i < 4; ++i) {
            aF[i] = *(const bf16x8*)&sA[quad * 1024 + (wm * 64 + i * 16 + idx) * 8];
            bF[i] = *(const bf16x8*)&sB[quad * 1024 + (wn * 64 + i * 16 + idx) * 8];
        }
#pragma unroll
        for (int mi = 0; mi < 4; ++mi)
#pragma unroll
            for (int ni = 0; ni < 4; ++ni)
                acc[mi][ni] = __builtin_amdgcn_mfma_f32_16x16x32_bf16(
                    aF[mi], bF[ni], acc[mi][ni], 0, 0, 0);
    }

    float bv[4], vv[4];
#pragma unroll
    for (int ni = 0; ni < 4; ++ni) {
        int c = c0 + wn * 64 + ni * 16 + idx;
        bv[ni] = bias[c]; vv[ni] = v[c];
    }
#pragma unroll
    for (int mi = 0; mi < 4; ++mi) {
        float s[4] = {0.f, 0.f, 0.f, 0.f};
#pragma unroll
        for (int ni = 0; ni < 4; ++ni)
#pragma unroll
            for (int r = 0; r < 4; ++r)
                s[r] += tanh_fast(acc[mi][ni][r] + bv[ni]) * vv[ni];
#pragma unroll
        for (int r = 0; r < 4; ++r) {
            s[r] += __shfl_xor(s[r], 1); s[r] += __shfl_xor(s[r], 2);
            s[r] += __shfl_xor(s[r], 4); s[r] += __shfl_xor(s[r], 8);
        }
        if (idx == 0) {
            int rbase = m0 + wm * 64 + mi * 16 + quad * 4;
#pragma unroll
            for (int r = 0; r < 4; ++r) atomicAdd(&e_out[rbase + r], s[r]);
        }
    }
}

// masked softmax over SEQ, writes attention weights back in place. grid 32.
__global__ void tok_softmax_kernel(const int* __restrict__ ctx_tok,
                                   float* __restrict__ e_ws) {
    __shared__ float redm[4];
    __shared__ float reds[4];
    int b = blockIdx.x, tid = threadIdx.x;
    int wave = tid >> 6, lane = tid & 63;
    int t = ctx_tok[b * SEQ + tid];
    float val = (t != 0) ? e_ws[b * SEQ + tid] : -1e9f;
    float mx = val;
    mx = fmaxf(mx, __shfl_xor(mx, 32)); mx = fmaxf(mx, __shfl_xor(mx, 16));
    mx = fmaxf(mx, __shfl_xor(mx, 8));  mx = fmaxf(mx, __shfl_xor(mx, 4));
    mx = fmaxf(mx, __shfl_xor(mx, 2));  mx = fmaxf(mx, __shfl_xor(mx, 1));
    if (lane == 0) redm[wave] = mx;
    __syncthreads();
    mx = fmaxf(fmaxf(redm[0], redm[1]), fmaxf(redm[2], redm[3]));
    float ex = expf(val - mx);
    float sm = ex;
    sm += __shfl_xor(sm, 32); sm += __shfl_xor(sm, 16); sm += __shfl_xor(sm, 8);
    sm += __shfl_xor(sm, 4);  sm += __shfl_xor(sm, 2);  sm += __shfl_xor(sm, 1);
    if (lane == 0) reds[wave] = sm;
    __syncthreads();
    sm = reds[0] + reds[1] + reds[2] + reds[3];
    e_ws[b * SEQ + tid] = ex / sm;
}

// pooled chunk (128 dims) + partial linear into tok_rep. grid (32, 6), 256 thr.
__global__ __launch_bounds__(256) void tok_pool2_kernel(const float* __restrict__ a_ws,
                                                        const float4* __restrict__ emb4,
                                                        const float* __restrict__ lin_W,
                                                        float* __restrict__ tok_rep) {
    __shared__ float a_s[SEQ];
    __shared__ float4 part[8][32];
    __shared__ __align__(16) float pooled[128];
    int b = blockIdx.x, c = blockIdx.y;
    int tid = threadIdx.x;
    a_s[tid] = a_ws[b * SEQ + tid];
    __syncthreads();
    int d4 = tid & 31, lg = tid >> 5;
    const float4* eb = emb4 + (size_t)b * SEQ * 192 + c * 32 + d4;
    float4 acc = make_float4(0.f, 0.f, 0.f, 0.f);
    for (int l = lg; l < SEQ; l += 8) {
        float al = a_s[l];
        float4 e = eb[(size_t)l * 192];
        acc.x += al * e.x; acc.y += al * e.y; acc.z += al * e.z; acc.w += al * e.w;
    }
    part[lg][d4] = acc;
    __syncthreads();
    if (tid < 32) {
        float4 s = part[0][tid];
#pragma unroll
        for (int g = 1; g < 8; ++g) {
            float4 p = part[g][tid];
            s.x += p.x; s.y += p.y; s.z += p.z; s.w += p.w;
        }
        ((float4*)pooled)[tid] = s;
    }
    __syncthreads();
    int d = tid & 127, hf = tid >> 7;
    const float* wr = lin_W + (size_t)d * TOK_DIM + c * 128 + hf * 64;
    float s = 0.f;
#pragma unroll 8
    for (int k = 0; k < 64; ++k) s += pooled[hf * 64 + k] * wr[k];
    atomicAdd(&tok_rep[b * KG_DIM + d], s);
}

__global__ void gate_kernel(const float* __restrict__ tok_rep,
                            const float* __restrict__ lin_b,
                            const float* __restrict__ ent_rep,
                            const float* __restrict__ gate_W,
                            const float* __restrict__ gate_b,
                            float* __restrict__ user) {
    __shared__ float tr[KG_DIM], er[KG_DIM];
    int b = blockIdx.x, d = threadIdx.x;  // 128 threads
    tr[d] = tok_rep[b * KG_DIM + d] + lin_b[d];
    er[d] = ent_rep[b * KG_DIM + d];
    __syncthreads();
    float g = gate_b[d];
    const float* wr = gate_W + (size_t)d * 256;
#pragma unroll 8
    for (int k = 0; k < KG_DIM; ++k) g += tr[k] * wr[k] + er[k] * wr[KG_DIM + k];
    float sig = 1.f / (1.f + expf(-g));
    user[b * KG_DIM + d] = sig * tr[d] + (1.f - sig) * er[d];
}

__global__ void scores_kernel(const float* __restrict__ user,
                              const float4* __restrict__ kg4,
                              float* __restrict__ out) {
    __shared__ float4 u4[BATCH * 32];  // 16 KB
    int tid = threadIdx.x;
    for (int i = tid; i < BATCH * 32; i += 256) u4[i] = ((const float4*)user)[i];
    __syncthreads();
    int n = blockIdx.x * 256 + tid;
    if (n >= N_ENTITY) return;
    float acc[BATCH];
#pragma unroll
    for (int b = 0; b < BATCH; ++b) acc[b] = 0.f;
    for (int d4 = 0; d4 < 32; ++d4) {
        float4 k = kg4[(size_t)n * 32 + d4];
#pragma unroll
        for (int b = 0; b < BATCH; ++b) {
            float4 u = u4[b * 32 + d4];
            acc[b] += k.x * u.x + k.y * u.y + k.z * u.z + k.w * u.w;
        }
    }
    for (int b = 0; b < BATCH; ++b) out[(size_t)b * N_ENTITY + n] = acc[b];
}

extern "C" void kernel_launch(void* const* d_in, const int* in_sizes, int n_in,
                              void* d_out, int out_size, void* d_ws, size_t ws_size,
                              hipStream_t stream) {
    (void)in_sizes; (void)n_in; (void)out_size;
    const int*   ctx_ent   = (const int*)d_in[0];
    const int*   ctx_tok   = (const int*)d_in[1];
    const int*   edge_index= (const int*)d_in[2];
    const int*   edge_type = (const int*)d_in[3];
    const float* tok_emb   = (const float*)d_in[4];
    const float* comp      = (const float*)d_in[5];
    const float* basis     = (const float*)d_in[6];
    const float* root      = (const float*)d_in[7];
    const float* rgcn_bias = (const float*)d_in[8];
    const float* ent_W     = (const float*)d_in[9];
    const float* ent_b     = (const float*)d_in[10];
    const float* ent_v     = (const float*)d_in[11];
    const float* tok_W     = (const float*)d_in[12];
    const float* tok_b     = (const float*)d_in[13];
    const float* tok_v     = (const float*)d_in[14];
    const float* lin_W     = (const float*)d_in[15];
    const float* lin_b     = (const float*)d_in[16];
    const float* gate_W    = (const float*)d_in[17];
    const float* gate_b    = (const float*)d_in[18];
    float* scores = (float*)d_out;

    float* ws = (float*)d_ws;
    float* kg      = ws + OFF_KG;
    int*   cnt     = (int*)(ws + OFF_CNT);
    int*   deg     = (int*)(ws + OFF_DEG);
    int*   start   = (int*)(ws + OFF_START);
    int*   cursor  = (int*)(ws + OFF_CURSOR);
    int2*  er      = (int2*)(ws + OFF_SR);
    float* e_ws    = ws + OFF_ETOK;
    float* ent_rep = ws + OFF_ENT;
    float* tok_rep = ws + OFF_TOK;
    float* user    = ws + OFF_USER;
    float* weight  = ws + OFF_W;
    __bf16* Abf    = (__bf16*)(ws + OFF_ABF);
    __bf16* Wbf    = (__bf16*)(ws + OFF_WBF);
    const bool use_weight = (ws_size >= NEED_W_BYTES);

    // ---- RGCN: sort edges by dst, materialize bf16 weight, gather ----
    zero_kernel<<<(390000 + 255) / 256, 256, 0, stream>>>(cnt, 390000);
    count_kernel<<<(N_EDGES + 255) / 256, 256, 0, stream>>>(edge_index, edge_type, cnt, deg);
    scan_kernel<<<1, 1024, 0, stream>>>(deg, start, cursor);
    place_kernel<<<(N_EDGES + 255) / 256, 256, 0, stream>>>(edge_index, edge_type, cnt,
                                                            cursor, er);
    // zero e_ws .. user (contiguous 20480 floats)
    zero_kernel<<<80, 256, 0, stream>>>((int*)e_ws, 20480);
    if (use_weight) {
        weight_bf16_kernel<<<1875, 256, 0, stream>>>(comp, (const float4*)basis,
                                                     (uint4*)weight);
        gather_kernel<<<(N_ENTITY + 3) / 4, 256, 0, stream>>>(
            start, deg, er, (const unsigned int*)weight, (const float2*)root,
            (const float2*)rgcn_bias, (float2*)kg);
    } else {
        gather_otf_kernel<<<(N_ENTITY + 3) / 4, 256, 0, stream>>>(
            start, deg, er, comp, (const float2*)basis, (const float2*)root,
            (const float2*)rgcn_bias, (float2*)kg);
    }
    ent_attn_kernel<<<BATCH, 256, 0, stream>>>(ctx_ent, kg, ent_W, ent_b, ent_v, ent_rep);

    // ---- tok path: bf16 convert (overlays weight region; gather is done) ----
    convA_kernel<<<(BATCH * SEQ * TOK_DIM / 8 + 255) / 256, 256, 0, stream>>>(
        tok_emb, Abf, BATCH * SEQ * TOK_DIM / 8);
    {
        dim3 g(12, 12);
        convWT_kernel<<<g, 256, 0, stream>>>(tok_W, Wbf);
    }
    {
        dim3 g(TOK_DIM / 128, BATCH * SEQ / 128);  // (6, 64)
        tok_gemm_kernel<<<g, 256, 0, stream>>>(Abf, Wbf, tok_b, tok_v, e_ws);
    }
    tok_softmax_kernel<<<BATCH, 256, 0, stream>>>(ctx_tok, e_ws);
    {
        dim3 g(BATCH, 6);
        tok_pool2_kernel<<<g, 256, 0, stream>>>(e_ws, (const float4*)tok_emb, lin_W,
                                                tok_rep);
    }
    gate_kernel<<<BATCH, 128, 0, stream>>>(tok_rep, lin_b, ent_rep, gate_W, gate_b, user);
    scores_kernel<<<(N_ENTITY + 255) / 256, 256, 0, stream>>>(user, (const float4*)kg, scores);
}

// Round 7
// 480.317 us; speedup vs baseline: 2.7562x; 1.0902x over previous
//
#include <hip/hip_runtime.h>
#include <hip/hip_bf16.h>
#include <math.h>

#define N_ENTITY 30000
#define N_REL    12
#define N_BASES  8
#define KG_DIM   128
#define TOK_DIM  768
#define BATCH    32
#define N_CTX    50
#define SEQ      256
#define N_EDGES  400000

// ---------------- workspace layout (in floats) ----------------
#define OFF_KG     0           // 3,840,000
#define OFF_CNT    3840000     // 360,000 ints
#define OFF_DEG    4200000     // 30,000 ints
#define OFF_START  4230000     // 30,004 ints (N+1 used)
#define OFF_CURSOR 4260004     // 30,000 ints
#define OFF_CHUNK  4290004     // 64 ints: [0,30) chunksum, [32,62) chunkoff
#define OFF_SR     4290068     // 400,000 int2 = 800,000 ints {src|r<<15, norm}
#define OFF_ETOK   5090068     // 8,192 (raw e from gemm atomics)
#define OFF_ENT    5098260     // 4,096
#define OFF_TOK    5102356     // 4,096
#define OFF_USER   5106452     // 4,096
// weight (bf16, 92.16 MB = 23,040,000 floats) overlaid later by bf16 tok bufs
#define OFF_W      5110548
#define OFF_ABF    5110548     // 6,291,456 bf16 = 3,145,728 floats
#define OFF_WBF    8256276     // 589,824 bf16 = 294,912 floats
#define NEED_W_BYTES ((size_t)(OFF_W + 23040000) * 4)

typedef __bf16 bf16x8 __attribute__((ext_vector_type(8)));
typedef float  floatx4 __attribute__((ext_vector_type(4)));

__device__ __forceinline__ float tanh_fast(float x) {
    float ax = fabsf(x);
    float e = __expf(-2.0f * ax);
    float t = 1.0f - 2.0f * e / (1.0f + e);
    return copysignf(t, x);
}

__global__ void zero_kernel(int* __restrict__ p, int n) {
    int i = blockIdx.x * 256 + threadIdx.x;
    if (i < n) p[i] = 0;
}

// per-(r,dst) count only (deg derived in scan1)
__global__ void count_kernel(const int* __restrict__ edge_index,
                             const int* __restrict__ edge_type,
                             int* __restrict__ cnt) {
    int e = blockIdx.x * 256 + threadIdx.x;
    if (e >= N_EDGES) return;
    int r = edge_type[e];
    int dst = edge_index[N_EDGES + e];
    atomicAdd(&cnt[r * N_ENTITY + dst], 1);
}

// scan1: deg[i] = sum_r cnt[r,i]; block-local exclusive scan -> start;
// per-block total -> chunksum. grid 30 x 1024.
__global__ __launch_bounds__(1024) void scan1_kernel(const int* __restrict__ cnt,
                                                     int* __restrict__ deg,
                                                     int* __restrict__ start,
                                                     int* __restrict__ chunksum) {
    __shared__ int wsum[16];
    int tid = threadIdx.x, lane = tid & 63, wv = tid >> 6;
    int i = blockIdx.x * 1024 + tid;
    int v = 0;
    if (i < N_ENTITY) {
#pragma unroll
        for (int r = 0; r < N_REL; ++r) v += cnt[r * N_ENTITY + i];
        deg[i] = v;
    }
    int x = v;
#pragma unroll
    for (int off = 1; off < 64; off <<= 1) {
        int t = __shfl_up(x, off);
        if (lane >= off) x += t;
    }
    if (lane == 63) wsum[wv] = x;
    __syncthreads();
    if (wv == 0 && lane < 16) {
        int w = wsum[lane];
#pragma unroll
        for (int off = 1; off < 16; off <<= 1) {
            int t = __shfl_up(w, off);
            if (lane >= off) w += t;
        }
        wsum[lane] = w;  // inclusive
    }
    __syncthreads();
    int wbase = (wv == 0) ? 0 : wsum[wv - 1];
    if (i < N_ENTITY) start[i] = wbase + x - v;      // block-local exclusive
    if (tid == 1023) chunksum[blockIdx.x] = wbase + x;  // block total
}

// scan2: one wave scans the 30 chunk sums -> chunkoff; total -> start[N]
__global__ void scan2_kernel(const int* __restrict__ chunksum,
                             int* __restrict__ chunkoff,
                             int* __restrict__ start) {
    int lane = threadIdx.x;  // 64 threads
    int v = (lane < 30) ? chunksum[lane] : 0;
    int x = v;
#pragma unroll
    for (int off = 1; off < 64; off <<= 1) {
        int t = __shfl_up(x, off);
        if (lane >= off) x += t;
    }
    if (lane < 30) chunkoff[lane] = x - v;
    if (lane == 63) start[N_ENTITY] = x;
}

// scan3: add chunk offset; write cursor. grid 30 x 1024.
__global__ __launch_bounds__(1024) void scan3_kernel(const int* __restrict__ chunkoff,
                                                     int* __restrict__ start,
                                                     int* __restrict__ cursor) {
    int i = blockIdx.x * 1024 + threadIdx.x;
    if (i < N_ENTITY) {
        int s = start[i] + chunkoff[blockIdx.x];
        start[i] = s;
        cursor[i] = s;
    }
}

// one packed int2 store per edge: {src | r<<15, norm bits}
__global__ void place_kernel(const int* __restrict__ edge_index,
                             const int* __restrict__ edge_type,
                             const int* __restrict__ cnt,
                             int* __restrict__ cursor,
                             int2* __restrict__ er) {
    int e = blockIdx.x * 256 + threadIdx.x;
    if (e >= N_EDGES) return;
    int r = edge_type[e];
    int src = edge_index[e];
    int dst = edge_index[N_EDGES + e];
    int c = cnt[r * N_ENTITY + dst];
    float norm = 1.0f / (float)(c > 1 ? c : 1);
    int slot = atomicAdd(&cursor[dst], 1);
    er[slot] = make_int2(src | (r << 15), __float_as_int(norm));
}

// weight_bf16: 4 dims/thread (8 float4 = 32 VGPRs of basis data -> structurally
// register-resident across the 12-relation loop; round-5/6 showed the 8-dim
// version re-read basis from L2 12x regardless of __launch_bounds__ hints).
// Layout (flat bf16 = uint halves): u = r*1920000 + n*64 + (d>>1) -- identical
// to what gather_kernel indexes.
__global__ void weight_bf16_kernel(const float* __restrict__ comp,
                                   const float4* __restrict__ basis4,
                                   uint2* __restrict__ w2) {
    int idx = blockIdx.x * 256 + threadIdx.x;  // over N_ENTITY*KG_DIM/4 = 960000
    float4 bv[N_BASES];
#pragma unroll
    for (int i = 0; i < N_BASES; ++i) bv[i] = basis4[(size_t)i * 960000 + idx];
#pragma unroll
    for (int r = 0; r < N_REL; ++r) {
        float s0 = 0.f, s1 = 0.f, s2 = 0.f, s3 = 0.f;
#pragma unroll
        for (int i = 0; i < N_BASES; ++i) {
            float c = comp[r * N_BASES + i];
            s0 += c * bv[i].x; s1 += c * bv[i].y;
            s2 += c * bv[i].z; s3 += c * bv[i].w;
        }
        union { __bf16 h[4]; uint2 u; } pk;
        pk.h[0] = (__bf16)s0; pk.h[1] = (__bf16)s1;
        pk.h[2] = (__bf16)s2; pk.h[3] = (__bf16)s3;
        w2[(size_t)r * 960000 + idx] = pk.u;
    }
}

// one wave per dst entity; lane owns dims [2*lane, 2*lane+1] (one uint of bf16x2)
__global__ __launch_bounds__(256) void gather_kernel(const int* __restrict__ start,
                                                     const int* __restrict__ deg,
                                                     const int2* __restrict__ er,
                                                     const unsigned int* __restrict__ w,
                                                     const float2* __restrict__ root2,
                                                     const float2* __restrict__ bias2,
                                                     float2* __restrict__ kg2) {
    int wv = threadIdx.x >> 6, lane = threadIdx.x & 63;
    int dst = blockIdx.x * 4 + wv;
    if (dst >= N_ENTITY) return;
    int s = start[dst], n = deg[dst];
    float ax = 0.f, ay = 0.f;
    int j = 0;
    for (; j + 1 < n; j += 2) {
        int2 e0 = er[s + j], e1 = er[s + j + 1];
        float n0 = __int_as_float(e0.y), n1 = __int_as_float(e1.y);
        int s0 = e0.x & 32767, r0 = e0.x >> 15;
        int s1 = e1.x & 32767, r1 = e1.x >> 15;
        unsigned int u0 = w[((size_t)(r0 * N_ENTITY + s0) << 6) + lane];
        unsigned int u1 = w[((size_t)(r1 * N_ENTITY + s1) << 6) + lane];
        ax += __uint_as_float(u0 << 16) * n0 + __uint_as_float(u1 << 16) * n1;
        ay += __uint_as_float(u0 & 0xffff0000u) * n0 +
              __uint_as_float(u1 & 0xffff0000u) * n1;
    }
    if (j < n) {
        int2 e0 = er[s + j];
        float n0 = __int_as_float(e0.y);
        int s0 = e0.x & 32767, r0 = e0.x >> 15;
        unsigned int u0 = w[((size_t)(r0 * N_ENTITY + s0) << 6) + lane];
        ax += __uint_as_float(u0 << 16) * n0;
        ay += __uint_as_float(u0 & 0xffff0000u) * n0;
    }
    float2 rt = root2[(size_t)dst * 64 + lane];
    float2 bs = bias2[lane];
    kg2[(size_t)dst * 64 + lane] = make_float2(ax + rt.x + bs.x, ay + rt.y + bs.y);
}

// fallback: compute message from basis on the fly (no weight buffer)
__global__ __launch_bounds__(256) void gather_otf_kernel(const int* __restrict__ start,
                                                         const int* __restrict__ deg,
                                                         const int2* __restrict__ er,
                                                         const float* __restrict__ comp,
                                                         const float2* __restrict__ basis2,
                                                         const float2* __restrict__ root2,
                                                         const float2* __restrict__ bias2,
                                                         float2* __restrict__ kg2) {
    int wv = threadIdx.x >> 6, lane = threadIdx.x & 63;
    int dst = blockIdx.x * 4 + wv;
    if (dst >= N_ENTITY) return;
    int s = start[dst], n = deg[dst];
    float ax = 0.f, ay = 0.f;
    for (int j = 0; j < n; ++j) {
        int2 e0 = er[s + j];
        float nm = __int_as_float(e0.y);
        int src = e0.x & 32767, r = e0.x >> 15;
        float mx = 0.f, my = 0.f;
#pragma unroll
        for (int b = 0; b < N_BASES; ++b) {
            float cf = comp[r * N_BASES + b];
            float2 bs = basis2[((size_t)b * N_ENTITY + src) * 64 + lane];
            mx += cf * bs.x; my += cf * bs.y;
        }
        ax += mx * nm; ay += my * nm;
    }
    float2 rt = root2[(size_t)dst * 64 + lane];
    float2 bs = bias2[lane];
    kg2[(size_t)dst * 64 + lane] = make_float2(ax + rt.x + bs.x, ay + rt.y + bs.y);
}

// entity self-dot attention pool: one block per batch element.
// ent_W staged in LDS (64 KB) -> no global loads in the hot loop.
__global__ __launch_bounds__(256) void ent_attn_kernel(const int* __restrict__ ctx_ent,
                                                       const float* __restrict__ kg,
                                                       const float* __restrict__ W,
                                                       const float* __restrict__ bb,
                                                       const float* __restrict__ v,
                                                       float* __restrict__ ent_rep) {
    __shared__ __align__(16) float Ws[KG_DIM * KG_DIM];  // 64 KB
    __shared__ __align__(16) float h[N_CTX * KG_DIM];    // 25.6 KB
    __shared__ float es[64];
    __shared__ int ids[N_CTX];
    int b = blockIdx.x, tid = threadIdx.x;
    if (tid < N_CTX) ids[tid] = ctx_ent[b * N_CTX + tid];
    __syncthreads();
    for (int i = tid; i < N_CTX * 32; i += 256) {
        int l = i >> 5, d4 = i & 31;
        ((float4*)h)[i] = ((const float4*)kg)[(size_t)ids[l] * 32 + d4];
    }
    for (int i = tid; i < KG_DIM * KG_DIM / 4; i += 256)
        ((float4*)Ws)[i] = ((const float4*)W)[i];
    __syncthreads();

    int wave = tid >> 6, lane = tid & 63;
    const int nl = (N_CTX - wave + 3) / 4;  // 13,13,12,12
    float s0[13], s1[13];
#pragma unroll
    for (int i = 0; i < 13; ++i) { s0[i] = 0.f; s1[i] = 0.f; }
    for (int k4 = 0; k4 < 32; ++k4) {
        float4 hk[13];
#pragma unroll
        for (int i = 0; i < 13; ++i)
            if (i < nl) hk[i] = ((const float4*)h)[(wave + i * 4) * 32 + k4];
#pragma unroll
        for (int kk = 0; kk < 4; ++kk) {
            int k = k4 * 4 + kk;
            float w0 = Ws[k * KG_DIM + lane];
            float w1 = Ws[k * KG_DIM + lane + 64];
#pragma unroll
            for (int i = 0; i < 13; ++i) {
                if (i < nl) {
                    float hv = (&hk[i].x)[kk];
                    s0[i] += hv * w0;
                    s1[i] += hv * w1;
                }
            }
        }
    }
    float bias0 = bb[lane], bias1 = bb[lane + 64];
    float v0 = v[lane], v1 = v[lane + 64];
    for (int i = 0; i < nl; ++i) {
        int l = wave + i * 4;
        float p = tanhf(s0[i] + bias0) * v0 + tanhf(s1[i] + bias1) * v1;
        p += __shfl_xor(p, 32); p += __shfl_xor(p, 16); p += __shfl_xor(p, 8);
        p += __shfl_xor(p, 4);  p += __shfl_xor(p, 2);  p += __shfl_xor(p, 1);
        if (lane == 0) es[l] = p;
    }
    __syncthreads();
    if (tid < 64) {
        float val = (tid < N_CTX && ids[tid] != 0) ? es[tid] : -1e9f;
        float mx = val;
        mx = fmaxf(mx, __shfl_xor(mx, 32)); mx = fmaxf(mx, __shfl_xor(mx, 16));
        mx = fmaxf(mx, __shfl_xor(mx, 8));  mx = fmaxf(mx, __shfl_xor(mx, 4));
        mx = fmaxf(mx, __shfl_xor(mx, 2));  mx = fmaxf(mx, __shfl_xor(mx, 1));
        float ex = (tid < N_CTX) ? expf(val - mx) : 0.f;
        float sm = ex;
        sm += __shfl_xor(sm, 32); sm += __shfl_xor(sm, 16); sm += __shfl_xor(sm, 8);
        sm += __shfl_xor(sm, 4);  sm += __shfl_xor(sm, 2);  sm += __shfl_xor(sm, 1);
        if (tid < N_CTX) es[tid] = ex / sm;
    }
    __syncthreads();
    if (tid < KG_DIM) {
        float o = 0.f;
#pragma unroll
        for (int l = 0; l < N_CTX; ++l) o += es[l] * h[l * KG_DIM + tid];
        ent_rep[b * KG_DIM + tid] = o;
    }
}

// ---------------- tok path: bf16 conversion + MFMA GEMM ----------------

__global__ void convA_kernel(const float* __restrict__ in, __bf16* __restrict__ out,
                             int n8) {
    int i = blockIdx.x * 256 + threadIdx.x;
    if (i >= n8) return;
    const float4* p = (const float4*)(in + (size_t)i * 8);
    float4 a = p[0], b = p[1];
    union { __bf16 h[8]; uint4 u; } r;
    r.h[0] = (__bf16)a.x; r.h[1] = (__bf16)a.y; r.h[2] = (__bf16)a.z; r.h[3] = (__bf16)a.w;
    r.h[4] = (__bf16)b.x; r.h[5] = (__bf16)b.y; r.h[6] = (__bf16)b.z; r.h[7] = (__bf16)b.w;
    *(uint4*)(out + (size_t)i * 8) = r.u;
}

// Wt[c][k] = (bf16) W[k][c] : 64x64 LDS tile transpose, grid (12,12)
__global__ void convWT_kernel(const float* __restrict__ W, __bf16* __restrict__ Wt) {
    __shared__ float tile[64][65];
    int tx = threadIdx.x & 63, ty = threadIdx.x >> 6;
    int kb = blockIdx.x * 64, cb = blockIdx.y * 64;
#pragma unroll
    for (int i = 0; i < 16; ++i) {
        int r = ty + i * 4;
        tile[r][tx] = W[(size_t)(kb + r) * TOK_DIM + cb + tx];
    }
    __syncthreads();
#pragma unroll
    for (int i = 0; i < 16; ++i) {
        int r = ty + i * 4;
        Wt[(size_t)(cb + r) * TOK_DIM + kb + tx] = (__bf16)tile[tx][r];
    }
}

// Z = A[8192x768] x W[768x768] bf16 MFMA; epilogue: e[row] += sum v*tanh(z+b)
__global__ __launch_bounds__(256) void tok_gemm_kernel(const __bf16* __restrict__ A,
                                                       const __bf16* __restrict__ Bt,
                                                       const float* __restrict__ bias,
                                                       const float* __restrict__ v,
                                                       float* __restrict__ e_out) {
    __shared__ __align__(16) __bf16 sA[4096];
    __shared__ __align__(16) __bf16 sB[4096];
    int tid = threadIdx.x;
    int wave = tid >> 6, lane = tid & 63;
    int wm = wave >> 1, wn = wave & 1;
    int quad = lane >> 4, idx = lane & 15;
    int m0 = blockIdx.y * 128, c0 = blockIdx.x * 128;

    int rowS = tid & 127, kpS = tid >> 7;
    const __bf16* gA0 = A + (size_t)(m0 + rowS) * TOK_DIM + kpS * 8;
    const __bf16* gA1 = gA0 + 16;
    const __bf16* gB0 = Bt + (size_t)(c0 + rowS) * TOK_DIM + kpS * 8;
    const __bf16* gB1 = gB0 + 16;
    __bf16* dA0 = &sA[tid * 8];
    __bf16* dA1 = &sA[tid * 8 + 2048];
    __bf16* dB0 = &sB[tid * 8];
    __bf16* dB1 = &sB[tid * 8 + 2048];

    floatx4 acc[4][4];
#pragma unroll
    for (int mi = 0; mi < 4; ++mi)
#pragma unroll
        for (int ni = 0; ni < 4; ++ni)
            acc[mi][ni] = (floatx4){0.f, 0.f, 0.f, 0.f};

    for (int k0 = 0; k0 < TOK_DIM; k0 += 32) {
        uint4 ra0 = *(const uint4*)(gA0 + k0);
        uint4 ra1 = *(const uint4*)(gA1 + k0);
        uint4 rb0 = *(const uint4*)(gB0 + k0);
        uint4 rb1 = *(const uint4*)(gB1 + k0);
        __syncthreads();
        *(uint4*)dA0 = ra0; *(uint4*)dA1 = ra1;
        *(uint4*)dB0 = rb0; *(uint4*)dB1 = rb1;
        __syncthreads();
        bf16x8 aF[4], bF[4];
#pragma unroll
        for (int i = 0; i < 4; ++i) {
            aF[i] = *(const bf16x8*)&sA[quad * 1024 + (wm * 64 + i * 16 + idx) * 8];
            bF[i] = *(const bf16x8*)&sB[quad * 1024 + (wn * 64 + i * 16 + idx) * 8];
        }
#pragma unroll
        for (int mi = 0; mi < 4; ++mi)
#pragma unroll
            for (int ni = 0; ni < 4; ++ni)
                acc[mi][ni] = __builtin_amdgcn_mfma_f32_16x16x32_bf16(
                    aF[mi], bF[ni], acc[mi][ni], 0, 0, 0);
    }

    float bv[4], vv[4];
#pragma unroll
    for (int ni = 0; ni < 4; ++ni) {
        int c = c0 + wn * 64 + ni * 16 + idx;
        bv[ni] = bias[c]; vv[ni] = v[c];
    }
#pragma unroll
    for (int mi = 0; mi < 4; ++mi) {
        float s[4] = {0.f, 0.f, 0.f, 0.f};
#pragma unroll
        for (int ni = 0; ni < 4; ++ni)
#pragma unroll
            for (int r = 0; r < 4; ++r)
                s[r] += tanh_fast(acc[mi][ni][r] + bv[ni]) * vv[ni];
#pragma unroll
        for (int r = 0; r < 4; ++r) {
            s[r] += __shfl_xor(s[r], 1); s[r] += __shfl_xor(s[r], 2);
            s[r] += __shfl_xor(s[r], 4); s[r] += __shfl_xor(s[r], 8);
        }
        if (idx == 0) {
            int rbase = m0 + wm * 64 + mi * 16 + quad * 4;
#pragma unroll
            for (int r = 0; r < 4; ++r) atomicAdd(&e_out[rbase + r], s[r]);
        }
    }
}

// fused masked-softmax + pooled chunk (128 dims) + partial linear into tok_rep.
// grid (32, 6), 256 thr. Each c-block redundantly computes the 256-wide softmax.
__global__ __launch_bounds__(256) void tok_pool2_kernel(const int* __restrict__ ctx_tok,
                                                        const float* __restrict__ e_ws,
                                                        const float4* __restrict__ emb4,
                                                        const float* __restrict__ lin_W,
                                                        float* __restrict__ tok_rep) {
    __shared__ float a_s[SEQ];
    __shared__ float4 part[8][32];
    __shared__ __align__(16) float pooled[128];
    __shared__ float redm[4];
    __shared__ float reds[4];
    int b = blockIdx.x, c = blockIdx.y;
    int tid = threadIdx.x;
    int wave = tid >> 6, lane = tid & 63;
    int t = ctx_tok[b * SEQ + tid];
    float val = (t != 0) ? e_ws[b * SEQ + tid] : -1e9f;
    float mx = val;
    mx = fmaxf(mx, __shfl_xor(mx, 32)); mx = fmaxf(mx, __shfl_xor(mx, 16));
    mx = fmaxf(mx, __shfl_xor(mx, 8));  mx = fmaxf(mx, __shfl_xor(mx, 4));
    mx = fmaxf(mx, __shfl_xor(mx, 2));  mx = fmaxf(mx, __shfl_xor(mx, 1));
    if (lane == 0) redm[wave] = mx;
    __syncthreads();
    mx = fmaxf(fmaxf(redm[0], redm[1]), fmaxf(redm[2], redm[3]));
    float ex = expf(val - mx);
    float sm = ex;
    sm += __shfl_xor(sm, 32); sm += __shfl_xor(sm, 16); sm += __shfl_xor(sm, 8);
    sm += __shfl_xor(sm, 4);  sm += __shfl_xor(sm, 2);  sm += __shfl_xor(sm, 1);
    if (lane == 0) reds[wave] = sm;
    __syncthreads();
    sm = reds[0] + reds[1] + reds[2] + reds[3];
    a_s[tid] = ex / sm;
    __syncthreads();
    int d4 = tid & 31, lg = tid >> 5;
    const float4* eb = emb4 + (size_t)b * SEQ * 192 + c * 32 + d4;
    float4 acc = make_float4(0.f, 0.f, 0.f, 0.f);
    for (int l = lg; l < SEQ; l += 8) {
        float al = a_s[l];
        float4 e = eb[(size_t)l * 192];
        acc.x += al * e.x; acc.y += al * e.y; acc.z += al * e.z; acc.w += al * e.w;
    }
    part[lg][d4] = acc;
    __syncthreads();
    if (tid < 32) {
        float4 s = part[0][tid];
#pragma unroll
        for (int g = 1; g < 8; ++g) {
            float4 p = part[g][tid];
            s.x += p.x; s.y += p.y; s.z += p.z; s.w += p.w;
        }
        ((float4*)pooled)[tid] = s;
    }
    __syncthreads();
    int d = tid & 127, hf = tid >> 7;
    const float* wr = lin_W + (size_t)d * TOK_DIM + c * 128 + hf * 64;
    float s = 0.f;
#pragma unroll 8
    for (int k = 0; k < 64; ++k) s += pooled[hf * 64 + k] * wr[k];
    atomicAdd(&tok_rep[b * KG_DIM + d], s);
}

__global__ void gate_kernel(const float* __restrict__ tok_rep,
                            const float* __restrict__ lin_b,
                            const float* __restrict__ ent_rep,
                            const float* __restrict__ gate_W,
                            const float* __restrict__ gate_b,
                            float* __restrict__ user) {
    __shared__ float tr[KG_DIM], er[KG_DIM];
    int b = blockIdx.x, d = threadIdx.x;  // 128 threads
    tr[d] = tok_rep[b * KG_DIM + d] + lin_b[d];
    er[d] = ent_rep[b * KG_DIM + d];
    __syncthreads();
    float g = gate_b[d];
    const float* wr = gate_W + (size_t)d * 256;
#pragma unroll 8
    for (int k = 0; k < KG_DIM; ++k) g += tr[k] * wr[k] + er[k] * wr[KG_DIM + k];
    float sig = 1.f / (1.f + expf(-g));
    user[b * KG_DIM + d] = sig * tr[d] + (1.f - sig) * er[d];
}

__global__ void scores_kernel(const float* __restrict__ user,
                              const float4* __restrict__ kg4,
                              float* __restrict__ out) {
    __shared__ float4 u4[BATCH * 32];  // 16 KB
    int tid = threadIdx.x;
    for (int i = tid; i < BATCH * 32; i += 256) u4[i] = ((const float4*)user)[i];
    __syncthreads();
    int n = blockIdx.x * 256 + tid;
    if (n >= N_ENTITY) return;
    float acc[BATCH];
#pragma unroll
    for (int b = 0; b < BATCH; ++b) acc[b] = 0.f;
    for (int d4 = 0; d4 < 32; ++d4) {
        float4 k = kg4[(size_t)n * 32 + d4];
#pragma unroll
        for (int b = 0; b < BATCH; ++b) {
            float4 u = u4[b * 32 + d4];
            acc[b] += k.x * u.x + k.y * u.y + k.z * u.z + k.w * u.w;
        }
    }
    for (int b = 0; b < BATCH; ++b) out[(size_t)b * N_ENTITY + n] = acc[b];
}

extern "C" void kernel_launch(void* const* d_in, const int* in_sizes, int n_in,
                              void* d_out, int out_size, void* d_ws, size_t ws_size,
                              hipStream_t stream) {
    (void)in_sizes; (void)n_in; (void)out_size;
    const int*   ctx_ent   = (const int*)d_in[0];
    const int*   ctx_tok   = (const int*)d_in[1];
    const int*   edge_index= (const int*)d_in[2];
    const int*   edge_type = (const int*)d_in[3];
    const float* tok_emb   = (const float*)d_in[4];
    const float* comp      = (const float*)d_in[5];
    const float* basis     = (const float*)d_in[6];
    const float* root      = (const float*)d_in[7];
    const float* rgcn_bias = (const float*)d_in[8];
    const float* ent_W     = (const float*)d_in[9];
    const float* ent_b     = (const float*)d_in[10];
    const float* ent_v     = (const float*)d_in[11];
    const float* tok_W     = (const float*)d_in[12];
    const float* tok_b     = (const float*)d_in[13];
    const float* tok_v     = (const float*)d_in[14];
    const float* lin_W     = (const float*)d_in[15];
    const float* lin_b     = (const float*)d_in[16];
    const float* gate_W    = (const float*)d_in[17];
    const float* gate_b    = (const float*)d_in[18];
    float* scores = (float*)d_out;

    float* ws = (float*)d_ws;
    float* kg      = ws + OFF_KG;
    int*   cnt     = (int*)(ws + OFF_CNT);
    int*   deg     = (int*)(ws + OFF_DEG);
    int*   start   = (int*)(ws + OFF_START);
    int*   cursor  = (int*)(ws + OFF_CURSOR);
    int*   chunk   = (int*)(ws + OFF_CHUNK);
    int2*  er      = (int2*)(ws + OFF_SR);
    float* e_ws    = ws + OFF_ETOK;
    float* ent_rep = ws + OFF_ENT;
    float* tok_rep = ws + OFF_TOK;
    float* user    = ws + OFF_USER;
    float* weight  = ws + OFF_W;
    __bf16* Abf    = (__bf16*)(ws + OFF_ABF);
    __bf16* Wbf    = (__bf16*)(ws + OFF_WBF);
    const bool use_weight = (ws_size >= NEED_W_BYTES);

    // ---- RGCN: sort edges by dst, materialize bf16 weight, gather ----
    zero_kernel<<<(360000 + 255) / 256, 256, 0, stream>>>(cnt, 360000);
    count_kernel<<<(N_EDGES + 255) / 256, 256, 0, stream>>>(edge_index, edge_type, cnt);
    scan1_kernel<<<30, 1024, 0, stream>>>(cnt, deg, start, chunk);
    scan2_kernel<<<1, 64, 0, stream>>>(chunk, chunk + 32, start);
    scan3_kernel<<<30, 1024, 0, stream>>>(chunk + 32, start, cursor);
    place_kernel<<<(N_EDGES + 255) / 256, 256, 0, stream>>>(edge_index, edge_type, cnt,
                                                            cursor, er);
    // zero e_ws .. user (contiguous 20480 floats)
    zero_kernel<<<80, 256, 0, stream>>>((int*)e_ws, 20480);
    if (use_weight) {
        weight_bf16_kernel<<<3750, 256, 0, stream>>>(comp, (const float4*)basis,
                                                     (uint2*)weight);
        gather_kernel<<<(N_ENTITY + 3) / 4, 256, 0, stream>>>(
            start, deg, er, (const unsigned int*)weight, (const float2*)root,
            (const float2*)rgcn_bias, (float2*)kg);
    } else {
        gather_otf_kernel<<<(N_ENTITY + 3) / 4, 256, 0, stream>>>(
            start, deg, er, comp, (const float2*)basis, (const float2*)root,
            (const float2*)rgcn_bias, (float2*)kg);
    }
    ent_attn_kernel<<<BATCH, 256, 0, stream>>>(ctx_ent, kg, ent_W, ent_b, ent_v, ent_rep);

    // ---- tok path: bf16 convert (overlays weight region; gather is done) ----
    convA_kernel<<<(BATCH * SEQ * TOK_DIM / 8 + 255) / 256, 256, 0, stream>>>(
        tok_emb, Abf, BATCH * SEQ * TOK_DIM / 8);
    {
        dim3 g(12, 12);
        convWT_kernel<<<g, 256, 0, stream>>>(tok_W, Wbf);
    }
    {
        dim3 g(TOK_DIM / 128, BATCH * SEQ / 128);  // (6, 64)
        tok_gemm_kernel<<<g, 256, 0, stream>>>(Abf, Wbf, tok_b, tok_v, e_ws);
    }
    {
        dim3 g(BATCH, 6);
        tok_pool2_kernel<<<g, 256, 0, stream>>>(ctx_tok, e_ws, (const float4*)tok_emb,
                                                lin_W, tok_rep);
    }
    gate_kernel<<<BATCH, 128, 0, stream>>>(tok_rep, lin_b, ent_rep, gate_W, gate_b, user);
    scores_kernel<<<(N_ENTITY + 255) / 256, 256, 0, stream>>>(user, (const float4*)kg, scores);
}

// Round 8
// 473.193 us; speedup vs baseline: 2.7977x; 1.0151x over previous
//
#include <hip/hip_runtime.h>
#include <hip/hip_bf16.h>
#include <math.h>

#define N_ENTITY 30000
#define N_REL    12
#define N_BASES  8
#define KG_DIM   128
#define TOK_DIM  768
#define BATCH    32
#define N_CTX    50
#define SEQ      256
#define N_EDGES  400000

// fp8 weight scale: values ~N(0,1.1e-3); x1024 -> std ~1.2, max ~6 sigma = 7,
// inside fp8 range; undone by one multiply in gather's epilogue.
#define W8_SCALE 1024.0f
#define W8_INV   (1.0f / 1024.0f)

// ---------------- workspace layout (in floats) ----------------
#define OFF_KG     0           // 3,840,000
#define OFF_CNT    3840000     // 360,000 ints
#define OFF_DEG    4200000     // 30,000 ints
#define OFF_START  4230000     // 30,004 ints (N+1 used)
#define OFF_CURSOR 4260004     // 30,000 ints
#define OFF_CHUNK  4290004     // 64 ints: [0,30) chunksum, [32,62) chunkoff
#define OFF_SR     4290068     // 400,000 int2 {src|r<<15, norm}
#define OFF_ETOK   5090068     // 8,192 (raw e from gemm atomics)
#define OFF_ENT    5098260     // 4,096
#define OFF_TOK    5102356     // 4,096
#define OFF_USER   5106452     // 4,096
// weight (fp8, 46.08 MB = 11,520,000 floats) overlaid later by bf16 tok bufs
#define OFF_W      5110548
#define OFF_ABF    5110548     // 6,291,456 bf16 = 3,145,728 floats
#define OFF_WBF    8256276     // 589,824 bf16 = 294,912 floats
#define NEED_W_BYTES ((size_t)(OFF_W + 11520000) * 4)

typedef __bf16 bf16x8 __attribute__((ext_vector_type(8)));
typedef float  floatx4 __attribute__((ext_vector_type(4)));

__device__ __forceinline__ float tanh_fast(float x) {
    float ax = fabsf(x);
    float e = __expf(-2.0f * ax);
    float t = 1.0f - 2.0f * e / (1.0f + e);
    return copysignf(t, x);
}

__global__ void zero_kernel(int* __restrict__ p, int n) {
    int i = blockIdx.x * 256 + threadIdx.x;
    if (i < n) p[i] = 0;
}

// per-(r,dst) count only (deg derived in scan1)
__global__ void count_kernel(const int* __restrict__ edge_index,
                             const int* __restrict__ edge_type,
                             int* __restrict__ cnt) {
    int e = blockIdx.x * 256 + threadIdx.x;
    if (e >= N_EDGES) return;
    int r = edge_type[e];
    int dst = edge_index[N_EDGES + e];
    atomicAdd(&cnt[r * N_ENTITY + dst], 1);
}

// scan1: deg[i] = sum_r cnt[r,i]; block-local exclusive scan -> start;
// per-block total -> chunksum. grid 30 x 1024.
__global__ __launch_bounds__(1024) void scan1_kernel(const int* __restrict__ cnt,
                                                     int* __restrict__ deg,
                                                     int* __restrict__ start,
                                                     int* __restrict__ chunksum) {
    __shared__ int wsum[16];
    int tid = threadIdx.x, lane = tid & 63, wv = tid >> 6;
    int i = blockIdx.x * 1024 + tid;
    int v = 0;
    if (i < N_ENTITY) {
#pragma unroll
        for (int r = 0; r < N_REL; ++r) v += cnt[r * N_ENTITY + i];
        deg[i] = v;
    }
    int x = v;
#pragma unroll
    for (int off = 1; off < 64; off <<= 1) {
        int t = __shfl_up(x, off);
        if (lane >= off) x += t;
    }
    if (lane == 63) wsum[wv] = x;
    __syncthreads();
    if (wv == 0 && lane < 16) {
        int w = wsum[lane];
#pragma unroll
        for (int off = 1; off < 16; off <<= 1) {
            int t = __shfl_up(w, off);
            if (lane >= off) w += t;
        }
        wsum[lane] = w;  // inclusive
    }
    __syncthreads();
    int wbase = (wv == 0) ? 0 : wsum[wv - 1];
    if (i < N_ENTITY) start[i] = wbase + x - v;      // block-local exclusive
    if (tid == 1023) chunksum[blockIdx.x] = wbase + x;  // block total
}

// scan2: wave 0 scans the 30 chunk sums; whole block also zeroes the small
// accumulator region (e_ws..user, 20480 floats) -- folds a launch.
__global__ __launch_bounds__(256) void scan2_kernel(const int* __restrict__ chunksum,
                                                    int* __restrict__ chunkoff,
                                                    int* __restrict__ start,
                                                    int* __restrict__ zp) {
    int tid = threadIdx.x;
    if (tid < 64) {
        int lane = tid;
        int v = (lane < 30) ? chunksum[lane] : 0;
        int x = v;
#pragma unroll
        for (int off = 1; off < 64; off <<= 1) {
            int t = __shfl_up(x, off);
            if (lane >= off) x += t;
        }
        if (lane < 30) chunkoff[lane] = x - v;
        if (lane == 63) start[N_ENTITY] = x;
    }
    for (int i = tid; i < 20480; i += 256) zp[i] = 0;
}

// scan3: add chunk offset; write cursor. grid 30 x 1024.
__global__ __launch_bounds__(1024) void scan3_kernel(const int* __restrict__ chunkoff,
                                                     int* __restrict__ start,
                                                     int* __restrict__ cursor) {
    int i = blockIdx.x * 1024 + threadIdx.x;
    if (i < N_ENTITY) {
        int s = start[i] + chunkoff[blockIdx.x];
        start[i] = s;
        cursor[i] = s;
    }
}

// one packed int2 store per edge: {src | r<<15, norm bits}
__global__ void place_kernel(const int* __restrict__ edge_index,
                             const int* __restrict__ edge_type,
                             const int* __restrict__ cnt,
                             int* __restrict__ cursor,
                             int2* __restrict__ er) {
    int e = blockIdx.x * 256 + threadIdx.x;
    if (e >= N_EDGES) return;
    int r = edge_type[e];
    int src = edge_index[e];
    int dst = edge_index[N_EDGES + e];
    int c = cnt[r * N_ENTITY + dst];
    float norm = 1.0f / (float)(c > 1 ? c : 1);
    int slot = atomicAdd(&cursor[dst], 1);
    er[slot] = make_int2(src | (r << 15), __float_as_int(norm));
}

// weight_fp8: 4 dims/thread, scaled x1024, packed into one uint (HW cvt_pk).
// Layout: uint u = r*960000 + n*32 + (d>>2); byte k of u = dim 4*(d>>2)+k.
__global__ void weight_fp8_kernel(const float* __restrict__ comp,
                                  const float4* __restrict__ basis4,
                                  unsigned int* __restrict__ w1) {
    int idx = blockIdx.x * 256 + threadIdx.x;  // over N_ENTITY*KG_DIM/4 = 960000
    float4 bv[N_BASES];
#pragma unroll
    for (int i = 0; i < N_BASES; ++i) bv[i] = basis4[(size_t)i * 960000 + idx];
#pragma unroll
    for (int r = 0; r < N_REL; ++r) {
        float s0 = 0.f, s1 = 0.f, s2 = 0.f, s3 = 0.f;
#pragma unroll
        for (int i = 0; i < N_BASES; ++i) {
            float c = comp[r * N_BASES + i];
            s0 += c * bv[i].x; s1 += c * bv[i].y;
            s2 += c * bv[i].z; s3 += c * bv[i].w;
        }
        int pk = __builtin_amdgcn_cvt_pk_fp8_f32(s0 * W8_SCALE, s1 * W8_SCALE, 0, false);
        pk = __builtin_amdgcn_cvt_pk_fp8_f32(s2 * W8_SCALE, s3 * W8_SCALE, pk, true);
        w1[(size_t)r * 960000 + idx] = (unsigned int)pk;
    }
}

// one wave per dst entity; lane owns dims [2*lane, 2*lane+1] (one ushort = 2 fp8)
__global__ __launch_bounds__(256) void gather_kernel(const int* __restrict__ start,
                                                     const int* __restrict__ deg,
                                                     const int2* __restrict__ er,
                                                     const unsigned short* __restrict__ w8,
                                                     const float2* __restrict__ root2,
                                                     const float2* __restrict__ bias2,
                                                     float2* __restrict__ kg2) {
    int wv = threadIdx.x >> 6, lane = threadIdx.x & 63;
    int dst = blockIdx.x * 4 + wv;
    if (dst >= N_ENTITY) return;
    int s = start[dst], n = deg[dst];
    float ax = 0.f, ay = 0.f;
    int j = 0;
    for (; j + 1 < n; j += 2) {
        int2 e0 = er[s + j], e1 = er[s + j + 1];
        float n0 = __int_as_float(e0.y), n1 = __int_as_float(e1.y);
        int s0 = e0.x & 32767, r0 = e0.x >> 15;
        int s1 = e1.x & 32767, r1 = e1.x >> 15;
        int u0 = (int)w8[((size_t)(r0 * N_ENTITY + s0) << 6) + lane];
        int u1 = (int)w8[((size_t)(r1 * N_ENTITY + s1) << 6) + lane];
        ax += __builtin_amdgcn_cvt_f32_fp8(u0, 0) * n0 +
              __builtin_amdgcn_cvt_f32_fp8(u1, 0) * n1;
        ay += __builtin_amdgcn_cvt_f32_fp8(u0, 1) * n0 +
              __builtin_amdgcn_cvt_f32_fp8(u1, 1) * n1;
    }
    if (j < n) {
        int2 e0 = er[s + j];
        float n0 = __int_as_float(e0.y);
        int s0 = e0.x & 32767, r0 = e0.x >> 15;
        int u0 = (int)w8[((size_t)(r0 * N_ENTITY + s0) << 6) + lane];
        ax += __builtin_amdgcn_cvt_f32_fp8(u0, 0) * n0;
        ay += __builtin_amdgcn_cvt_f32_fp8(u0, 1) * n0;
    }
    float2 rt = root2[(size_t)dst * 64 + lane];
    float2 bs = bias2[lane];
    kg2[(size_t)dst * 64 + lane] = make_float2(ax * W8_INV + rt.x + bs.x,
                                               ay * W8_INV + rt.y + bs.y);
}

// fallback: compute message from basis on the fly (no weight buffer)
__global__ __launch_bounds__(256) void gather_otf_kernel(const int* __restrict__ start,
                                                         const int* __restrict__ deg,
                                                         const int2* __restrict__ er,
                                                         const float* __restrict__ comp,
                                                         const float2* __restrict__ basis2,
                                                         const float2* __restrict__ root2,
                                                         const float2* __restrict__ bias2,
                                                         float2* __restrict__ kg2) {
    int wv = threadIdx.x >> 6, lane = threadIdx.x & 63;
    int dst = blockIdx.x * 4 + wv;
    if (dst >= N_ENTITY) return;
    int s = start[dst], n = deg[dst];
    float ax = 0.f, ay = 0.f;
    for (int j = 0; j < n; ++j) {
        int2 e0 = er[s + j];
        float nm = __int_as_float(e0.y);
        int src = e0.x & 32767, r = e0.x >> 15;
        float mx = 0.f, my = 0.f;
#pragma unroll
        for (int b = 0; b < N_BASES; ++b) {
            float cf = comp[r * N_BASES + b];
            float2 bs = basis2[((size_t)b * N_ENTITY + src) * 64 + lane];
            mx += cf * bs.x; my += cf * bs.y;
        }
        ax += mx * nm; ay += my * nm;
    }
    float2 rt = root2[(size_t)dst * 64 + lane];
    float2 bs = bias2[lane];
    kg2[(size_t)dst * 64 + lane] = make_float2(ax + rt.x + bs.x, ay + rt.y + bs.y);
}

// entity self-dot attention pool: one block per batch element.
__global__ __launch_bounds__(256) void ent_attn_kernel(const int* __restrict__ ctx_ent,
                                                       const float* __restrict__ kg,
                                                       const float* __restrict__ W,
                                                       const float* __restrict__ bb,
                                                       const float* __restrict__ v,
                                                       float* __restrict__ ent_rep) {
    __shared__ __align__(16) float Ws[KG_DIM * KG_DIM];  // 64 KB
    __shared__ __align__(16) float h[N_CTX * KG_DIM];    // 25.6 KB
    __shared__ float es[64];
    __shared__ int ids[N_CTX];
    int b = blockIdx.x, tid = threadIdx.x;
    if (tid < N_CTX) ids[tid] = ctx_ent[b * N_CTX + tid];
    __syncthreads();
    for (int i = tid; i < N_CTX * 32; i += 256) {
        int l = i >> 5, d4 = i & 31;
        ((float4*)h)[i] = ((const float4*)kg)[(size_t)ids[l] * 32 + d4];
    }
    for (int i = tid; i < KG_DIM * KG_DIM / 4; i += 256)
        ((float4*)Ws)[i] = ((const float4*)W)[i];
    __syncthreads();

    int wave = tid >> 6, lane = tid & 63;
    const int nl = (N_CTX - wave + 3) / 4;  // 13,13,12,12
    float s0[13], s1[13];
#pragma unroll
    for (int i = 0; i < 13; ++i) { s0[i] = 0.f; s1[i] = 0.f; }
    for (int k4 = 0; k4 < 32; ++k4) {
        float4 hk[13];
#pragma unroll
        for (int i = 0; i < 13; ++i)
            if (i < nl) hk[i] = ((const float4*)h)[(wave + i * 4) * 32 + k4];
#pragma unroll
        for (int kk = 0; kk < 4; ++kk) {
            int k = k4 * 4 + kk;
            float w0 = Ws[k * KG_DIM + lane];
            float w1 = Ws[k * KG_DIM + lane + 64];
#pragma unroll
            for (int i = 0; i < 13; ++i) {
                if (i < nl) {
                    float hv = (&hk[i].x)[kk];
                    s0[i] += hv * w0;
                    s1[i] += hv * w1;
                }
            }
        }
    }
    float bias0 = bb[lane], bias1 = bb[lane + 64];
    float v0 = v[lane], v1 = v[lane + 64];
    for (int i = 0; i < nl; ++i) {
        int l = wave + i * 4;
        float p = tanhf(s0[i] + bias0) * v0 + tanhf(s1[i] + bias1) * v1;
        p += __shfl_xor(p, 32); p += __shfl_xor(p, 16); p += __shfl_xor(p, 8);
        p += __shfl_xor(p, 4);  p += __shfl_xor(p, 2);  p += __shfl_xor(p, 1);
        if (lane == 0) es[l] = p;
    }
    __syncthreads();
    if (tid < 64) {
        float val = (tid < N_CTX && ids[tid] != 0) ? es[tid] : -1e9f;
        float mx = val;
        mx = fmaxf(mx, __shfl_xor(mx, 32)); mx = fmaxf(mx, __shfl_xor(mx, 16));
        mx = fmaxf(mx, __shfl_xor(mx, 8));  mx = fmaxf(mx, __shfl_xor(mx, 4));
        mx = fmaxf(mx, __shfl_xor(mx, 2));  mx = fmaxf(mx, __shfl_xor(mx, 1));
        float ex = (tid < N_CTX) ? expf(val - mx) : 0.f;
        float sm = ex;
        sm += __shfl_xor(sm, 32); sm += __shfl_xor(sm, 16); sm += __shfl_xor(sm, 8);
        sm += __shfl_xor(sm, 4);  sm += __shfl_xor(sm, 2);  sm += __shfl_xor(sm, 1);
        if (tid < N_CTX) es[tid] = ex / sm;
    }
    __syncthreads();
    if (tid < KG_DIM) {
        float o = 0.f;
#pragma unroll
        for (int l = 0; l < N_CTX; ++l) o += es[l] * h[l * KG_DIM + tid];
        ent_rep[b * KG_DIM + tid] = o;
    }
}

// ---------------- tok path: bf16 conversion + MFMA GEMM ----------------

__global__ void convA_kernel(const float* __restrict__ in, __bf16* __restrict__ out,
                             int n8) {
    int i = blockIdx.x * 256 + threadIdx.x;
    if (i >= n8) return;
    const float4* p = (const float4*)(in + (size_t)i * 8);
    float4 a = p[0], b = p[1];
    union { __bf16 h[8]; uint4 u; } r;
    r.h[0] = (__bf16)a.x; r.h[1] = (__bf16)a.y; r.h[2] = (__bf16)a.z; r.h[3] = (__bf16)a.w;
    r.h[4] = (__bf16)b.x; r.h[5] = (__bf16)b.y; r.h[6] = (__bf16)b.z; r.h[7] = (__bf16)b.w;
    *(uint4*)(out + (size_t)i * 8) = r.u;
}

// Wt[c][k] = (bf16) W[k][c] : 64x64 LDS tile transpose, grid (12,12)
__global__ void convWT_kernel(const float* __restrict__ W, __bf16* __restrict__ Wt) {
    __shared__ float tile[64][65];
    int tx = threadIdx.x & 63, ty = threadIdx.x >> 6;
    int kb = blockIdx.x * 64, cb = blockIdx.y * 64;
#pragma unroll
    for (int i = 0; i < 16; ++i) {
        int r = ty + i * 4;
        tile[r][tx] = W[(size_t)(kb + r) * TOK_DIM + cb + tx];
    }
    __syncthreads();
#pragma unroll
    for (int i = 0; i < 16; ++i) {
        int r = ty + i * 4;
        Wt[(size_t)(cb + r) * TOK_DIM + kb + tx] = (__bf16)tile[tx][r];
    }
}

// Z = A[8192x768] x W[768x768] bf16 MFMA; epilogue: e[row] += sum v*tanh(z+b)
__global__ __launch_bounds__(256) void tok_gemm_kernel(const __bf16* __restrict__ A,
                                                       const __bf16* __restrict__ Bt,
                                                       const float* __restrict__ bias,
                                                       const float* __restrict__ v,
                                                       float* __restrict__ e_out) {
    __shared__ __align__(16) __bf16 sA[4096];
    __shared__ __align__(16) __bf16 sB[4096];
    int tid = threadIdx.x;
    int wave = tid >> 6, lane = tid & 63;
    int wm = wave >> 1, wn = wave & 1;
    int quad = lane >> 4, idx = lane & 15;
    int m0 = blockIdx.y * 128, c0 = blockIdx.x * 128;

    int rowS = tid & 127, kpS = tid >> 7;
    const __bf16* gA0 = A + (size_t)(m0 + rowS) * TOK_DIM + kpS * 8;
    const __bf16* gA1 = gA0 + 16;
    const __bf16* gB0 = Bt + (size_t)(c0 + rowS) * TOK_DIM + kpS * 8;
    const __bf16* gB1 = gB0 + 16;
    __bf16* dA0 = &sA[tid * 8];
    __bf16* dA1 = &sA[tid * 8 + 2048];
    __bf16* dB0 = &sB[tid * 8];
    __bf16* dB1 = &sB[tid * 8 + 2048];

    floatx4 acc[4][4];
#pragma unroll
    for (int mi = 0; mi < 4; ++mi)
#pragma unroll
        for (int ni = 0; ni < 4; ++ni)
            acc[mi][ni] = (floatx4){0.f, 0.f, 0.f, 0.f};

    for (int k0 = 0; k0 < TOK_DIM; k0 += 32) {
        uint4 ra0 = *(const uint4*)(gA0 + k0);
        uint4 ra1 = *(const uint4*)(gA1 + k0);
        uint4 rb0 = *(const uint4*)(gB0 + k0);
        uint4 rb1 = *(const uint4*)(gB1 + k0);
        __syncthreads();
        *(uint4*)dA0 = ra0; *(uint4*)dA1 = ra1;
        *(uint4*)dB0 = rb0; *(uint4*)dB1 = rb1;
        __syncthreads();
        bf16x8 aF[4], bF[4];
#pragma unroll
        for (int i = 0; i < 4; ++i) {
            aF[i] = *(const bf16x8*)&sA[quad * 1024 + (wm * 64 + i * 16 + idx) * 8];
            bF[i] = *(const bf16x8*)&sB[quad * 1024 + (wn * 64 + i * 16 + idx) * 8];
        }
#pragma unroll
        for (int mi = 0; mi < 4; ++mi)
#pragma unroll
            for (int ni = 0; ni < 4; ++ni)
                acc[mi][ni] = __builtin_amdgcn_mfma_f32_16x16x32_bf16(
                    aF[mi], bF[ni], acc[mi][ni], 0, 0, 0);
    }

    float bv[4], vv[4];
#pragma unroll
    for (int ni = 0; ni < 4; ++ni) {
        int c = c0 + wn * 64 + ni * 16 + idx;
        bv[ni] = bias[c]; vv[ni] = v[c];
    }
#pragma unroll
    for (int mi = 0; mi < 4; ++mi) {
        float s[4] = {0.f, 0.f, 0.f, 0.f};
#pragma unroll
        for (int ni = 0; ni < 4; ++ni)
#pragma unroll
            for (int r = 0; r < 4; ++r)
                s[r] += tanh_fast(acc[mi][ni][r] + bv[ni]) * vv[ni];
#pragma unroll
        for (int r = 0; r < 4; ++r) {
            s[r] += __shfl_xor(s[r], 1); s[r] += __shfl_xor(s[r], 2);
            s[r] += __shfl_xor(s[r], 4); s[r] += __shfl_xor(s[r], 8);
        }
        if (idx == 0) {
            int rbase = m0 + wm * 64 + mi * 16 + quad * 4;
#pragma unroll
            for (int r = 0; r < 4; ++r) atomicAdd(&e_out[rbase + r], s[r]);
        }
    }
}

// fused masked-softmax + pooled chunk (128 dims, read from bf16 A copy) +
// partial linear into tok_rep. grid (32, 6), 256 thr.
__global__ __launch_bounds__(256) void tok_pool2_kernel(const int* __restrict__ ctx_tok,
                                                        const float* __restrict__ e_ws,
                                                        const __bf16* __restrict__ Abf,
                                                        const float* __restrict__ lin_W,
                                                        float* __restrict__ tok_rep) {
    __shared__ float a_s[SEQ];
    __shared__ float4 part[8][32];
    __shared__ __align__(16) float pooled[128];
    __shared__ float redm[4];
    __shared__ float reds[4];
    int b = blockIdx.x, c = blockIdx.y;
    int tid = threadIdx.x;
    int wave = tid >> 6, lane = tid & 63;
    int t = ctx_tok[b * SEQ + tid];
    float val = (t != 0) ? e_ws[b * SEQ + tid] : -1e9f;
    float mx = val;
    mx = fmaxf(mx, __shfl_xor(mx, 32)); mx = fmaxf(mx, __shfl_xor(mx, 16));
    mx = fmaxf(mx, __shfl_xor(mx, 8));  mx = fmaxf(mx, __shfl_xor(mx, 4));
    mx = fmaxf(mx, __shfl_xor(mx, 2));  mx = fmaxf(mx, __shfl_xor(mx, 1));
    if (lane == 0) redm[wave] = mx;
    __syncthreads();
    mx = fmaxf(fmaxf(redm[0], redm[1]), fmaxf(redm[2], redm[3]));
    float ex = expf(val - mx);
    float sm = ex;
    sm += __shfl_xor(sm, 32); sm += __shfl_xor(sm, 16); sm += __shfl_xor(sm, 8);
    sm += __shfl_xor(sm, 4);  sm += __shfl_xor(sm, 2);  sm += __shfl_xor(sm, 1);
    if (lane == 0) reds[wave] = sm;
    __syncthreads();
    sm = reds[0] + reds[1] + reds[2] + reds[3];
    a_s[tid] = ex / sm;
    __syncthreads();
    int d4 = tid & 31, lg = tid >> 5;
    // lane covers dims [c*128 + d4*4, +4) from the bf16 A copy (8 B loads)
    const unsigned int* eb = (const unsigned int*)(Abf + (size_t)b * SEQ * TOK_DIM +
                                                   c * 128 + d4 * 4);
    float4 acc = make_float4(0.f, 0.f, 0.f, 0.f);
    for (int l = lg; l < SEQ; l += 8) {
        float al = a_s[l];
        unsigned int u0 = eb[(size_t)l * 384];      // dims d,d+1
        unsigned int u1 = eb[(size_t)l * 384 + 1];  // dims d+2,d+3
        acc.x += al * __uint_as_float(u0 << 16);
        acc.y += al * __uint_as_float(u0 & 0xffff0000u);
        acc.z += al * __uint_as_float(u1 << 16);
        acc.w += al * __uint_as_float(u1 & 0xffff0000u);
    }
    part[lg][d4] = acc;
    __syncthreads();
    if (tid < 32) {
        float4 s = part[0][tid];
#pragma unroll
        for (int g = 1; g < 8; ++g) {
            float4 p = part[g][tid];
            s.x += p.x; s.y += p.y; s.z += p.z; s.w += p.w;
        }
        ((float4*)pooled)[tid] = s;
    }
    __syncthreads();
    int d = tid & 127, hf = tid >> 7;
    const float* wr = lin_W + (size_t)d * TOK_DIM + c * 128 + hf * 64;
    float s = 0.f;
#pragma unroll 8
    for (int k = 0; k < 64; ++k) s += pooled[hf * 64 + k] * wr[k];
    atomicAdd(&tok_rep[b * KG_DIM + d], s);
}

__global__ void gate_kernel(const float* __restrict__ tok_rep,
                            const float* __restrict__ lin_b,
                            const float* __restrict__ ent_rep,
                            const float* __restrict__ gate_W,
                            const float* __restrict__ gate_b,
                            float* __restrict__ user) {
    __shared__ float tr[KG_DIM], er[KG_DIM];
    int b = blockIdx.x, d = threadIdx.x;  // 128 threads
    tr[d] = tok_rep[b * KG_DIM + d] + lin_b[d];
    er[d] = ent_rep[b * KG_DIM + d];
    __syncthreads();
    float g = gate_b[d];
    const float* wr = gate_W + (size_t)d * 256;
#pragma unroll 8
    for (int k = 0; k < KG_DIM; ++k) g += tr[k] * wr[k] + er[k] * wr[KG_DIM + k];
    float sig = 1.f / (1.f + expf(-g));
    user[b * KG_DIM + d] = sig * tr[d] + (1.f - sig) * er[d];
}

__global__ void scores_kernel(const float* __restrict__ user,
                              const float4* __restrict__ kg4,
                              float* __restrict__ out) {
    __shared__ float4 u4[BATCH * 32];  // 16 KB
    int tid = threadIdx.x;
    for (int i = tid; i < BATCH * 32; i += 256) u4[i] = ((const float4*)user)[i];
    __syncthreads();
    int n = blockIdx.x * 256 + tid;
    if (n >= N_ENTITY) return;
    float acc[BATCH];
#pragma unroll
    for (int b = 0; b < BATCH; ++b) acc[b] = 0.f;
    for (int d4 = 0; d4 < 32; ++d4) {
        float4 k = kg4[(size_t)n * 32 + d4];
#pragma unroll
        for (int b = 0; b < BATCH; ++b) {
            float4 u = u4[b * 32 + d4];
            acc[b] += k.x * u.x + k.y * u.y + k.z * u.z + k.w * u.w;
        }
    }
    for (int b = 0; b < BATCH; ++b) out[(size_t)b * N_ENTITY + n] = acc[b];
}

extern "C" void kernel_launch(void* const* d_in, const int* in_sizes, int n_in,
                              void* d_out, int out_size, void* d_ws, size_t ws_size,
                              hipStream_t stream) {
    (void)in_sizes; (void)n_in; (void)out_size;
    const int*   ctx_ent   = (const int*)d_in[0];
    const int*   ctx_tok   = (const int*)d_in[1];
    const int*   edge_index= (const int*)d_in[2];
    const int*   edge_type = (const int*)d_in[3];
    const float* tok_emb   = (const float*)d_in[4];
    const float* comp      = (const float*)d_in[5];
    const float* basis     = (const float*)d_in[6];
    const float* root      = (const float*)d_in[7];
    const float* rgcn_bias = (const float*)d_in[8];
    const float* ent_W     = (const float*)d_in[9];
    const float* ent_b     = (const float*)d_in[10];
    const float* ent_v     = (const float*)d_in[11];
    const float* tok_W     = (const float*)d_in[12];
    const float* tok_b     = (const float*)d_in[13];
    const float* tok_v     = (const float*)d_in[14];
    const float* lin_W     = (const float*)d_in[15];
    const float* lin_b     = (const float*)d_in[16];
    const float* gate_W    = (const float*)d_in[17];
    const float* gate_b    = (const float*)d_in[18];
    float* scores = (float*)d_out;

    float* ws = (float*)d_ws;
    float* kg      = ws + OFF_KG;
    int*   cnt     = (int*)(ws + OFF_CNT);
    int*   deg     = (int*)(ws + OFF_DEG);
    int*   start   = (int*)(ws + OFF_START);
    int*   cursor  = (int*)(ws + OFF_CURSOR);
    int*   chunk   = (int*)(ws + OFF_CHUNK);
    int2*  er      = (int2*)(ws + OFF_SR);
    float* e_ws    = ws + OFF_ETOK;
    float* ent_rep = ws + OFF_ENT;
    float* tok_rep = ws + OFF_TOK;
    float* user    = ws + OFF_USER;
    float* weight  = ws + OFF_W;
    __bf16* Abf    = (__bf16*)(ws + OFF_ABF);
    __bf16* Wbf    = (__bf16*)(ws + OFF_WBF);
    const bool use_weight = (ws_size >= NEED_W_BYTES);

    // ---- RGCN: sort edges by dst, materialize fp8 weight, gather ----
    zero_kernel<<<(360000 + 255) / 256, 256, 0, stream>>>(cnt, 360000);
    count_kernel<<<(N_EDGES + 255) / 256, 256, 0, stream>>>(edge_index, edge_type, cnt);
    scan1_kernel<<<30, 1024, 0, stream>>>(cnt, deg, start, chunk);
    scan2_kernel<<<1, 256, 0, stream>>>(chunk, chunk + 32, start, (int*)e_ws);
    scan3_kernel<<<30, 1024, 0, stream>>>(chunk + 32, start, cursor);
    place_kernel<<<(N_EDGES + 255) / 256, 256, 0, stream>>>(edge_index, edge_type, cnt,
                                                            cursor, er);
    if (use_weight) {
        weight_fp8_kernel<<<3750, 256, 0, stream>>>(comp, (const float4*)basis,
                                                    (unsigned int*)weight);
        gather_kernel<<<(N_ENTITY + 3) / 4, 256, 0, stream>>>(
            start, deg, er, (const unsigned short*)weight, (const float2*)root,
            (const float2*)rgcn_bias, (float2*)kg);
    } else {
        gather_otf_kernel<<<(N_ENTITY + 3) / 4, 256, 0, stream>>>(
            start, deg, er, comp, (const float2*)basis, (const float2*)root,
            (const float2*)rgcn_bias, (float2*)kg);
    }
    ent_attn_kernel<<<BATCH, 256, 0, stream>>>(ctx_ent, kg, ent_W, ent_b, ent_v, ent_rep);

    // ---- tok path: bf16 convert (overlays weight region; gather is done) ----
    convA_kernel<<<(BATCH * SEQ * TOK_DIM / 8 + 255) / 256, 256, 0, stream>>>(
        tok_emb, Abf, BATCH * SEQ * TOK_DIM / 8);
    {
        dim3 g(12, 12);
        convWT_kernel<<<g, 256, 0, stream>>>(tok_W, Wbf);
    }
    {
        dim3 g(TOK_DIM / 128, BATCH * SEQ / 128);  // (6, 64)
        tok_gemm_kernel<<<g, 256, 0, stream>>>(Abf, Wbf, tok_b, tok_v, e_ws);
    }
    {
        dim3 g(BATCH, 6);
        tok_pool2_kernel<<<g, 256, 0, stream>>>(ctx_tok, e_ws, Abf, lin_W, tok_rep);
    }
    gate_kernel<<<BATCH, 128, 0, stream>>>(tok_rep, lin_b, ent_rep, gate_W, gate_b, user);
    scores_kernel<<<(N_ENTITY + 255) / 256, 256, 0, stream>>>(user, (const float4*)kg, scores);
}